// Round 10
// baseline (537.600 us; speedup 1.0000x reference)
//
#include <hip/hip_runtime.h>
#include <hip/hip_bf16.h>

#define NN 1024
#define DD 256
#define LL 6

typedef __attribute__((ext_vector_type(8))) short bf16x8;
typedef __attribute__((ext_vector_type(4))) float f32x4;
typedef __attribute__((ext_vector_type(4))) unsigned short u16x4;

__device__ __forceinline__ unsigned short f2bf(float f) {
    union { float f; unsigned u; } x; x.f = f;
    return (unsigned short)((x.u + 0x7fffu + ((x.u >> 16) & 1u)) >> 16);
}

__device__ __forceinline__ unsigned short f2bf_trunc(float f) {
    union { float f; unsigned u; } x; x.f = f;
    return (unsigned short)(x.u >> 16);
}

__device__ __forceinline__ float bf2f(unsigned short u) {
    union { unsigned u; float f; } x; x.u = ((unsigned)u) << 16; return x.f;
}

__device__ __forceinline__ f32x4 mfma16(bf16x8 a, bf16x8 b, f32x4 c) {
    return __builtin_amdgcn_mfma_f32_16x16x32_bf16(a, b, c, 0, 0, 0);
}

// async global->LDS, 16B per lane; lds dest = wave-uniform base + lane*16
__device__ __forceinline__ void gll16(const unsigned short* g, unsigned short* l) {
    __builtin_amdgcn_global_load_lds(
        (const __attribute__((address_space(1))) unsigned int*)g,
        (__attribute__((address_space(3))) unsigned int*)l, 16, 0, 0);
}

// ---------------- prep: wconv | maskconv | fold2 | init | fold1, block-partitioned ----
__global__ __launch_bounds__(256) void prep_kernel(
    const float* __restrict__ desc0, const float* __restrict__ desc1,
    const float* __restrict__ M0, const float* __restrict__ M1,
    const float* __restrict__ Wq, const float* __restrict__ Wk,
    const float* __restrict__ Wv, const float* __restrict__ Wm,
    const float* __restrict__ W1, const float* __restrict__ W2,
    const float* __restrict__ bm, const float* __restrict__ b1,
    unsigned short* __restrict__ wbf, unsigned short* __restrict__ maskbf,
    float* __restrict__ bmix, float* __restrict__ desc, unsigned short* __restrict__ xbf,
    unsigned short* __restrict__ W1m) {
    __shared__ __align__(16) char pmem[17408];
    const int SQ = LL * 65536;
    const int S1 = LL * 262144;
    int blk = blockIdx.x, tid = threadIdx.x;
    if (blk < 15360) {
        int idx = blk * 256 + tid;
        int total = 4 * SQ + S1 + LL * 131072;
        if (idx >= total) return;
        float v;
        if (idx < 4 * SQ) {
            int seg = idx / SQ, off = idx % SQ;
            const float* p = (seg == 0) ? Wq : (seg == 1) ? Wk : (seg == 2) ? Wv : Wm;
            if (seg < 3) {
                int l = off >> 16, rem = off & 65535;
                int op = rem >> 8, i = rem & 255;
                int src = ((op & 63) << 2) | (op >> 6);
                v = p[(size_t)l * 65536 + src * 256 + i];
            } else v = p[off];
        } else if (idx < 4 * SQ + S1) v = W1[idx - 4 * SQ];
        else v = W2[idx - 4 * SQ - S1];
        wbf[idx] = f2bf(v);
    } else if (blk < 19456) {
        int idx = (blk - 15360) * 256 + tid;
        size_t base = (size_t)idx * 4;
        int bb = (int)(base >> 20);
        const float* src = (bb < 2) ? (M0 + base) : (M1 + base - (2ull << 20));
        f32x4 v = *(const f32x4*)src;
        u16x4 o;
#pragma unroll
        for (int j = 0; j < 4; j++) o[j] = f2bf(v[j]);
        *(u16x4*)(maskbf + base) = o;
    } else if (blk < 20224) {
        int lane = tid & 63;
        int wid = (blk - 19456) * 4 + (tid >> 6);
        int l = wid >> 9, o = wid & 511;
        const float* row = W1 + ((size_t)l * 512 + o) * 512 + 256;
        const float* bmr = bm + (size_t)l * 256;
        f32x4 r = *(const f32x4*)(row + lane * 4);
        f32x4 b4 = *(const f32x4*)(bmr + lane * 4);
        float acc = r[0] * b4[0] + r[1] * b4[1] + r[2] * b4[2] + r[3] * b4[3];
        acc += __shfl_xor(acc, 1, 64);
        acc += __shfl_xor(acc, 2, 64);
        acc += __shfl_xor(acc, 4, 64);
        acc += __shfl_xor(acc, 8, 64);
        acc += __shfl_xor(acc, 16, 64);
        acc += __shfl_xor(acc, 32, 64);
        if (lane == 0) bmix[wid] = b1[wid] + acc;
    } else if (blk < 21248) {
        float* T = (float*)pmem;   // [32][33]
        int task = blk - 20224;
        int bb = task >> 8, tt = task & 255;
        int n0 = (tt >> 3) * 32, c0 = (tt & 7) * 32;
        const float* src = (bb < 2) ? (desc0 + (size_t)bb * DD * NN)
                                    : (desc1 + (size_t)(bb - 2) * DD * NN);
        int i = tid >> 5, j = tid & 31;
#pragma unroll
        for (int r = 0; r < 4; r++) {
            int c = i + r * 8;
            T[c * 33 + j] = src[(size_t)(c0 + c) * NN + n0 + j];
        }
        __syncthreads();
#pragma unroll
        for (int r = 0; r < 4; r++) {
            int n = i + r * 8;
            float v = T[j * 33 + n];
            size_t di = ((size_t)bb * NN + n0 + n) * DD + c0 + j;
            desc[di] = v;
            xbf[di] = f2bf(v);
        }
    } else {
        // fold1 from fp32: W1m_perm[l][o][h*64+d] = W1[:,256:] @ Wm  (192 tasks)
        unsigned short* Bt = (unsigned short*)pmem;   // [64][136]
        int w = tid >> 6, lane = tid & 63, quad = lane >> 4, l15 = lane & 15;
        int wr = (w & 1) * 32, wc = (w >> 1) * 32;
        int task = blk - 21248;
        int l = task / 32, tt = task % 32;
        int o0 = (tt >> 2) * 64, i0 = (tt & 3) * 64;
        const float* A = W1 + (size_t)l * 262144;
        const float* B = Wm + (size_t)l * 65536;
        f32x4 acc[2][2];
#pragma unroll
        for (int r = 0; r < 2; r++)
#pragma unroll
            for (int c = 0; c < 2; c++) acc[r][c] = (f32x4){0.f, 0.f, 0.f, 0.f};
        for (int ch = 0; ch < 2; ch++) {
            __syncthreads();
            int jj = tid >> 1, ih = (tid & 1) * 32;
            const float* bs = B + (size_t)(ch * 128 + jj) * 256 + i0 + ih;
#pragma unroll
            for (int r = 0; r < 8; r++) {
                f32x4 b4 = *(const f32x4*)(bs + r * 4);
#pragma unroll
                for (int q2 = 0; q2 < 4; q2++)
                    Bt[(ih + r * 4 + q2) * 136 + jj] = f2bf(b4[q2]);
            }
            __syncthreads();
#pragma unroll
            for (int s = 0; s < 4; s++) {
                bf16x8 af[2], bf[2];
#pragma unroll
                for (int rs = 0; rs < 2; rs++) {
                    const float* ap = A + (size_t)(o0 + wr + rs * 16 + l15) * 512 + 256
                                      + ch * 128 + s * 32 + quad * 8;
                    f32x4 a04 = *(const f32x4*)ap;
                    f32x4 a14 = *(const f32x4*)(ap + 4);
                    union { bf16x8 v; unsigned short u[8]; } pk;
#pragma unroll
                    for (int jx = 0; jx < 4; jx++) { pk.u[jx] = f2bf(a04[jx]); pk.u[4 + jx] = f2bf(a14[jx]); }
                    af[rs] = pk.v;
                }
#pragma unroll
                for (int cs = 0; cs < 2; cs++)
                    bf[cs] = *(const bf16x8*)(&Bt[(wc + cs * 16 + l15) * 136 + s * 32 + quad * 8]);
                acc[0][0] = mfma16(af[0], bf[0], acc[0][0]);
                acc[0][1] = mfma16(af[0], bf[1], acc[0][1]);
                acc[1][0] = mfma16(af[1], bf[0], acc[1][0]);
                acc[1][1] = mfma16(af[1], bf[1], acc[1][1]);
            }
        }
#pragma unroll
        for (int rs = 0; rs < 2; rs++)
#pragma unroll
            for (int cs = 0; cs < 2; cs++)
#pragma unroll
                for (int reg = 0; reg < 4; reg++) {
                    int o = o0 + wr + rs * 16 + quad * 4 + reg;
                    int i = i0 + wc + cs * 16 + l15;
                    int pc = (i & 3) * 64 + (i >> 2);
                    W1m[((size_t)l * 512 + o) * 256 + pc] = f2bf(acc[rs][cs][reg]);
                }
    }
}

// ---------------- final: [4][1024][256] -> [4][256][1024] via LDS tiles ----------------
__global__ __launch_bounds__(256) void final_kernel(const float* __restrict__ desc,
                                                    float* __restrict__ out) {
    __shared__ float T[32][33];
    int bb = blockIdx.z;
    int n0 = blockIdx.x * 32, c0 = blockIdx.y * 32;
    int i = threadIdx.x >> 5, j = threadIdx.x & 31;
#pragma unroll
    for (int r = 0; r < 4; r++) {
        int n = i + r * 8;
        T[n][j] = desc[((size_t)bb * NN + n0 + n) * DD + c0 + j];
    }
    __syncthreads();
#pragma unroll
    for (int r = 0; r < 4; r++) {
        int c = i + r * 8;
        out[((size_t)bb * DD + c0 + c) * NN + n0 + j] = T[j][c];
    }
}

// ---------------- proj: M=4096, N=768 (q|k|v), K=256; 64x64 tiles, LDS staging --------
// q-scale folds 0.125 * log2(e) so flash can use exp2 directly.
__global__ __launch_bounds__(256) void proj_kernel(
    const unsigned short* __restrict__ xbf,
    const unsigned short* __restrict__ Wq_l, const unsigned short* __restrict__ Wk_l,
    const unsigned short* __restrict__ Wv_l,
    const float* __restrict__ bq_l, const float* __restrict__ bk_l,
    const float* __restrict__ bv_l,
    unsigned short* __restrict__ qb, unsigned short* __restrict__ kb,
    unsigned short* __restrict__ vb, int cross) {
    __shared__ __align__(16) unsigned short sm[8192];
    unsigned short* Al = sm;
    unsigned short* Bl = sm + 4096;

    int m0 = blockIdx.x * 64;
    int by = blockIdx.y;
    int mat = by >> 2;
    int o0c = (by & 3) * 64;
    int bb = m0 >> 10, nloc0 = m0 & 1023;
    int srcbb = (mat == 0) ? bb : (cross ? (bb ^ 2) : bb);
    const unsigned short* A = xbf + (size_t)srcbb * NN * DD + (size_t)nloc0 * DD;
    const unsigned short* W = ((mat == 0) ? Wq_l : (mat == 1) ? Wk_l : Wv_l) + (size_t)o0c * DD;
    const float* bias = (mat == 0) ? bq_l : (mat == 1) ? bk_l : bv_l;

    int tid = threadIdx.x, w = tid >> 6, lane = tid & 63, quad = lane >> 4, l15 = lane & 15;
    int wrow = (w & 1) * 32, wcol = (w >> 1) * 32;
    int lrow = lane >> 3, lcol = (lane & 7) * 8;

    f32x4 acc[2][2];
#pragma unroll
    for (int r = 0; r < 2; r++)
#pragma unroll
        for (int c = 0; c < 2; c++) acc[r][c] = (f32x4){0.f, 0.f, 0.f, 0.f};

    for (int ks = 0; ks < 4; ks++) {
        int k0 = ks * 64;
        __syncthreads();
#pragma unroll
        for (int j = 0; j < 2; j++)
            gll16(A + (size_t)(w * 16 + j * 8 + lrow) * DD + k0 + lcol, Al + (w * 16 + j * 8) * 64);
#pragma unroll
        for (int j = 0; j < 2; j++)
            gll16(W + (size_t)(w * 16 + j * 8 + lrow) * DD + k0 + lcol, Bl + (w * 16 + j * 8) * 64);
        __syncthreads();
#pragma unroll
        for (int kh = 0; kh < 2; kh++) {
            bf16x8 bf[2], af[2];
#pragma unroll
            for (int cs = 0; cs < 2; cs++)
                bf[cs] = *(const bf16x8*)(Bl + (wcol + cs * 16 + l15) * 64 + kh * 32 + quad * 8);
#pragma unroll
            for (int rs = 0; rs < 2; rs++)
                af[rs] = *(const bf16x8*)(Al + (wrow + rs * 16 + l15) * 64 + kh * 32 + quad * 8);
#pragma unroll
            for (int rs = 0; rs < 2; rs++)
#pragma unroll
                for (int cs = 0; cs < 2; cs++)
                    acc[rs][cs] = mfma16(af[rs], bf[cs], acc[rs][cs]);
        }
    }
    __syncthreads();
    float qscale = (mat == 0) ? 0.1803368801f : 1.0f;   // 0.125 * log2(e) for q
    if (mat < 2) {
#pragma unroll
        for (int rs = 0; rs < 2; rs++)
#pragma unroll
            for (int cs = 0; cs < 2; cs++) {
                int op = o0c + wcol + cs * 16 + l15;
                float bv4 = bias[((op & 63) << 2) | (op >> 6)];
#pragma unroll
                for (int reg = 0; reg < 4; reg++)
                    sm[(wrow + rs * 16 + quad * 4 + reg) * 72 + wcol + cs * 16 + l15] =
                        f2bf((acc[rs][cs][reg] + bv4) * qscale);
            }
        __syncthreads();
        int r = tid >> 2, ch = (tid & 3) * 16;
        unsigned short* dst = ((mat == 0) ? qb : kb) + ((size_t)(bb * NN) + nloc0 + r) * 256 + o0c + ch;
        *(bf16x8*)(dst) = *(const bf16x8*)(&sm[r * 72 + ch]);
        *(bf16x8*)(dst + 8) = *(const bf16x8*)(&sm[r * 72 + ch + 8]);
    } else {
#pragma unroll
        for (int rs = 0; rs < 2; rs++)
#pragma unroll
            for (int cs = 0; cs < 2; cs++) {
                int op = o0c + wcol + cs * 16 + l15;
                float bv4 = bias[((op & 63) << 2) | (op >> 6)];
#pragma unroll
                for (int reg = 0; reg < 4; reg++)
                    sm[(wcol + cs * 16 + l15) * 72 + wrow + rs * 16 + quad * 4 + reg] =
                        f2bf(acc[rs][cs][reg] + bv4);
            }
        __syncthreads();
        int o = tid >> 2, nch = (tid & 3) * 16;
        int opg = o0c + o;
        unsigned short* dst = vb + ((size_t)(bb * 4 + (opg >> 6)) * 64 + (opg & 63)) * NN + nloc0 + nch;
        *(bf16x8*)(dst) = *(const bf16x8*)(&sm[o * 72 + nch]);
        *(bf16x8*)(dst + 8) = *(const bf16x8*)(&sm[o * 72 + nch + 8]);
    }
}

// ---------------- flash attention: exp2-based softmax (log2e folded into q) -----------
__global__ __launch_bounds__(512, 4) void flash_kernel(
    const unsigned short* __restrict__ qb, const unsigned short* __restrict__ kb,
    const unsigned short* __restrict__ vb,
    const unsigned short* __restrict__ maskbf,
    unsigned short* __restrict__ xattn, float* __restrict__ bnsumm) {
    __shared__ __align__(16) char smem[51200];
    unsigned short* Plds = (unsigned short*)smem;   // phase 1: [8][16][72]
    float* OL = (float*)smem;                        // phase 2: [8][64][25]

    int bh = blockIdx.y, nb = blockIdx.x;
    int bb = bh >> 2, h = bh & 3;
    int tid = threadIdx.x, w = tid >> 6, lane = tid & 63, quad = lane >> 4, l15 = lane & 15;
    int qg = w & 1, sp = w >> 1;

    if (nb == 0 && bh == 0) { bnsumm[tid] = 0.f; bnsumm[tid + 512] = 0.f; }

    const unsigned short* mask = maskbf + (size_t)bb * NN * NN;
    const unsigned short* Q = qb + (size_t)bb * NN * 256 + h * 64;
    const unsigned short* Kb = kb + (size_t)bb * NN * 256 + h * 64;
    const unsigned short* Vb = vb + (size_t)bh * 64 * NN;
    int row0 = nb * 32 + qg * 16;

    bf16x8 qf[2];
#pragma unroll
    for (int kc = 0; kc < 2; kc++)
        qf[kc] = *(const bf16x8*)(Q + (size_t)(row0 + l15) * 256 + kc * 32 + quad * 8);

    const unsigned short* mrow[4];
#pragma unroll
    for (int reg = 0; reg < 4; reg++)
        mrow[reg] = mask + (size_t)(row0 + quad * 4 + reg) * NN + sp * 256;

    f32x4 Oa[4];
#pragma unroll
    for (int dt = 0; dt < 4; dt++) Oa[dt] = (f32x4){0.f, 0.f, 0.f, 0.f};
    float mrun[4], lrun[4];
#pragma unroll
    for (int r = 0; r < 4; r++) { mrun[r] = -1e30f; lrun[r] = 0.f; }

    unsigned short* Pw = Plds + w * (16 * 72);

    for (int mt = 0; mt < 4; mt++) {
        int ml = mt * 64;
        int m0 = sp * 256 + ml;
        f32x4 s4[4];
#pragma unroll
        for (int t = 0; t < 4; t++) s4[t] = (f32x4){0.f, 0.f, 0.f, 0.f};
#pragma unroll
        for (int t = 0; t < 4; t++)
#pragma unroll
            for (int kc = 0; kc < 2; kc++) {
                bf16x8 kf = *(const bf16x8*)(Kb + (size_t)(m0 + t * 16 + l15) * 256 + kc * 32 + quad * 8);
                s4[t] = mfma16(qf[kc], kf, s4[t]);
            }
        bf16x8 vf[8];
#pragma unroll
        for (int dt = 0; dt < 4; dt++)
#pragma unroll
            for (int kc = 0; kc < 2; kc++)
                vf[dt * 2 + kc] = *(const bf16x8*)(Vb + (size_t)(dt * 16 + l15) * NN + m0 + kc * 32 + quad * 8);
        // scores already in log2 units (q pre-scaled by 0.125*log2e); mask scales linearly
        float sv[4][4], rmax[4];
#pragma unroll
        for (int r = 0; r < 4; r++) rmax[r] = -1e30f;
#pragma unroll
        for (int t = 0; t < 4; t++)
#pragma unroll
            for (int reg = 0; reg < 4; reg++) {
                float v = s4[t][reg] * bf2f(mrow[reg][ml + t * 16 + l15]);
                sv[t][reg] = v;
                rmax[reg] = fmaxf(rmax[reg], v);
            }
#pragma unroll
        for (int reg = 0; reg < 4; reg++) {
            rmax[reg] = fmaxf(rmax[reg], __shfl_xor(rmax[reg], 1, 64));
            rmax[reg] = fmaxf(rmax[reg], __shfl_xor(rmax[reg], 2, 64));
            rmax[reg] = fmaxf(rmax[reg], __shfl_xor(rmax[reg], 4, 64));
            rmax[reg] = fmaxf(rmax[reg], __shfl_xor(rmax[reg], 8, 64));
        }
        float alpha[4], rsum[4];
#pragma unroll
        for (int reg = 0; reg < 4; reg++) {
            float mn = fmaxf(mrun[reg], rmax[reg]);
            alpha[reg] = exp2f(mrun[reg] - mn);
            mrun[reg] = mn;
            rsum[reg] = 0.f;
        }
#pragma unroll
        for (int t = 0; t < 4; t++)
#pragma unroll
            for (int reg = 0; reg < 4; reg++) {
                float p = exp2f(sv[t][reg] - mrun[reg]);
                sv[t][reg] = p;
                rsum[reg] += p;
            }
#pragma unroll
        for (int reg = 0; reg < 4; reg++) {
            rsum[reg] += __shfl_xor(rsum[reg], 1, 64);
            rsum[reg] += __shfl_xor(rsum[reg], 2, 64);
            rsum[reg] += __shfl_xor(rsum[reg], 4, 64);
            rsum[reg] += __shfl_xor(rsum[reg], 8, 64);
            lrun[reg] = lrun[reg] * alpha[reg] + rsum[reg];
        }
#pragma unroll
        for (int dt = 0; dt < 4; dt++)
#pragma unroll
            for (int reg = 0; reg < 4; reg++) Oa[dt][reg] *= alpha[reg];
        // P pack: truncation (values in [0,1], consumed immediately)
#pragma unroll
        for (int t = 0; t < 4; t++)
#pragma unroll
            for (int reg = 0; reg < 4; reg++)
                Pw[(quad * 4 + reg) * 72 + t * 16 + l15] = f2bf_trunc(sv[t][reg]);
        bf16x8 pf[2];
#pragma unroll
        for (int kc = 0; kc < 2; kc++)
            pf[kc] = *(const bf16x8*)(Pw + l15 * 72 + kc * 32 + quad * 8);
#pragma unroll
        for (int dt = 0; dt < 4; dt++)
#pragma unroll
            for (int kc = 0; kc < 2; kc++)
                Oa[dt] = mfma16(pf[kc], vf[dt * 2 + kc], Oa[dt]);
    }
    __syncthreads();
    float* mine = OL + (size_t)(w * 64 + lane) * 25;
#pragma unroll
    for (int dt = 0; dt < 4; dt++)
#pragma unroll
        for (int reg = 0; reg < 4; reg++) mine[dt * 4 + reg] = Oa[dt][reg];
#pragma unroll
    for (int reg = 0; reg < 4; reg++) { mine[16 + reg] = mrun[reg]; mine[20 + reg] = lrun[reg]; }
    __syncthreads();
    if (sp == 0) {
        const float* p[4];
#pragma unroll
        for (int j = 0; j < 4; j++) p[j] = OL + (size_t)((qg + 2 * j) * 64 + lane) * 25;
        float e[4][4], li[4];
#pragma unroll
        for (int reg = 0; reg < 4; reg++) {
            float M = fmaxf(fmaxf(p[0][16 + reg], p[1][16 + reg]),
                            fmaxf(p[2][16 + reg], p[3][16 + reg]));
            float L = 0.f;
#pragma unroll
            for (int j = 0; j < 4; j++) {
                e[j][reg] = exp2f(p[j][16 + reg] - M);
                L += p[j][20 + reg] * e[j][reg];
            }
            li[reg] = 1.f / L;
        }
#pragma unroll
        for (int dt = 0; dt < 4; dt++)
#pragma unroll
            for (int reg = 0; reg < 4; reg++) {
                float val = 0.f;
#pragma unroll
                for (int j = 0; j < 4; j++) val += p[j][dt * 4 + reg] * e[j][reg];
                val *= li[reg];
                int n = row0 + quad * 4 + reg;
                int col = h * 64 + dt * 16 + l15;
                xattn[((size_t)bb * NN + n) * DD + col] = f2bf(val);
            }
    }
}

// ---------------- conv1: M=4096, N=512, K=512 (x|attn); 64x64 tiles + BN stats -------
__global__ __launch_bounds__(256) void conv1_kernel(
    const unsigned short* __restrict__ xbf, const unsigned short* __restrict__ xattn,
    const unsigned short* __restrict__ W1_l, const unsigned short* __restrict__ W1m_l,
    const float* __restrict__ bmix_l,
    unsigned short* __restrict__ out1, float* __restrict__ bnsumm) {
    __shared__ __align__(16) unsigned short sm[8192];
    unsigned short* Al = sm;
    unsigned short* Bl = sm + 4096;

    int m0 = blockIdx.x * 64, o0 = blockIdx.y * 64;
    int bb = m0 >> 10, nloc0 = m0 & 1023;
    const unsigned short* A1 = xbf + (size_t)bb * NN * DD + (size_t)nloc0 * DD;
    const unsigned short* A2 = xattn + (size_t)bb * NN * DD + (size_t)nloc0 * DD;

    int tid = threadIdx.x, w = tid >> 6, lane = tid & 63, quad = lane >> 4, l15 = lane & 15;
    int wrow = (w & 1) * 32, wcol = (w >> 1) * 32;
    int lrow = lane >> 3, lcol = (lane & 7) * 8;

    f32x4 acc[2][2];
#pragma unroll
    for (int r = 0; r < 2; r++)
#pragma unroll
        for (int c = 0; c < 2; c++) acc[r][c] = (f32x4){0.f, 0.f, 0.f, 0.f};

    for (int ks = 0; ks < 8; ks++) {
        const unsigned short* As = (ks < 4) ? A1 : A2;
        int kloc = (ks & 3) * 64;
        __syncthreads();
#pragma unroll
        for (int j = 0; j < 2; j++)
            gll16(As + (size_t)(w * 16 + j * 8 + lrow) * DD + kloc + lcol, Al + (w * 16 + j * 8) * 64);
#pragma unroll
        for (int j = 0; j < 2; j++) {
            int orow = o0 + w * 16 + j * 8 + lrow;
            const unsigned short* bg = (ks < 4)
                ? (W1_l + (size_t)orow * 512 + ks * 64 + lcol)
                : (W1m_l + (size_t)orow * 256 + (ks - 4) * 64 + lcol);
            gll16(bg, Bl + (w * 16 + j * 8) * 64);
        }
        __syncthreads();
#pragma unroll
        for (int kh = 0; kh < 2; kh++) {
            bf16x8 bf[2], af[2];
#pragma unroll
            for (int cs = 0; cs < 2; cs++)
                bf[cs] = *(const bf16x8*)(Bl + (wcol + cs * 16 + l15) * 64 + kh * 32 + quad * 8);
#pragma unroll
            for (int rs = 0; rs < 2; rs++)
                af[rs] = *(const bf16x8*)(Al + (wrow + rs * 16 + l15) * 64 + kh * 32 + quad * 8);
#pragma unroll
            for (int rs = 0; rs < 2; rs++)
#pragma unroll
                for (int cs = 0; cs < 2; cs++)
                    acc[rs][cs] = mfma16(af[rs], bf[cs], acc[rs][cs]);
        }
    }
    __syncthreads();
    float cs_s[2] = {0.f, 0.f}, cs_q[2] = {0.f, 0.f};
#pragma unroll
    for (int rs = 0; rs < 2; rs++)
#pragma unroll
        for (int cs = 0; cs < 2; cs++) {
            int o = o0 + wcol + cs * 16 + l15;
            float bvx = bmix_l[o];
#pragma unroll
            for (int reg = 0; reg < 4; reg++) {
                float val = acc[rs][cs][reg] + bvx;
                sm[(wrow + rs * 16 + quad * 4 + reg) * 72 + wcol + cs * 16 + l15] = f2bf(val);
                cs_s[cs] += val;
                cs_q[cs] += val * val;
            }
        }
#pragma unroll
    for (int cs = 0; cs < 2; cs++) {
        cs_s[cs] += __shfl_xor(cs_s[cs], 16, 64);
        cs_s[cs] += __shfl_xor(cs_s[cs], 32, 64);
        cs_q[cs] += __shfl_xor(cs_q[cs], 16, 64);
        cs_q[cs] += __shfl_xor(cs_q[cs], 32, 64);
    }
    if (lane < 16) {
#pragma unroll
        for (int cs = 0; cs < 2; cs++) {
            atomicAdd(&bnsumm[o0 + wcol + cs * 16 + lane], cs_s[cs]);
            atomicAdd(&bnsumm[512 + o0 + wcol + cs * 16 + lane], cs_q[cs]);
        }
    }
    __syncthreads();
    int r = tid >> 2, ch = (tid & 3) * 16;
    unsigned short* dst = out1 + ((size_t)(bb * NN) + nloc0 + r) * 512 + o0 + ch;
    *(bf16x8*)(dst) = *(const bf16x8*)(&sm[r * 72 + ch]);
    *(bf16x8*)(dst + 8) = *(const bf16x8*)(&sm[r * 72 + ch + 8]);
}

// ---------------- bnrelu: y = relu(sc*out1 + sh) -> bf16 (BN finalize inlined) --------
__global__ __launch_bounds__(256) void bnrelu_kernel(
    const unsigned short* __restrict__ out1, const float* __restrict__ bnsumm,
    const float* __restrict__ g1_l, const float* __restrict__ beta1_l,
    unsigned short* __restrict__ ybf) {
    int idx = blockIdx.x * 256 + threadIdx.x;
    int base = idx * 8;
    int o = base & 511;
    union { bf16x8 v; unsigned short u[8]; } in, op;
    in.v = *(const bf16x8*)(out1 + base);
#pragma unroll
    for (int j = 0; j < 8; j++) {
        int ch = o + j;
        float s = bnsumm[ch], s2 = bnsumm[512 + ch];
        float mean = s * (1.f / 4096.f);
        float var = s2 * (1.f / 4096.f) - mean * mean;
        float sc = g1_l[ch] * rsqrtf(var + 1e-5f);
        float sh = beta1_l[ch] - mean * sc;
        op.u[j] = f2bf(fmaxf(0.f, bf2f(in.u[j]) * sc + sh));
    }
    *(bf16x8*)(ybf + base) = op.v;
}

// ---------------- conv2: pure GEMM M=4096, N=256, K=512; 32x64 tiles, LDS staging -----
__global__ __launch_bounds__(256) void conv2_kernel(
    const unsigned short* __restrict__ ybf, const unsigned short* __restrict__ W2_l,
    const float* __restrict__ b2_l, float* __restrict__ desc,
    unsigned short* __restrict__ xbf) {
    __shared__ __align__(16) unsigned short sm[6144];
    unsigned short* Al = sm;
    unsigned short* Bl = sm + 2048;

    int m0 = blockIdx.x * 32, o0 = blockIdx.y * 64;
    int bb = m0 >> 10, nloc0 = m0 & 1023;
    const unsigned short* A = ybf + ((size_t)(bb * NN) + nloc0) * 512;

    int tid = threadIdx.x, w = tid >> 6, lane = tid & 63, quad = lane >> 4, l15 = lane & 15;
    int wr = (w & 1) * 16, wc = (w >> 1) * 32;
    int lrow = lane >> 3, lcol = (lane & 7) * 8;

    f32x4 acc[2];
    acc[0] = (f32x4){0.f, 0.f, 0.f, 0.f};
    acc[1] = (f32x4){0.f, 0.f, 0.f, 0.f};

    for (int ks = 0; ks < 8; ks++) {
        int k0 = ks * 64;
        __syncthreads();
        gll16(A + (size_t)(w * 8 + lrow) * 512 + k0 + lcol, Al + (w * 8) * 64);
#pragma unroll
        for (int j = 0; j < 2; j++)
            gll16(W2_l + (size_t)(o0 + w * 16 + j * 8 + lrow) * 512 + k0 + lcol,
                  Bl + (w * 16 + j * 8) * 64);
        __syncthreads();
#pragma unroll
        for (int kh = 0; kh < 2; kh++) {
            bf16x8 af = *(const bf16x8*)(Al + (wr + l15) * 64 + kh * 32 + quad * 8);
#pragma unroll
            for (int cs = 0; cs < 2; cs++) {
                bf16x8 bf = *(const bf16x8*)(Bl + (wc + cs * 16 + l15) * 64 + kh * 32 + quad * 8);
                acc[cs] = mfma16(af, bf, acc[cs]);
            }
        }
    }
#pragma unroll
    for (int cs = 0; cs < 2; cs++)
#pragma unroll
        for (int reg = 0; reg < 4; reg++) {
            int n = nloc0 + wr + quad * 4 + reg;
            int o = o0 + wc + cs * 16 + l15;
            size_t di = ((size_t)bb * NN + n) * DD + o;
            float nd = desc[di] + acc[cs][reg] + b2_l[o];
            desc[di] = nd;
            xbf[di] = f2bf(nd);
        }
}

extern "C" void kernel_launch(void* const* d_in, const int* in_sizes, int n_in,
                              void* d_out, int out_size, void* d_ws, size_t ws_size,
                              hipStream_t stream) {
    const float* desc0 = (const float*)d_in[0];
    const float* desc1 = (const float*)d_in[1];
    const float* M0p   = (const float*)d_in[2];
    const float* M1p   = (const float*)d_in[3];
    const float* Wq = (const float*)d_in[4];  const float* bq = (const float*)d_in[5];
    const float* Wk = (const float*)d_in[6];  const float* bk = (const float*)d_in[7];
    const float* Wv = (const float*)d_in[8];  const float* bv = (const float*)d_in[9];
    const float* Wm = (const float*)d_in[10]; const float* bm = (const float*)d_in[11];
    const float* W1 = (const float*)d_in[12]; const float* b1 = (const float*)d_in[13];
    const float* g1 = (const float*)d_in[14]; const float* beta1 = (const float*)d_in[15];
    const float* W2 = (const float*)d_in[16]; const float* b2 = (const float*)d_in[17];
    float* out = (float*)d_out;
    char* ws = (char*)d_ws;

    float*          desc   = (float*)(ws);
    unsigned short* xbf    = (unsigned short*)(ws + (4ull << 20));
    unsigned short* qb     = (unsigned short*)(ws + (6ull << 20));
    unsigned short* kbuf   = (unsigned short*)(ws + (8ull << 20));
    unsigned short* vbuf   = (unsigned short*)(ws + (10ull << 20));
    unsigned short* xattn  = (unsigned short*)(ws + (12ull << 20));
    unsigned short* out1   = (unsigned short*)(ws + (14ull << 20));
    float*          bnsumm = (float*)(ws + (18ull << 20));
    float*          bmix   = (float*)(ws + (18ull << 20) + 8192);
    unsigned short* maskbf = (unsigned short*)(ws + (19ull << 20));
    unsigned short* W1m    = (unsigned short*)(ws + (27ull << 20));
    unsigned short* wbf    = (unsigned short*)(ws + (29ull << 20));
    unsigned short* ybf    = (unsigned short*)(ws + (37ull << 20));

    const int SQ = LL * 65536;

    prep_kernel<<<21440, 256, 0, stream>>>(desc0, desc1, M0p, M1p, Wq, Wk, Wv, Wm,
                                           W1, W2, bm, b1, wbf, maskbf, bmix, desc, xbf, W1m);

    for (int l = 0; l < LL; l++) {
        int cross = l & 1;
        const unsigned short* Wq_l = wbf + (size_t)l * 65536;
        const unsigned short* Wk_l = wbf + SQ + (size_t)l * 65536;
        const unsigned short* Wv_l = wbf + 2 * (size_t)SQ + (size_t)l * 65536;
        const unsigned short* W1_l = wbf + 4 * (size_t)SQ + (size_t)l * 262144;
        const unsigned short* W2_l = wbf + 4 * (size_t)SQ + (size_t)LL * 262144 + (size_t)l * 131072;
        const unsigned short* W1m_l = W1m + (size_t)l * 131072;

        proj_kernel<<<dim3(64, 12), 256, 0, stream>>>(
            xbf, Wq_l, Wk_l, Wv_l, bq + l * 256, bk + l * 256, bv + l * 256,
            qb, kbuf, vbuf, cross);
        flash_kernel<<<dim3(32, 16), 512, 0, stream>>>(qb, kbuf, vbuf, maskbf, xattn, bnsumm);
        conv1_kernel<<<dim3(64, 8), 256, 0, stream>>>(
            xbf, xattn, W1_l, W1m_l, bmix + l * 512, out1, bnsumm);
        bnrelu_kernel<<<1024, 256, 0, stream>>>(out1, bnsumm, g1 + l * 512, beta1 + l * 512, ybf);
        conv2_kernel<<<dim3(128, 4), 256, 0, stream>>>(
            ybf, W2_l, b2 + l * 256, desc, xbf);
    }

    final_kernel<<<dim3(32, 8, 4), 256, 0, stream>>>(desc, out);
}

// Round 11
// 520.756 us; speedup vs baseline: 1.0323x; 1.0323x over previous
//
#include <hip/hip_runtime.h>
#include <hip/hip_bf16.h>

#define NN 1024
#define DD 256
#define LL 6

typedef __attribute__((ext_vector_type(8))) short bf16x8;
typedef __attribute__((ext_vector_type(4))) float f32x4;
typedef __attribute__((ext_vector_type(4))) unsigned short u16x4;

__device__ __forceinline__ unsigned short f2bf(float f) {
    union { float f; unsigned u; } x; x.f = f;
    return (unsigned short)((x.u + 0x7fffu + ((x.u >> 16) & 1u)) >> 16);
}

__device__ __forceinline__ unsigned short f2bf_trunc(float f) {
    union { float f; unsigned u; } x; x.f = f;
    return (unsigned short)(x.u >> 16);
}

__device__ __forceinline__ float bf2f(unsigned short u) {
    union { unsigned u; float f; } x; x.u = ((unsigned)u) << 16; return x.f;
}

__device__ __forceinline__ f32x4 mfma16(bf16x8 a, bf16x8 b, f32x4 c) {
    return __builtin_amdgcn_mfma_f32_16x16x32_bf16(a, b, c, 0, 0, 0);
}

// async global->LDS, 16B per lane; lds dest = wave-uniform base + lane*16
__device__ __forceinline__ void gll16(const unsigned short* g, unsigned short* l) {
    __builtin_amdgcn_global_load_lds(
        (const __attribute__((address_space(1))) unsigned int*)g,
        (__attribute__((address_space(3))) unsigned int*)l, 16, 0, 0);
}

// ---------------- prep: wconv(vec4) | maskconv | fold2 | init, block-partitioned ------
__global__ __launch_bounds__(256) void prep_kernel(
    const float* __restrict__ desc0, const float* __restrict__ desc1,
    const float* __restrict__ M0, const float* __restrict__ M1,
    const float* __restrict__ Wq, const float* __restrict__ Wk,
    const float* __restrict__ Wv, const float* __restrict__ Wm,
    const float* __restrict__ W1, const float* __restrict__ W2,
    const float* __restrict__ bm, const float* __restrict__ b1,
    unsigned short* __restrict__ wbf, unsigned short* __restrict__ maskbf,
    float* __restrict__ bmix, float* __restrict__ desc, unsigned short* __restrict__ xbf) {
    __shared__ float T[32][33];
    const int SQ = LL * 65536;
    const int S1 = LL * 262144;
    int blk = blockIdx.x, tid = threadIdx.x;
    if (blk < 3840) {
        // weights fp32 -> bf16, 4 elems/thread (16B loads); q/k/v rows permuted to o'=h*64+d
        int idx = blk * 256 + tid;
        size_t base = (size_t)idx * 4;
        f32x4 v;
        if (base < (size_t)4 * SQ) {
            int seg = (int)(base / SQ), off = (int)(base % SQ);
            const float* p = (seg == 0) ? Wq : (seg == 1) ? Wk : (seg == 2) ? Wv : Wm;
            if (seg < 3) {
                int l = off >> 16, rem = off & 65535;
                int op = rem >> 8, i = rem & 255;          // op = h*64+d, i aligned to 4
                int src = ((op & 63) << 2) | (op >> 6);    // source row d*4+h
                v = *(const f32x4*)(p + (size_t)l * 65536 + (size_t)src * 256 + i);
            } else {
                v = *(const f32x4*)(p + off);
            }
        } else if (base < (size_t)4 * SQ + S1) {
            v = *(const f32x4*)(W1 + base - 4 * SQ);
        } else {
            v = *(const f32x4*)(W2 + base - 4 * SQ - S1);
        }
        u16x4 o;
#pragma unroll
        for (int j = 0; j < 4; j++) o[j] = f2bf(v[j]);
        *(u16x4*)(wbf + base) = o;
    } else if (blk < 7936) {
        // mask fp32 -> bf16 (4 elems/thread)
        int idx = (blk - 3840) * 256 + tid;
        size_t base = (size_t)idx * 4;
        int bb = (int)(base >> 20);
        const float* src = (bb < 2) ? (M0 + base) : (M1 + base - (2ull << 20));
        f32x4 v = *(const f32x4*)src;
        u16x4 o;
#pragma unroll
        for (int j = 0; j < 4; j++) o[j] = f2bf(v[j]);
        *(u16x4*)(maskbf + base) = o;
    } else if (blk < 8704) {
        // fold2: bmix = b1 + W1[:,256:] @ bm  (one wave per output)
        int lane = tid & 63;
        int wid = (blk - 7936) * 4 + (tid >> 6);
        int l = wid >> 9, o = wid & 511;
        const float* row = W1 + ((size_t)l * 512 + o) * 512 + 256;
        const float* bmr = bm + (size_t)l * 256;
        f32x4 r = *(const f32x4*)(row + lane * 4);
        f32x4 b4 = *(const f32x4*)(bmr + lane * 4);
        float acc = r[0] * b4[0] + r[1] * b4[1] + r[2] * b4[2] + r[3] * b4[3];
        acc += __shfl_xor(acc, 1, 64);
        acc += __shfl_xor(acc, 2, 64);
        acc += __shfl_xor(acc, 4, 64);
        acc += __shfl_xor(acc, 8, 64);
        acc += __shfl_xor(acc, 16, 64);
        acc += __shfl_xor(acc, 32, 64);
        if (lane == 0) bmix[wid] = b1[wid] + acc;
    } else {
        // init transpose [2][256][1024] -> [4][1024][256]
        int task = blk - 8704;
        int bb = task >> 8, tt = task & 255;
        int n0 = (tt >> 3) * 32, c0 = (tt & 7) * 32;
        const float* src = (bb < 2) ? (desc0 + (size_t)bb * DD * NN)
                                    : (desc1 + (size_t)(bb - 2) * DD * NN);
        int i = tid >> 5, j = tid & 31;
#pragma unroll
        for (int r = 0; r < 4; r++) {
            int c = i + r * 8;
            T[c][j] = src[(size_t)(c0 + c) * NN + n0 + j];
        }
        __syncthreads();
#pragma unroll
        for (int r = 0; r < 4; r++) {
            int n = i + r * 8;
            float v = T[j][n];
            size_t di = ((size_t)bb * NN + n0 + n) * DD + c0 + j;
            desc[di] = v;
            xbf[di] = f2bf(v);
        }
    }
}

// ---------------- fold1 (MFMA, bf16 inputs): W1m_perm[l][o][h*64+d] ----------------
__global__ __launch_bounds__(256) void fold1_kernel(const unsigned short* __restrict__ W1bf,
                                                    const unsigned short* __restrict__ Wmbf,
                                                    unsigned short* __restrict__ W1m) {
    int l = blockIdx.z;
    int o0 = blockIdx.x * 64, i0 = blockIdx.y * 64;
    const unsigned short* A = W1bf + (size_t)l * 262144;
    const unsigned short* B = Wmbf + (size_t)l * 65536;
    __shared__ unsigned short Bt[64][264];
    int t = threadIdx.x;
#pragma unroll
    for (int r = 0; r < 8; r++) {
        int j = r * 32 + (t >> 3);
        int il = (t & 7) * 8;
        union { bf16x8 v; unsigned short u[8]; } ld;
        ld.v = *(const bf16x8*)(B + (size_t)j * 256 + i0 + il);
#pragma unroll
        for (int jj = 0; jj < 8; jj++) Bt[il + jj][j] = ld.u[jj];
    }
    __syncthreads();
    int w = t >> 6, lane = t & 63, quad = lane >> 4, l15 = lane & 15;
    int wr = (w & 1) * 32, wc = (w >> 1) * 32;
    const unsigned short* Ab = A + (size_t)(o0 + wr + l15) * 512 + 256 + quad * 8;
    f32x4 acc[2][2];
#pragma unroll
    for (int r = 0; r < 2; r++)
#pragma unroll
        for (int c = 0; c < 2; c++) acc[r][c] = (f32x4){0.f, 0.f, 0.f, 0.f};
#pragma unroll
    for (int s = 0; s < 8; s++) {
        int kk = s * 32;
        bf16x8 a0 = *(const bf16x8*)(Ab + kk);
        bf16x8 a1 = *(const bf16x8*)(Ab + 16 * 512 + kk);
        bf16x8 b0 = *(const bf16x8*)(&Bt[wc + l15][kk + quad * 8]);
        bf16x8 b1 = *(const bf16x8*)(&Bt[wc + 16 + l15][kk + quad * 8]);
        acc[0][0] = mfma16(a0, b0, acc[0][0]);
        acc[0][1] = mfma16(a0, b1, acc[0][1]);
        acc[1][0] = mfma16(a1, b0, acc[1][0]);
        acc[1][1] = mfma16(a1, b1, acc[1][1]);
    }
#pragma unroll
    for (int rs = 0; rs < 2; rs++)
#pragma unroll
        for (int cs = 0; cs < 2; cs++)
#pragma unroll
            for (int reg = 0; reg < 4; reg++) {
                int o = o0 + wr + rs * 16 + quad * 4 + reg;
                int i = i0 + wc + cs * 16 + l15;
                int pc = (i & 3) * 64 + (i >> 2);
                W1m[((size_t)l * 512 + o) * 256 + pc] = f2bf(acc[rs][cs][reg]);
            }
}

// ---------------- final: [4][1024][256] -> [4][256][1024] via LDS tiles ----------------
__global__ __launch_bounds__(256) void final_kernel(const float* __restrict__ desc,
                                                    float* __restrict__ out) {
    __shared__ float T[32][33];
    int bb = blockIdx.z;
    int n0 = blockIdx.x * 32, c0 = blockIdx.y * 32;
    int i = threadIdx.x >> 5, j = threadIdx.x & 31;
#pragma unroll
    for (int r = 0; r < 4; r++) {
        int n = i + r * 8;
        T[n][j] = desc[((size_t)bb * NN + n0 + n) * DD + c0 + j];
    }
    __syncthreads();
#pragma unroll
    for (int r = 0; r < 4; r++) {
        int c = i + r * 8;
        out[((size_t)bb * DD + c0 + c) * NN + n0 + j] = T[j][c];
    }
}

// ---------------- proj: M=4096, N=768 (q|k|v), K=256; 64x64 tiles, LDS staging --------
// q-scale folds 0.125 * log2(e) so flash can use exp2 directly.
__global__ __launch_bounds__(256) void proj_kernel(
    const unsigned short* __restrict__ xbf,
    const unsigned short* __restrict__ Wq_l, const unsigned short* __restrict__ Wk_l,
    const unsigned short* __restrict__ Wv_l,
    const float* __restrict__ bq_l, const float* __restrict__ bk_l,
    const float* __restrict__ bv_l,
    unsigned short* __restrict__ qb, unsigned short* __restrict__ kb,
    unsigned short* __restrict__ vb, int cross) {
    __shared__ __align__(16) unsigned short sm[8192];
    unsigned short* Al = sm;
    unsigned short* Bl = sm + 4096;

    int m0 = blockIdx.x * 64;
    int by = blockIdx.y;
    int mat = by >> 2;
    int o0c = (by & 3) * 64;
    int bb = m0 >> 10, nloc0 = m0 & 1023;
    int srcbb = (mat == 0) ? bb : (cross ? (bb ^ 2) : bb);
    const unsigned short* A = xbf + (size_t)srcbb * NN * DD + (size_t)nloc0 * DD;
    const unsigned short* W = ((mat == 0) ? Wq_l : (mat == 1) ? Wk_l : Wv_l) + (size_t)o0c * DD;
    const float* bias = (mat == 0) ? bq_l : (mat == 1) ? bk_l : bv_l;

    int tid = threadIdx.x, w = tid >> 6, lane = tid & 63, quad = lane >> 4, l15 = lane & 15;
    int wrow = (w & 1) * 32, wcol = (w >> 1) * 32;
    int lrow = lane >> 3, lcol = (lane & 7) * 8;

    f32x4 acc[2][2];
#pragma unroll
    for (int r = 0; r < 2; r++)
#pragma unroll
        for (int c = 0; c < 2; c++) acc[r][c] = (f32x4){0.f, 0.f, 0.f, 0.f};

    for (int ks = 0; ks < 4; ks++) {
        int k0 = ks * 64;
        __syncthreads();
#pragma unroll
        for (int j = 0; j < 2; j++)
            gll16(A + (size_t)(w * 16 + j * 8 + lrow) * DD + k0 + lcol, Al + (w * 16 + j * 8) * 64);
#pragma unroll
        for (int j = 0; j < 2; j++)
            gll16(W + (size_t)(w * 16 + j * 8 + lrow) * DD + k0 + lcol, Bl + (w * 16 + j * 8) * 64);
        __syncthreads();
#pragma unroll
        for (int kh = 0; kh < 2; kh++) {
            bf16x8 bf[2], af[2];
#pragma unroll
            for (int cs = 0; cs < 2; cs++)
                bf[cs] = *(const bf16x8*)(Bl + (wcol + cs * 16 + l15) * 64 + kh * 32 + quad * 8);
#pragma unroll
            for (int rs = 0; rs < 2; rs++)
                af[rs] = *(const bf16x8*)(Al + (wrow + rs * 16 + l15) * 64 + kh * 32 + quad * 8);
#pragma unroll
            for (int rs = 0; rs < 2; rs++)
#pragma unroll
                for (int cs = 0; cs < 2; cs++)
                    acc[rs][cs] = mfma16(af[rs], bf[cs], acc[rs][cs]);
        }
    }
    __syncthreads();
    float qscale = (mat == 0) ? 0.1803368801f : 1.0f;   // 0.125 * log2(e) for q
    if (mat < 2) {
#pragma unroll
        for (int rs = 0; rs < 2; rs++)
#pragma unroll
            for (int cs = 0; cs < 2; cs++) {
                int op = o0c + wcol + cs * 16 + l15;
                float bv4 = bias[((op & 63) << 2) | (op >> 6)];
#pragma unroll
                for (int reg = 0; reg < 4; reg++)
                    sm[(wrow + rs * 16 + quad * 4 + reg) * 72 + wcol + cs * 16 + l15] =
                        f2bf((acc[rs][cs][reg] + bv4) * qscale);
            }
        __syncthreads();
        int r = tid >> 2, ch = (tid & 3) * 16;
        unsigned short* dst = ((mat == 0) ? qb : kb) + ((size_t)(bb * NN) + nloc0 + r) * 256 + o0c + ch;
        *(bf16x8*)(dst) = *(const bf16x8*)(&sm[r * 72 + ch]);
        *(bf16x8*)(dst + 8) = *(const bf16x8*)(&sm[r * 72 + ch + 8]);
    } else {
#pragma unroll
        for (int rs = 0; rs < 2; rs++)
#pragma unroll
            for (int cs = 0; cs < 2; cs++) {
                int op = o0c + wcol + cs * 16 + l15;
                float bv4 = bias[((op & 63) << 2) | (op >> 6)];
#pragma unroll
                for (int reg = 0; reg < 4; reg++)
                    sm[(wcol + cs * 16 + l15) * 72 + wrow + rs * 16 + quad * 4 + reg] =
                        f2bf(acc[rs][cs][reg] + bv4);
            }
        __syncthreads();
        int o = tid >> 2, nch = (tid & 3) * 16;
        int opg = o0c + o;
        unsigned short* dst = vb + ((size_t)(bb * 4 + (opg >> 6)) * 64 + (opg & 63)) * NN + nloc0 + nch;
        *(bf16x8*)(dst) = *(const bf16x8*)(&sm[o * 72 + nch]);
        *(bf16x8*)(dst + 8) = *(const bf16x8*)(&sm[o * 72 + nch + 8]);
    }
}

// ---------------- flash attention: exp2-based softmax (log2e folded into q) -----------
__global__ __launch_bounds__(512, 4) void flash_kernel(
    const unsigned short* __restrict__ qb, const unsigned short* __restrict__ kb,
    const unsigned short* __restrict__ vb,
    const unsigned short* __restrict__ maskbf,
    unsigned short* __restrict__ xattn, float* __restrict__ bnsumm) {
    __shared__ __align__(16) char smem[51200];
    unsigned short* Plds = (unsigned short*)smem;   // phase 1: [8][16][72]
    float* OL = (float*)smem;                        // phase 2: [8][64][25]

    int bh = blockIdx.y, nb = blockIdx.x;
    int bb = bh >> 2, h = bh & 3;
    int tid = threadIdx.x, w = tid >> 6, lane = tid & 63, quad = lane >> 4, l15 = lane & 15;
    int qg = w & 1, sp = w >> 1;

    if (nb == 0 && bh == 0) { bnsumm[tid] = 0.f; bnsumm[tid + 512] = 0.f; }

    const unsigned short* mask = maskbf + (size_t)bb * NN * NN;
    const unsigned short* Q = qb + (size_t)bb * NN * 256 + h * 64;
    const unsigned short* Kb = kb + (size_t)bb * NN * 256 + h * 64;
    const unsigned short* Vb = vb + (size_t)bh * 64 * NN;
    int row0 = nb * 32 + qg * 16;

    bf16x8 qf[2];
#pragma unroll
    for (int kc = 0; kc < 2; kc++)
        qf[kc] = *(const bf16x8*)(Q + (size_t)(row0 + l15) * 256 + kc * 32 + quad * 8);

    const unsigned short* mrow[4];
#pragma unroll
    for (int reg = 0; reg < 4; reg++)
        mrow[reg] = mask + (size_t)(row0 + quad * 4 + reg) * NN + sp * 256;

    f32x4 Oa[4];
#pragma unroll
    for (int dt = 0; dt < 4; dt++) Oa[dt] = (f32x4){0.f, 0.f, 0.f, 0.f};
    float mrun[4], lrun[4];
#pragma unroll
    for (int r = 0; r < 4; r++) { mrun[r] = -1e30f; lrun[r] = 0.f; }

    unsigned short* Pw = Plds + w * (16 * 72);

    for (int mt = 0; mt < 4; mt++) {
        int ml = mt * 64;
        int m0 = sp * 256 + ml;
        f32x4 s4[4];
#pragma unroll
        for (int t = 0; t < 4; t++) s4[t] = (f32x4){0.f, 0.f, 0.f, 0.f};
#pragma unroll
        for (int t = 0; t < 4; t++)
#pragma unroll
            for (int kc = 0; kc < 2; kc++) {
                bf16x8 kf = *(const bf16x8*)(Kb + (size_t)(m0 + t * 16 + l15) * 256 + kc * 32 + quad * 8);
                s4[t] = mfma16(qf[kc], kf, s4[t]);
            }
        bf16x8 vf[8];
#pragma unroll
        for (int dt = 0; dt < 4; dt++)
#pragma unroll
            for (int kc = 0; kc < 2; kc++)
                vf[dt * 2 + kc] = *(const bf16x8*)(Vb + (size_t)(dt * 16 + l15) * NN + m0 + kc * 32 + quad * 8);
        float sv[4][4], rmax[4];
#pragma unroll
        for (int r = 0; r < 4; r++) rmax[r] = -1e30f;
#pragma unroll
        for (int t = 0; t < 4; t++)
#pragma unroll
            for (int reg = 0; reg < 4; reg++) {
                float v = s4[t][reg] * bf2f(mrow[reg][ml + t * 16 + l15]);
                sv[t][reg] = v;
                rmax[reg] = fmaxf(rmax[reg], v);
            }
#pragma unroll
        for (int reg = 0; reg < 4; reg++) {
            rmax[reg] = fmaxf(rmax[reg], __shfl_xor(rmax[reg], 1, 64));
            rmax[reg] = fmaxf(rmax[reg], __shfl_xor(rmax[reg], 2, 64));
            rmax[reg] = fmaxf(rmax[reg], __shfl_xor(rmax[reg], 4, 64));
            rmax[reg] = fmaxf(rmax[reg], __shfl_xor(rmax[reg], 8, 64));
        }
        float alpha[4], rsum[4];
#pragma unroll
        for (int reg = 0; reg < 4; reg++) {
            float mn = fmaxf(mrun[reg], rmax[reg]);
            alpha[reg] = exp2f(mrun[reg] - mn);
            mrun[reg] = mn;
            rsum[reg] = 0.f;
        }
#pragma unroll
        for (int t = 0; t < 4; t++)
#pragma unroll
            for (int reg = 0; reg < 4; reg++) {
                float p = exp2f(sv[t][reg] - mrun[reg]);
                sv[t][reg] = p;
                rsum[reg] += p;
            }
#pragma unroll
        for (int reg = 0; reg < 4; reg++) {
            rsum[reg] += __shfl_xor(rsum[reg], 1, 64);
            rsum[reg] += __shfl_xor(rsum[reg], 2, 64);
            rsum[reg] += __shfl_xor(rsum[reg], 4, 64);
            rsum[reg] += __shfl_xor(rsum[reg], 8, 64);
            lrun[reg] = lrun[reg] * alpha[reg] + rsum[reg];
        }
#pragma unroll
        for (int dt = 0; dt < 4; dt++)
#pragma unroll
            for (int reg = 0; reg < 4; reg++) Oa[dt][reg] *= alpha[reg];
#pragma unroll
        for (int t = 0; t < 4; t++)
#pragma unroll
            for (int reg = 0; reg < 4; reg++)
                Pw[(quad * 4 + reg) * 72 + t * 16 + l15] = f2bf_trunc(sv[t][reg]);
        bf16x8 pf[2];
#pragma unroll
        for (int kc = 0; kc < 2; kc++)
            pf[kc] = *(const bf16x8*)(Pw + l15 * 72 + kc * 32 + quad * 8);
#pragma unroll
        for (int dt = 0; dt < 4; dt++)
#pragma unroll
            for (int kc = 0; kc < 2; kc++)
                Oa[dt] = mfma16(pf[kc], vf[dt * 2 + kc], Oa[dt]);
    }
    __syncthreads();
    float* mine = OL + (size_t)(w * 64 + lane) * 25;
#pragma unroll
    for (int dt = 0; dt < 4; dt++)
#pragma unroll
        for (int reg = 0; reg < 4; reg++) mine[dt * 4 + reg] = Oa[dt][reg];
#pragma unroll
    for (int reg = 0; reg < 4; reg++) { mine[16 + reg] = mrun[reg]; mine[20 + reg] = lrun[reg]; }
    __syncthreads();
    if (sp == 0) {
        const float* p[4];
#pragma unroll
        for (int j = 0; j < 4; j++) p[j] = OL + (size_t)((qg + 2 * j) * 64 + lane) * 25;
        float e[4][4], li[4];
#pragma unroll
        for (int reg = 0; reg < 4; reg++) {
            float M = fmaxf(fmaxf(p[0][16 + reg], p[1][16 + reg]),
                            fmaxf(p[2][16 + reg], p[3][16 + reg]));
            float L = 0.f;
#pragma unroll
            for (int j = 0; j < 4; j++) {
                e[j][reg] = exp2f(p[j][16 + reg] - M);
                L += p[j][20 + reg] * e[j][reg];
            }
            li[reg] = 1.f / L;
        }
#pragma unroll
        for (int dt = 0; dt < 4; dt++)
#pragma unroll
            for (int reg = 0; reg < 4; reg++) {
                float val = 0.f;
#pragma unroll
                for (int j = 0; j < 4; j++) val += p[j][dt * 4 + reg] * e[j][reg];
                val *= li[reg];
                int n = row0 + quad * 4 + reg;
                int col = h * 64 + dt * 16 + l15;
                xattn[((size_t)bb * NN + n) * DD + col] = f2bf(val);
            }
    }
}

// ---------------- conv1: M=4096, N=512, K=512 (x|attn); 64x64 tiles + BN stats -------
__global__ __launch_bounds__(256) void conv1_kernel(
    const unsigned short* __restrict__ xbf, const unsigned short* __restrict__ xattn,
    const unsigned short* __restrict__ W1_l, const unsigned short* __restrict__ W1m_l,
    const float* __restrict__ bmix_l,
    unsigned short* __restrict__ out1, float* __restrict__ bnsumm) {
    __shared__ __align__(16) unsigned short sm[8192];
    unsigned short* Al = sm;
    unsigned short* Bl = sm + 4096;

    int m0 = blockIdx.x * 64, o0 = blockIdx.y * 64;
    int bb = m0 >> 10, nloc0 = m0 & 1023;
    const unsigned short* A1 = xbf + (size_t)bb * NN * DD + (size_t)nloc0 * DD;
    const unsigned short* A2 = xattn + (size_t)bb * NN * DD + (size_t)nloc0 * DD;

    int tid = threadIdx.x, w = tid >> 6, lane = tid & 63, quad = lane >> 4, l15 = lane & 15;
    int wrow = (w & 1) * 32, wcol = (w >> 1) * 32;
    int lrow = lane >> 3, lcol = (lane & 7) * 8;

    f32x4 acc[2][2];
#pragma unroll
    for (int r = 0; r < 2; r++)
#pragma unroll
        for (int c = 0; c < 2; c++) acc[r][c] = (f32x4){0.f, 0.f, 0.f, 0.f};

    for (int ks = 0; ks < 8; ks++) {
        const unsigned short* As = (ks < 4) ? A1 : A2;
        int kloc = (ks & 3) * 64;
        __syncthreads();
#pragma unroll
        for (int j = 0; j < 2; j++)
            gll16(As + (size_t)(w * 16 + j * 8 + lrow) * DD + kloc + lcol, Al + (w * 16 + j * 8) * 64);
#pragma unroll
        for (int j = 0; j < 2; j++) {
            int orow = o0 + w * 16 + j * 8 + lrow;
            const unsigned short* bg = (ks < 4)
                ? (W1_l + (size_t)orow * 512 + ks * 64 + lcol)
                : (W1m_l + (size_t)orow * 256 + (ks - 4) * 64 + lcol);
            gll16(bg, Bl + (w * 16 + j * 8) * 64);
        }
        __syncthreads();
#pragma unroll
        for (int kh = 0; kh < 2; kh++) {
            bf16x8 bf[2], af[2];
#pragma unroll
            for (int cs = 0; cs < 2; cs++)
                bf[cs] = *(const bf16x8*)(Bl + (wcol + cs * 16 + l15) * 64 + kh * 32 + quad * 8);
#pragma unroll
            for (int rs = 0; rs < 2; rs++)
                af[rs] = *(const bf16x8*)(Al + (wrow + rs * 16 + l15) * 64 + kh * 32 + quad * 8);
#pragma unroll
            for (int rs = 0; rs < 2; rs++)
#pragma unroll
                for (int cs = 0; cs < 2; cs++)
                    acc[rs][cs] = mfma16(af[rs], bf[cs], acc[rs][cs]);
        }
    }
    __syncthreads();
    float cs_s[2] = {0.f, 0.f}, cs_q[2] = {0.f, 0.f};
#pragma unroll
    for (int rs = 0; rs < 2; rs++)
#pragma unroll
        for (int cs = 0; cs < 2; cs++) {
            int o = o0 + wcol + cs * 16 + l15;
            float bvx = bmix_l[o];
#pragma unroll
            for (int reg = 0; reg < 4; reg++) {
                float val = acc[rs][cs][reg] + bvx;
                sm[(wrow + rs * 16 + quad * 4 + reg) * 72 + wcol + cs * 16 + l15] = f2bf(val);
                cs_s[cs] += val;
                cs_q[cs] += val * val;
            }
        }
#pragma unroll
    for (int cs = 0; cs < 2; cs++) {
        cs_s[cs] += __shfl_xor(cs_s[cs], 16, 64);
        cs_s[cs] += __shfl_xor(cs_s[cs], 32, 64);
        cs_q[cs] += __shfl_xor(cs_q[cs], 16, 64);
        cs_q[cs] += __shfl_xor(cs_q[cs], 32, 64);
    }
    if (lane < 16) {
#pragma unroll
        for (int cs = 0; cs < 2; cs++) {
            atomicAdd(&bnsumm[o0 + wcol + cs * 16 + lane], cs_s[cs]);
            atomicAdd(&bnsumm[512 + o0 + wcol + cs * 16 + lane], cs_q[cs]);
        }
    }
    __syncthreads();
    int r = tid >> 2, ch = (tid & 3) * 16;
    unsigned short* dst = out1 + ((size_t)(bb * NN) + nloc0 + r) * 512 + o0 + ch;
    *(bf16x8*)(dst) = *(const bf16x8*)(&sm[r * 72 + ch]);
    *(bf16x8*)(dst + 8) = *(const bf16x8*)(&sm[r * 72 + ch + 8]);
}

// ---------------- bnrelu: y = relu(sc*out1 + sh) -> bf16 (BN finalize inlined) --------
__global__ __launch_bounds__(256) void bnrelu_kernel(
    const unsigned short* __restrict__ out1, const float* __restrict__ bnsumm,
    const float* __restrict__ g1_l, const float* __restrict__ beta1_l,
    unsigned short* __restrict__ ybf) {
    int idx = blockIdx.x * 256 + threadIdx.x;
    int base = idx * 8;
    int o = base & 511;
    union { bf16x8 v; unsigned short u[8]; } in, op;
    in.v = *(const bf16x8*)(out1 + base);
#pragma unroll
    for (int j = 0; j < 8; j++) {
        int ch = o + j;
        float s = bnsumm[ch], s2 = bnsumm[512 + ch];
        float mean = s * (1.f / 4096.f);
        float var = s2 * (1.f / 4096.f) - mean * mean;
        float sc = g1_l[ch] * rsqrtf(var + 1e-5f);
        float sh = beta1_l[ch] - mean * sc;
        op.u[j] = f2bf(fmaxf(0.f, bf2f(in.u[j]) * sc + sh));
    }
    *(bf16x8*)(ybf + base) = op.v;
}

// ---------------- conv2: pure GEMM M=4096, N=256, K=512; 32x64 tiles, LDS staging -----
__global__ __launch_bounds__(256) void conv2_kernel(
    const unsigned short* __restrict__ ybf, const unsigned short* __restrict__ W2_l,
    const float* __restrict__ b2_l, float* __restrict__ desc,
    unsigned short* __restrict__ xbf) {
    __shared__ __align__(16) unsigned short sm[6144];
    unsigned short* Al = sm;
    unsigned short* Bl = sm + 2048;

    int m0 = blockIdx.x * 32, o0 = blockIdx.y * 64;
    int bb = m0 >> 10, nloc0 = m0 & 1023;
    const unsigned short* A = ybf + ((size_t)(bb * NN) + nloc0) * 512;

    int tid = threadIdx.x, w = tid >> 6, lane = tid & 63, quad = lane >> 4, l15 = lane & 15;
    int wr = (w & 1) * 16, wc = (w >> 1) * 32;
    int lrow = lane >> 3, lcol = (lane & 7) * 8;

    f32x4 acc[2];
    acc[0] = (f32x4){0.f, 0.f, 0.f, 0.f};
    acc[1] = (f32x4){0.f, 0.f, 0.f, 0.f};

    for (int ks = 0; ks < 8; ks++) {
        int k0 = ks * 64;
        __syncthreads();
        gll16(A + (size_t)(w * 8 + lrow) * 512 + k0 + lcol, Al + (w * 8) * 64);
#pragma unroll
        for (int j = 0; j < 2; j++)
            gll16(W2_l + (size_t)(o0 + w * 16 + j * 8 + lrow) * 512 + k0 + lcol,
                  Bl + (w * 16 + j * 8) * 64);
        __syncthreads();
#pragma unroll
        for (int kh = 0; kh < 2; kh++) {
            bf16x8 af = *(const bf16x8*)(Al + (wr + l15) * 64 + kh * 32 + quad * 8);
#pragma unroll
            for (int cs = 0; cs < 2; cs++) {
                bf16x8 bf = *(const bf16x8*)(Bl + (wc + cs * 16 + l15) * 64 + kh * 32 + quad * 8);
                acc[cs] = mfma16(af, bf, acc[cs]);
            }
        }
    }
#pragma unroll
    for (int cs = 0; cs < 2; cs++)
#pragma unroll
        for (int reg = 0; reg < 4; reg++) {
            int n = nloc0 + wr + quad * 4 + reg;
            int o = o0 + wc + cs * 16 + l15;
            size_t di = ((size_t)bb * NN + n) * DD + o;
            float nd = desc[di] + acc[cs][reg] + b2_l[o];
            desc[di] = nd;
            xbf[di] = f2bf(nd);
        }
}

extern "C" void kernel_launch(void* const* d_in, const int* in_sizes, int n_in,
                              void* d_out, int out_size, void* d_ws, size_t ws_size,
                              hipStream_t stream) {
    const float* desc0 = (const float*)d_in[0];
    const float* desc1 = (const float*)d_in[1];
    const float* M0p   = (const float*)d_in[2];
    const float* M1p   = (const float*)d_in[3];
    const float* Wq = (const float*)d_in[4];  const float* bq = (const float*)d_in[5];
    const float* Wk = (const float*)d_in[6];  const float* bk = (const float*)d_in[7];
    const float* Wv = (const float*)d_in[8];  const float* bv = (const float*)d_in[9];
    const float* Wm = (const float*)d_in[10]; const float* bm = (const float*)d_in[11];
    const float* W1 = (const float*)d_in[12]; const float* b1 = (const float*)d_in[13];
    const float* g1 = (const float*)d_in[14]; const float* beta1 = (const float*)d_in[15];
    const float* W2 = (const float*)d_in[16]; const float* b2 = (const float*)d_in[17];
    float* out = (float*)d_out;
    char* ws = (char*)d_ws;

    float*          desc   = (float*)(ws);
    unsigned short* xbf    = (unsigned short*)(ws + (4ull << 20));
    unsigned short* qb     = (unsigned short*)(ws + (6ull << 20));
    unsigned short* kbuf   = (unsigned short*)(ws + (8ull << 20));
    unsigned short* vbuf   = (unsigned short*)(ws + (10ull << 20));
    unsigned short* xattn  = (unsigned short*)(ws + (12ull << 20));
    unsigned short* out1   = (unsigned short*)(ws + (14ull << 20));
    float*          bnsumm = (float*)(ws + (18ull << 20));
    float*          bmix   = (float*)(ws + (18ull << 20) + 8192);
    unsigned short* maskbf = (unsigned short*)(ws + (19ull << 20));
    unsigned short* W1m    = (unsigned short*)(ws + (27ull << 20));
    unsigned short* wbf    = (unsigned short*)(ws + (29ull << 20));
    unsigned short* ybf    = (unsigned short*)(ws + (37ull << 20));

    const int SQ = LL * 65536;

    prep_kernel<<<9728, 256, 0, stream>>>(desc0, desc1, M0p, M1p, Wq, Wk, Wv, Wm,
                                          W1, W2, bm, b1, wbf, maskbf, bmix, desc, xbf);
    fold1_kernel<<<dim3(8, 4, 6), 256, 0, stream>>>(wbf + 4 * (size_t)SQ, wbf + 3 * (size_t)SQ, W1m);

    for (int l = 0; l < LL; l++) {
        int cross = l & 1;
        const unsigned short* Wq_l = wbf + (size_t)l * 65536;
        const unsigned short* Wk_l = wbf + SQ + (size_t)l * 65536;
        const unsigned short* Wv_l = wbf + 2 * (size_t)SQ + (size_t)l * 65536;
        const unsigned short* W1_l = wbf + 4 * (size_t)SQ + (size_t)l * 262144;
        const unsigned short* W2_l = wbf + 4 * (size_t)SQ + (size_t)LL * 262144 + (size_t)l * 131072;
        const unsigned short* W1m_l = W1m + (size_t)l * 131072;

        proj_kernel<<<dim3(64, 12), 256, 0, stream>>>(
            xbf, Wq_l, Wk_l, Wv_l, bq + l * 256, bk + l * 256, bv + l * 256,
            qb, kbuf, vbuf, cross);
        flash_kernel<<<dim3(32, 16), 512, 0, stream>>>(qb, kbuf, vbuf, maskbf, xattn, bnsumm);
        conv1_kernel<<<dim3(64, 8), 256, 0, stream>>>(
            xbf, xattn, W1_l, W1m_l, bmix + l * 512, out1, bnsumm);
        bnrelu_kernel<<<1024, 256, 0, stream>>>(out1, bnsumm, g1 + l * 512, beta1 + l * 512, ybf);
        conv2_kernel<<<dim3(128, 4), 256, 0, stream>>>(
            ybf, W2_l, b2 + l * 256, desc, xbf);
    }

    final_kernel<<<dim3(32, 8, 4), 256, 0, stream>>>(desc, out);
}

// Round 12
// 465.769 us; speedup vs baseline: 1.1542x; 1.1181x over previous
//
#include <hip/hip_runtime.h>
#include <hip/hip_bf16.h>

#define NN 1024
#define DD 256
#define LL 6

typedef __attribute__((ext_vector_type(8))) short bf16x8;
typedef __attribute__((ext_vector_type(4))) float f32x4;
typedef __attribute__((ext_vector_type(4))) unsigned short u16x4;

__device__ __forceinline__ unsigned short f2bf(float f) {
    union { float f; unsigned u; } x; x.f = f;
    return (unsigned short)((x.u + 0x7fffu + ((x.u >> 16) & 1u)) >> 16);
}

__device__ __forceinline__ unsigned short f2bf_trunc(float f) {
    union { float f; unsigned u; } x; x.f = f;
    return (unsigned short)(x.u >> 16);
}

__device__ __forceinline__ float bf2f(unsigned short u) {
    union { unsigned u; float f; } x; x.u = ((unsigned)u) << 16; return x.f;
}

__device__ __forceinline__ f32x4 mfma16(bf16x8 a, bf16x8 b, f32x4 c) {
    return __builtin_amdgcn_mfma_f32_16x16x32_bf16(a, b, c, 0, 0, 0);
}

// async global->LDS, 16B per lane; lds dest = wave-uniform base + lane*16
__device__ __forceinline__ void gll16(const unsigned short* g, unsigned short* l) {
    __builtin_amdgcn_global_load_lds(
        (const __attribute__((address_space(1))) unsigned int*)g,
        (__attribute__((address_space(3))) unsigned int*)l, 16, 0, 0);
}

// ---------------- prep: wconv(vec4) | maskconv | fold2 | init, block-partitioned ------
__global__ __launch_bounds__(256) void prep_kernel(
    const float* __restrict__ desc0, const float* __restrict__ desc1,
    const float* __restrict__ M0, const float* __restrict__ M1,
    const float* __restrict__ Wq, const float* __restrict__ Wk,
    const float* __restrict__ Wv, const float* __restrict__ Wm,
    const float* __restrict__ W1, const float* __restrict__ W2,
    const float* __restrict__ bm, const float* __restrict__ b1,
    unsigned short* __restrict__ wbf, unsigned short* __restrict__ maskbf,
    float* __restrict__ bmix, float* __restrict__ desc, unsigned short* __restrict__ xbf) {
    __shared__ float T[32][33];
    const int SQ = LL * 65536;
    const int S1 = LL * 262144;
    int blk = blockIdx.x, tid = threadIdx.x;
    if (blk < 3840) {
        int idx = blk * 256 + tid;
        size_t base = (size_t)idx * 4;
        f32x4 v;
        if (base < (size_t)4 * SQ) {
            int seg = (int)(base / SQ), off = (int)(base % SQ);
            const float* p = (seg == 0) ? Wq : (seg == 1) ? Wk : (seg == 2) ? Wv : Wm;
            if (seg < 3) {
                int l = off >> 16, rem = off & 65535;
                int op = rem >> 8, i = rem & 255;
                int src = ((op & 63) << 2) | (op >> 6);
                v = *(const f32x4*)(p + (size_t)l * 65536 + (size_t)src * 256 + i);
            } else {
                v = *(const f32x4*)(p + off);
            }
        } else if (base < (size_t)4 * SQ + S1) {
            v = *(const f32x4*)(W1 + base - 4 * SQ);
        } else {
            v = *(const f32x4*)(W2 + base - 4 * SQ - S1);
        }
        u16x4 o;
#pragma unroll
        for (int j = 0; j < 4; j++) o[j] = f2bf(v[j]);
        *(u16x4*)(wbf + base) = o;
    } else if (blk < 7936) {
        int idx = (blk - 3840) * 256 + tid;
        size_t base = (size_t)idx * 4;
        int bb = (int)(base >> 20);
        const float* src = (bb < 2) ? (M0 + base) : (M1 + base - (2ull << 20));
        f32x4 v = *(const f32x4*)src;
        u16x4 o;
#pragma unroll
        for (int j = 0; j < 4; j++) o[j] = f2bf(v[j]);
        *(u16x4*)(maskbf + base) = o;
    } else if (blk < 8704) {
        int lane = tid & 63;
        int wid = (blk - 7936) * 4 + (tid >> 6);
        int l = wid >> 9, o = wid & 511;
        const float* row = W1 + ((size_t)l * 512 + o) * 512 + 256;
        const float* bmr = bm + (size_t)l * 256;
        f32x4 r = *(const f32x4*)(row + lane * 4);
        f32x4 b4 = *(const f32x4*)(bmr + lane * 4);
        float acc = r[0] * b4[0] + r[1] * b4[1] + r[2] * b4[2] + r[3] * b4[3];
        acc += __shfl_xor(acc, 1, 64);
        acc += __shfl_xor(acc, 2, 64);
        acc += __shfl_xor(acc, 4, 64);
        acc += __shfl_xor(acc, 8, 64);
        acc += __shfl_xor(acc, 16, 64);
        acc += __shfl_xor(acc, 32, 64);
        if (lane == 0) bmix[wid] = b1[wid] + acc;
    } else {
        int task = blk - 8704;
        int bb = task >> 8, tt = task & 255;
        int n0 = (tt >> 3) * 32, c0 = (tt & 7) * 32;
        const float* src = (bb < 2) ? (desc0 + (size_t)bb * DD * NN)
                                    : (desc1 + (size_t)(bb - 2) * DD * NN);
        int i = tid >> 5, j = tid & 31;
#pragma unroll
        for (int r = 0; r < 4; r++) {
            int c = i + r * 8;
            T[c][j] = src[(size_t)(c0 + c) * NN + n0 + j];
        }
        __syncthreads();
#pragma unroll
        for (int r = 0; r < 4; r++) {
            int n = i + r * 8;
            float v = T[j][n];
            size_t di = ((size_t)bb * NN + n0 + n) * DD + c0 + j;
            desc[di] = v;
            xbf[di] = f2bf(v);
        }
    }
}

// ---------------- fold1 (MFMA, bf16 inputs): W1m_perm[l][o][h*64+d] ----------------
__global__ __launch_bounds__(256) void fold1_kernel(const unsigned short* __restrict__ W1bf,
                                                    const unsigned short* __restrict__ Wmbf,
                                                    unsigned short* __restrict__ W1m) {
    int l = blockIdx.z;
    int o0 = blockIdx.x * 64, i0 = blockIdx.y * 64;
    const unsigned short* A = W1bf + (size_t)l * 262144;
    const unsigned short* B = Wmbf + (size_t)l * 65536;
    __shared__ unsigned short Bt[64][264];
    int t = threadIdx.x;
#pragma unroll
    for (int r = 0; r < 8; r++) {
        int j = r * 32 + (t >> 3);
        int il = (t & 7) * 8;
        union { bf16x8 v; unsigned short u[8]; } ld;
        ld.v = *(const bf16x8*)(B + (size_t)j * 256 + i0 + il);
#pragma unroll
        for (int jj = 0; jj < 8; jj++) Bt[il + jj][j] = ld.u[jj];
    }
    __syncthreads();
    int w = t >> 6, lane = t & 63, quad = lane >> 4, l15 = lane & 15;
    int wr = (w & 1) * 32, wc = (w >> 1) * 32;
    const unsigned short* Ab = A + (size_t)(o0 + wr + l15) * 512 + 256 + quad * 8;
    f32x4 acc[2][2];
#pragma unroll
    for (int r = 0; r < 2; r++)
#pragma unroll
        for (int c = 0; c < 2; c++) acc[r][c] = (f32x4){0.f, 0.f, 0.f, 0.f};
#pragma unroll
    for (int s = 0; s < 8; s++) {
        int kk = s * 32;
        bf16x8 a0 = *(const bf16x8*)(Ab + kk);
        bf16x8 a1 = *(const bf16x8*)(Ab + 16 * 512 + kk);
        bf16x8 b0 = *(const bf16x8*)(&Bt[wc + l15][kk + quad * 8]);
        bf16x8 b1 = *(const bf16x8*)(&Bt[wc + 16 + l15][kk + quad * 8]);
        acc[0][0] = mfma16(a0, b0, acc[0][0]);
        acc[0][1] = mfma16(a0, b1, acc[0][1]);
        acc[1][0] = mfma16(a1, b0, acc[1][0]);
        acc[1][1] = mfma16(a1, b1, acc[1][1]);
    }
#pragma unroll
    for (int rs = 0; rs < 2; rs++)
#pragma unroll
        for (int cs = 0; cs < 2; cs++)
#pragma unroll
            for (int reg = 0; reg < 4; reg++) {
                int o = o0 + wr + rs * 16 + quad * 4 + reg;
                int i = i0 + wc + cs * 16 + l15;
                int pc = (i & 3) * 64 + (i >> 2);
                W1m[((size_t)l * 512 + o) * 256 + pc] = f2bf(acc[rs][cs][reg]);
            }
}

// ---------------- final: [4][1024][256] -> [4][256][1024] via LDS tiles ----------------
__global__ __launch_bounds__(256) void final_kernel(const float* __restrict__ desc,
                                                    float* __restrict__ out) {
    __shared__ float T[32][33];
    int bb = blockIdx.z;
    int n0 = blockIdx.x * 32, c0 = blockIdx.y * 32;
    int i = threadIdx.x >> 5, j = threadIdx.x & 31;
#pragma unroll
    for (int r = 0; r < 4; r++) {
        int n = i + r * 8;
        T[n][j] = desc[((size_t)bb * NN + n0 + n) * DD + c0 + j];
    }
    __syncthreads();
#pragma unroll
    for (int r = 0; r < 4; r++) {
        int c = i + r * 8;
        out[((size_t)bb * DD + c0 + c) * NN + n0 + j] = T[j][c];
    }
}

// ---------------- proj: M=4096, N=768 (q|k|v), K=256; 64x64 tiles, LDS staging --------
__global__ __launch_bounds__(256) void proj_kernel(
    const unsigned short* __restrict__ xbf,
    const unsigned short* __restrict__ Wq_l, const unsigned short* __restrict__ Wk_l,
    const unsigned short* __restrict__ Wv_l,
    const float* __restrict__ bq_l, const float* __restrict__ bk_l,
    const float* __restrict__ bv_l,
    unsigned short* __restrict__ qb, unsigned short* __restrict__ kb,
    unsigned short* __restrict__ vb, int cross) {
    __shared__ __align__(16) unsigned short sm[8192];
    unsigned short* Al = sm;
    unsigned short* Bl = sm + 4096;

    int m0 = blockIdx.x * 64;
    int by = blockIdx.y;
    int mat = by >> 2;
    int o0c = (by & 3) * 64;
    int bb = m0 >> 10, nloc0 = m0 & 1023;
    int srcbb = (mat == 0) ? bb : (cross ? (bb ^ 2) : bb);
    const unsigned short* A = xbf + (size_t)srcbb * NN * DD + (size_t)nloc0 * DD;
    const unsigned short* W = ((mat == 0) ? Wq_l : (mat == 1) ? Wk_l : Wv_l) + (size_t)o0c * DD;
    const float* bias = (mat == 0) ? bq_l : (mat == 1) ? bk_l : bv_l;

    int tid = threadIdx.x, w = tid >> 6, lane = tid & 63, quad = lane >> 4, l15 = lane & 15;
    int wrow = (w & 1) * 32, wcol = (w >> 1) * 32;
    int lrow = lane >> 3, lcol = (lane & 7) * 8;

    f32x4 acc[2][2];
#pragma unroll
    for (int r = 0; r < 2; r++)
#pragma unroll
        for (int c = 0; c < 2; c++) acc[r][c] = (f32x4){0.f, 0.f, 0.f, 0.f};

    for (int ks = 0; ks < 4; ks++) {
        int k0 = ks * 64;
        __syncthreads();
#pragma unroll
        for (int j = 0; j < 2; j++)
            gll16(A + (size_t)(w * 16 + j * 8 + lrow) * DD + k0 + lcol, Al + (w * 16 + j * 8) * 64);
#pragma unroll
        for (int j = 0; j < 2; j++)
            gll16(W + (size_t)(w * 16 + j * 8 + lrow) * DD + k0 + lcol, Bl + (w * 16 + j * 8) * 64);
        __syncthreads();
#pragma unroll
        for (int kh = 0; kh < 2; kh++) {
            bf16x8 bf[2], af[2];
#pragma unroll
            for (int cs = 0; cs < 2; cs++)
                bf[cs] = *(const bf16x8*)(Bl + (wcol + cs * 16 + l15) * 64 + kh * 32 + quad * 8);
#pragma unroll
            for (int rs = 0; rs < 2; rs++)
                af[rs] = *(const bf16x8*)(Al + (wrow + rs * 16 + l15) * 64 + kh * 32 + quad * 8);
#pragma unroll
            for (int rs = 0; rs < 2; rs++)
#pragma unroll
                for (int cs = 0; cs < 2; cs++)
                    acc[rs][cs] = mfma16(af[rs], bf[cs], acc[rs][cs]);
        }
    }
    __syncthreads();
    float qscale = (mat == 0) ? 0.1803368801f : 1.0f;   // 0.125 * log2(e) for q
    if (mat < 2) {
#pragma unroll
        for (int rs = 0; rs < 2; rs++)
#pragma unroll
            for (int cs = 0; cs < 2; cs++) {
                int op = o0c + wcol + cs * 16 + l15;
                float bv4 = bias[((op & 63) << 2) | (op >> 6)];
#pragma unroll
                for (int reg = 0; reg < 4; reg++)
                    sm[(wrow + rs * 16 + quad * 4 + reg) * 72 + wcol + cs * 16 + l15] =
                        f2bf((acc[rs][cs][reg] + bv4) * qscale);
            }
        __syncthreads();
        int r = tid >> 2, ch = (tid & 3) * 16;
        unsigned short* dst = ((mat == 0) ? qb : kb) + ((size_t)(bb * NN) + nloc0 + r) * 256 + o0c + ch;
        *(bf16x8*)(dst) = *(const bf16x8*)(&sm[r * 72 + ch]);
        *(bf16x8*)(dst + 8) = *(const bf16x8*)(&sm[r * 72 + ch + 8]);
    } else {
#pragma unroll
        for (int rs = 0; rs < 2; rs++)
#pragma unroll
            for (int cs = 0; cs < 2; cs++) {
                int op = o0c + wcol + cs * 16 + l15;
                float bv4 = bias[((op & 63) << 2) | (op >> 6)];
#pragma unroll
                for (int reg = 0; reg < 4; reg++)
                    sm[(wcol + cs * 16 + l15) * 72 + wrow + rs * 16 + quad * 4 + reg] =
                        f2bf(acc[rs][cs][reg] + bv4);
            }
        __syncthreads();
        int o = tid >> 2, nch = (tid & 3) * 16;
        int opg = o0c + o;
        unsigned short* dst = vb + ((size_t)(bb * 4 + (opg >> 6)) * 64 + (opg & 63)) * NN + nloc0 + nch;
        *(bf16x8*)(dst) = *(const bf16x8*)(&sm[o * 72 + nch]);
        *(bf16x8*)(dst + 8) = *(const bf16x8*)(&sm[o * 72 + nch + 8]);
    }
}

// ---------------- flash: 4 waves/block, wave = m-split, 2 q-groups per wave -----------
// Each K/V fragment load feeds 2 MFMAs (both q-groups) -> 2:1 MFMA:load density,
// K/V L2 traffic halved vs 8-wave version.
__global__ __launch_bounds__(256, 2) void flash_kernel(
    const unsigned short* __restrict__ qb, const unsigned short* __restrict__ kb,
    const unsigned short* __restrict__ vb,
    const unsigned short* __restrict__ maskbf,
    unsigned short* __restrict__ xattn, float* __restrict__ bnsumm) {
    __shared__ __align__(16) char smem[51200];
    unsigned short* Plds = (unsigned short*)smem;   // phase 1: [4][16][72] per-wave
    float* OL = (float*)smem;                        // phase 2: [8][64][25]

    int bh = blockIdx.y, nb = blockIdx.x;
    int bb = bh >> 2, h = bh & 3;
    int tid = threadIdx.x, w = tid >> 6, lane = tid & 63, quad = lane >> 4, l15 = lane & 15;

    if (nb == 0 && bh == 0) {
        bnsumm[tid] = 0.f; bnsumm[tid + 256] = 0.f;
        bnsumm[tid + 512] = 0.f; bnsumm[tid + 768] = 0.f;
    }

    const unsigned short* mask = maskbf + (size_t)bb * NN * NN;
    const unsigned short* Q = qb + (size_t)bb * NN * 256 + h * 64;
    const unsigned short* Kb = kb + (size_t)bb * NN * 256 + h * 64;
    const unsigned short* Vb = vb + (size_t)bh * 64 * NN;
    int row0 = nb * 32;

    bf16x8 qf[2][2];
#pragma unroll
    for (int s = 0; s < 2; s++)
#pragma unroll
        for (int kc = 0; kc < 2; kc++)
            qf[s][kc] = *(const bf16x8*)(Q + (size_t)(row0 + s * 16 + l15) * 256 + kc * 32 + quad * 8);

    const unsigned short* mrow[2][4];
#pragma unroll
    for (int s = 0; s < 2; s++)
#pragma unroll
        for (int reg = 0; reg < 4; reg++)
            mrow[s][reg] = mask + (size_t)(row0 + s * 16 + quad * 4 + reg) * NN + w * 256;

    f32x4 Oa[2][4];
#pragma unroll
    for (int s = 0; s < 2; s++)
#pragma unroll
        for (int dt = 0; dt < 4; dt++) Oa[s][dt] = (f32x4){0.f, 0.f, 0.f, 0.f};
    float mrun[2][4], lrun[2][4];
#pragma unroll
    for (int s = 0; s < 2; s++)
#pragma unroll
        for (int r = 0; r < 4; r++) { mrun[s][r] = -1e30f; lrun[s][r] = 0.f; }

    unsigned short* Pw = Plds + w * (16 * 72);

    for (int mt = 0; mt < 4; mt++) {
        int ml = mt * 64;
        int m0 = w * 256 + ml;
        // QK^T for both q-groups off one K-fragment stream
        f32x4 sA[4], sB[4];
#pragma unroll
        for (int t = 0; t < 4; t++) {
            sA[t] = (f32x4){0.f, 0.f, 0.f, 0.f};
            sB[t] = (f32x4){0.f, 0.f, 0.f, 0.f};
        }
#pragma unroll
        for (int t = 0; t < 4; t++)
#pragma unroll
            for (int kc = 0; kc < 2; kc++) {
                bf16x8 kf = *(const bf16x8*)(Kb + (size_t)(m0 + t * 16 + l15) * 256 + kc * 32 + quad * 8);
                sA[t] = mfma16(qf[0][kc], kf, sA[t]);
                sB[t] = mfma16(qf[1][kc], kf, sB[t]);
            }
        bf16x8 vf[8];
#pragma unroll
        for (int dt = 0; dt < 4; dt++)
#pragma unroll
            for (int kc = 0; kc < 2; kc++)
                vf[dt * 2 + kc] = *(const bf16x8*)(Vb + (size_t)(dt * 16 + l15) * NN + m0 + kc * 32 + quad * 8);
        // per-q-group softmax + PV (sequential; set B's VALU overlaps set A's MFMAs)
#pragma unroll
        for (int s = 0; s < 2; s++) {
            float sv[4][4], rmax[4];
#pragma unroll
            for (int r = 0; r < 4; r++) rmax[r] = -1e30f;
#pragma unroll
            for (int t = 0; t < 4; t++)
#pragma unroll
                for (int reg = 0; reg < 4; reg++) {
                    float sc = (s == 0) ? sA[t][reg] : sB[t][reg];
                    float v = sc * bf2f(mrow[s][reg][ml + t * 16 + l15]);
                    sv[t][reg] = v;
                    rmax[reg] = fmaxf(rmax[reg], v);
                }
#pragma unroll
            for (int reg = 0; reg < 4; reg++) {
                rmax[reg] = fmaxf(rmax[reg], __shfl_xor(rmax[reg], 1, 64));
                rmax[reg] = fmaxf(rmax[reg], __shfl_xor(rmax[reg], 2, 64));
                rmax[reg] = fmaxf(rmax[reg], __shfl_xor(rmax[reg], 4, 64));
                rmax[reg] = fmaxf(rmax[reg], __shfl_xor(rmax[reg], 8, 64));
            }
            float alpha[4], rsum[4];
#pragma unroll
            for (int reg = 0; reg < 4; reg++) {
                float mn = fmaxf(mrun[s][reg], rmax[reg]);
                alpha[reg] = exp2f(mrun[s][reg] - mn);
                mrun[s][reg] = mn;
                rsum[reg] = 0.f;
            }
#pragma unroll
            for (int t = 0; t < 4; t++)
#pragma unroll
                for (int reg = 0; reg < 4; reg++) {
                    float p = exp2f(sv[t][reg] - mrun[s][reg]);
                    sv[t][reg] = p;
                    rsum[reg] += p;
                }
#pragma unroll
            for (int reg = 0; reg < 4; reg++) {
                rsum[reg] += __shfl_xor(rsum[reg], 1, 64);
                rsum[reg] += __shfl_xor(rsum[reg], 2, 64);
                rsum[reg] += __shfl_xor(rsum[reg], 4, 64);
                rsum[reg] += __shfl_xor(rsum[reg], 8, 64);
                lrun[s][reg] = lrun[s][reg] * alpha[reg] + rsum[reg];
            }
#pragma unroll
            for (int dt = 0; dt < 4; dt++)
#pragma unroll
                for (int reg = 0; reg < 4; reg++) Oa[s][dt][reg] *= alpha[reg];
            // P C->A layout via per-wave LDS slice (in-wave reuse across sets is ordered)
#pragma unroll
            for (int t = 0; t < 4; t++)
#pragma unroll
                for (int reg = 0; reg < 4; reg++)
                    Pw[(quad * 4 + reg) * 72 + t * 16 + l15] = f2bf_trunc(sv[t][reg]);
            bf16x8 pf[2];
#pragma unroll
            for (int kc = 0; kc < 2; kc++)
                pf[kc] = *(const bf16x8*)(Pw + l15 * 72 + kc * 32 + quad * 8);
#pragma unroll
            for (int dt = 0; dt < 4; dt++)
#pragma unroll
                for (int kc = 0; kc < 2; kc++)
                    Oa[s][dt] = mfma16(pf[kc], vf[dt * 2 + kc], Oa[s][dt]);
        }
    }
    __syncthreads();   // phase change: Plds -> OL
#pragma unroll
    for (int s = 0; s < 2; s++) {
        float* mine = OL + (size_t)((s + 2 * w) * 64 + lane) * 25;
#pragma unroll
        for (int dt = 0; dt < 4; dt++)
#pragma unroll
            for (int reg = 0; reg < 4; reg++) mine[dt * 4 + reg] = Oa[s][dt][reg];
#pragma unroll
        for (int reg = 0; reg < 4; reg++) { mine[16 + reg] = mrun[s][reg]; mine[20 + reg] = lrun[s][reg]; }
    }
    __syncthreads();
    if (w < 2) {   // wave w merges q-group w
        const float* p[4];
#pragma unroll
        for (int j = 0; j < 4; j++) p[j] = OL + (size_t)((w + 2 * j) * 64 + lane) * 25;
        float e[4][4], li[4];
#pragma unroll
        for (int reg = 0; reg < 4; reg++) {
            float M = fmaxf(fmaxf(p[0][16 + reg], p[1][16 + reg]),
                            fmaxf(p[2][16 + reg], p[3][16 + reg]));
            float L = 0.f;
#pragma unroll
            for (int j = 0; j < 4; j++) {
                e[j][reg] = exp2f(p[j][16 + reg] - M);
                L += p[j][20 + reg] * e[j][reg];
            }
            li[reg] = 1.f / L;
        }
#pragma unroll
        for (int dt = 0; dt < 4; dt++)
#pragma unroll
            for (int reg = 0; reg < 4; reg++) {
                float val = 0.f;
#pragma unroll
                for (int j = 0; j < 4; j++) val += p[j][dt * 4 + reg] * e[j][reg];
                val *= li[reg];
                int n = row0 + w * 16 + quad * 4 + reg;
                int col = h * 64 + dt * 16 + l15;
                xattn[((size_t)bb * NN + n) * DD + col] = f2bf(val);
            }
    }
}

// ---------------- conv1: M=4096, N=512, K=512 (x|attn); 64x64 tiles + BN stats -------
__global__ __launch_bounds__(256) void conv1_kernel(
    const unsigned short* __restrict__ xbf, const unsigned short* __restrict__ xattn,
    const unsigned short* __restrict__ W1_l, const unsigned short* __restrict__ W1m_l,
    const float* __restrict__ bmix_l,
    unsigned short* __restrict__ out1, float* __restrict__ bnsumm) {
    __shared__ __align__(16) unsigned short sm[8192];
    unsigned short* Al = sm;
    unsigned short* Bl = sm + 4096;

    int m0 = blockIdx.x * 64, o0 = blockIdx.y * 64;
    int bb = m0 >> 10, nloc0 = m0 & 1023;
    const unsigned short* A1 = xbf + (size_t)bb * NN * DD + (size_t)nloc0 * DD;
    const unsigned short* A2 = xattn + (size_t)bb * NN * DD + (size_t)nloc0 * DD;

    int tid = threadIdx.x, w = tid >> 6, lane = tid & 63, quad = lane >> 4, l15 = lane & 15;
    int wrow = (w & 1) * 32, wcol = (w >> 1) * 32;
    int lrow = lane >> 3, lcol = (lane & 7) * 8;

    f32x4 acc[2][2];
#pragma unroll
    for (int r = 0; r < 2; r++)
#pragma unroll
        for (int c = 0; c < 2; c++) acc[r][c] = (f32x4){0.f, 0.f, 0.f, 0.f};

    for (int ks = 0; ks < 8; ks++) {
        const unsigned short* As = (ks < 4) ? A1 : A2;
        int kloc = (ks & 3) * 64;
        __syncthreads();
#pragma unroll
        for (int j = 0; j < 2; j++)
            gll16(As + (size_t)(w * 16 + j * 8 + lrow) * DD + kloc + lcol, Al + (w * 16 + j * 8) * 64);
#pragma unroll
        for (int j = 0; j < 2; j++) {
            int orow = o0 + w * 16 + j * 8 + lrow;
            const unsigned short* bg = (ks < 4)
                ? (W1_l + (size_t)orow * 512 + ks * 64 + lcol)
                : (W1m_l + (size_t)orow * 256 + (ks - 4) * 64 + lcol);
            gll16(bg, Bl + (w * 16 + j * 8) * 64);
        }
        __syncthreads();
#pragma unroll
        for (int kh = 0; kh < 2; kh++) {
            bf16x8 bf[2], af[2];
#pragma unroll
            for (int cs = 0; cs < 2; cs++)
                bf[cs] = *(const bf16x8*)(Bl + (wcol + cs * 16 + l15) * 64 + kh * 32 + quad * 8);
#pragma unroll
            for (int rs = 0; rs < 2; rs++)
                af[rs] = *(const bf16x8*)(Al + (wrow + rs * 16 + l15) * 64 + kh * 32 + quad * 8);
#pragma unroll
            for (int rs = 0; rs < 2; rs++)
#pragma unroll
                for (int cs = 0; cs < 2; cs++)
                    acc[rs][cs] = mfma16(af[rs], bf[cs], acc[rs][cs]);
        }
    }
    __syncthreads();
    float cs_s[2] = {0.f, 0.f}, cs_q[2] = {0.f, 0.f};
#pragma unroll
    for (int rs = 0; rs < 2; rs++)
#pragma unroll
        for (int cs = 0; cs < 2; cs++) {
            int o = o0 + wcol + cs * 16 + l15;
            float bvx = bmix_l[o];
#pragma unroll
            for (int reg = 0; reg < 4; reg++) {
                float val = acc[rs][cs][reg] + bvx;
                sm[(wrow + rs * 16 + quad * 4 + reg) * 72 + wcol + cs * 16 + l15] = f2bf(val);
                cs_s[cs] += val;
                cs_q[cs] += val * val;
            }
        }
#pragma unroll
    for (int cs = 0; cs < 2; cs++) {
        cs_s[cs] += __shfl_xor(cs_s[cs], 16, 64);
        cs_s[cs] += __shfl_xor(cs_s[cs], 32, 64);
        cs_q[cs] += __shfl_xor(cs_q[cs], 16, 64);
        cs_q[cs] += __shfl_xor(cs_q[cs], 32, 64);
    }
    if (lane < 16) {
#pragma unroll
        for (int cs = 0; cs < 2; cs++) {
            atomicAdd(&bnsumm[o0 + wcol + cs * 16 + lane], cs_s[cs]);
            atomicAdd(&bnsumm[512 + o0 + wcol + cs * 16 + lane], cs_q[cs]);
        }
    }
    __syncthreads();
    int r = tid >> 2, ch = (tid & 3) * 16;
    unsigned short* dst = out1 + ((size_t)(bb * NN) + nloc0 + r) * 512 + o0 + ch;
    *(bf16x8*)(dst) = *(const bf16x8*)(&sm[r * 72 + ch]);
    *(bf16x8*)(dst + 8) = *(const bf16x8*)(&sm[r * 72 + ch + 8]);
}

// ---------------- bnrelu: y = relu(sc*out1 + sh) -> bf16 (BN finalize inlined) --------
__global__ __launch_bounds__(256) void bnrelu_kernel(
    const unsigned short* __restrict__ out1, const float* __restrict__ bnsumm,
    const float* __restrict__ g1_l, const float* __restrict__ beta1_l,
    unsigned short* __restrict__ ybf) {
    int idx = blockIdx.x * 256 + threadIdx.x;
    int base = idx * 8;
    int o = base & 511;
    union { bf16x8 v; unsigned short u[8]; } in, op;
    in.v = *(const bf16x8*)(out1 + base);
#pragma unroll
    for (int j = 0; j < 8; j++) {
        int ch = o + j;
        float s = bnsumm[ch], s2 = bnsumm[512 + ch];
        float mean = s * (1.f / 4096.f);
        float var = s2 * (1.f / 4096.f) - mean * mean;
        float sc = g1_l[ch] * rsqrtf(var + 1e-5f);
        float sh = beta1_l[ch] - mean * sc;
        op.u[j] = f2bf(fmaxf(0.f, bf2f(in.u[j]) * sc + sh));
    }
    *(bf16x8*)(ybf + base) = op.v;
}

// ---------------- conv2: pure GEMM M=4096, N=256, K=512; 32x64 tiles, LDS staging -----
__global__ __launch_bounds__(256) void conv2_kernel(
    const unsigned short* __restrict__ ybf, const unsigned short* __restrict__ W2_l,
    const float* __restrict__ b2_l, float* __restrict__ desc,
    unsigned short* __restrict__ xbf) {
    __shared__ __align__(16) unsigned short sm[6144];
    unsigned short* Al = sm;
    unsigned short* Bl = sm + 2048;

    int m0 = blockIdx.x * 32, o0 = blockIdx.y * 64;
    int bb = m0 >> 10, nloc0 = m0 & 1023;
    const unsigned short* A = ybf + ((size_t)(bb * NN) + nloc0) * 512;

    int tid = threadIdx.x, w = tid >> 6, lane = tid & 63, quad = lane >> 4, l15 = lane & 15;
    int wr = (w & 1) * 16, wc = (w >> 1) * 32;
    int lrow = lane >> 3, lcol = (lane & 7) * 8;

    f32x4 acc[2];
    acc[0] = (f32x4){0.f, 0.f, 0.f, 0.f};
    acc[1] = (f32x4){0.f, 0.f, 0.f, 0.f};

    for (int ks = 0; ks < 8; ks++) {
        int k0 = ks * 64;
        __syncthreads();
        gll16(A + (size_t)(w * 8 + lrow) * 512 + k0 + lcol, Al + (w * 8) * 64);
#pragma unroll
        for (int j = 0; j < 2; j++)
            gll16(W2_l + (size_t)(o0 + w * 16 + j * 8 + lrow) * 512 + k0 + lcol,
                  Bl + (w * 16 + j * 8) * 64);
        __syncthreads();
#pragma unroll
        for (int kh = 0; kh < 2; kh++) {
            bf16x8 af = *(const bf16x8*)(Al + (wr + l15) * 64 + kh * 32 + quad * 8);
#pragma unroll
            for (int cs = 0; cs < 2; cs++) {
                bf16x8 bf = *(const bf16x8*)(Bl + (wc + cs * 16 + l15) * 64 + kh * 32 + quad * 8);
                acc[cs] = mfma16(af, bf, acc[cs]);
            }
        }
    }
#pragma unroll
    for (int cs = 0; cs < 2; cs++)
#pragma unroll
        for (int reg = 0; reg < 4; reg++) {
            int n = nloc0 + wr + quad * 4 + reg;
            int o = o0 + wc + cs * 16 + l15;
            size_t di = ((size_t)bb * NN + n) * DD + o;
            float nd = desc[di] + acc[cs][reg] + b2_l[o];
            desc[di] = nd;
            xbf[di] = f2bf(nd);
        }
}

extern "C" void kernel_launch(void* const* d_in, const int* in_sizes, int n_in,
                              void* d_out, int out_size, void* d_ws, size_t ws_size,
                              hipStream_t stream) {
    const float* desc0 = (const float*)d_in[0];
    const float* desc1 = (const float*)d_in[1];
    const float* M0p   = (const float*)d_in[2];
    const float* M1p   = (const float*)d_in[3];
    const float* Wq = (const float*)d_in[4];  const float* bq = (const float*)d_in[5];
    const float* Wk = (const float*)d_in[6];  const float* bk = (const float*)d_in[7];
    const float* Wv = (const float*)d_in[8];  const float* bv = (const float*)d_in[9];
    const float* Wm = (const float*)d_in[10]; const float* bm = (const float*)d_in[11];
    const float* W1 = (const float*)d_in[12]; const float* b1 = (const float*)d_in[13];
    const float* g1 = (const float*)d_in[14]; const float* beta1 = (const float*)d_in[15];
    const float* W2 = (const float*)d_in[16]; const float* b2 = (const float*)d_in[17];
    float* out = (float*)d_out;
    char* ws = (char*)d_ws;

    float*          desc   = (float*)(ws);
    unsigned short* xbf    = (unsigned short*)(ws + (4ull << 20));
    unsigned short* qb     = (unsigned short*)(ws + (6ull << 20));
    unsigned short* kbuf   = (unsigned short*)(ws + (8ull << 20));
    unsigned short* vbuf   = (unsigned short*)(ws + (10ull << 20));
    unsigned short* xattn  = (unsigned short*)(ws + (12ull << 20));
    unsigned short* out1   = (unsigned short*)(ws + (14ull << 20));
    float*          bnsumm = (float*)(ws + (18ull << 20));
    float*          bmix   = (float*)(ws + (18ull << 20) + 8192);
    unsigned short* maskbf = (unsigned short*)(ws + (19ull << 20));
    unsigned short* W1m    = (unsigned short*)(ws + (27ull << 20));
    unsigned short* wbf    = (unsigned short*)(ws + (29ull << 20));
    unsigned short* ybf    = (unsigned short*)(ws + (37ull << 20));

    const int SQ = LL * 65536;

    prep_kernel<<<9728, 256, 0, stream>>>(desc0, desc1, M0p, M1p, Wq, Wk, Wv, Wm,
                                          W1, W2, bm, b1, wbf, maskbf, bmix, desc, xbf);
    fold1_kernel<<<dim3(8, 4, 6), 256, 0, stream>>>(wbf + 4 * (size_t)SQ, wbf + 3 * (size_t)SQ, W1m);

    for (int l = 0; l < LL; l++) {
        int cross = l & 1;
        const unsigned short* Wq_l = wbf + (size_t)l * 65536;
        const unsigned short* Wk_l = wbf + SQ + (size_t)l * 65536;
        const unsigned short* Wv_l = wbf + 2 * (size_t)SQ + (size_t)l * 65536;
        const unsigned short* W1_l = wbf + 4 * (size_t)SQ + (size_t)l * 262144;
        const unsigned short* W2_l = wbf + 4 * (size_t)SQ + (size_t)LL * 262144 + (size_t)l * 131072;
        const unsigned short* W1m_l = W1m + (size_t)l * 131072;

        proj_kernel<<<dim3(64, 12), 256, 0, stream>>>(
            xbf, Wq_l, Wk_l, Wv_l, bq + l * 256, bk + l * 256, bv + l * 256,
            qb, kbuf, vbuf, cross);
        flash_kernel<<<dim3(32, 16), 256, 0, stream>>>(qb, kbuf, vbuf, maskbf, xattn, bnsumm);
        conv1_kernel<<<dim3(64, 8), 256, 0, stream>>>(
            xbf, xattn, W1_l, W1m_l, bmix + l * 512, out1, bnsumm);
        bnrelu_kernel<<<1024, 256, 0, stream>>>(out1, bnsumm, g1 + l * 512, beta1 + l * 512, ybf);
        conv2_kernel<<<dim3(128, 4), 256, 0, stream>>>(
            ybf, W2_l, b2 + l * 256, desc, xbf);
    }

    final_kernel<<<dim3(32, 8, 4), 256, 0, stream>>>(desc, out);
}

// Round 13
// 452.017 us; speedup vs baseline: 1.1893x; 1.0304x over previous
//
#include <hip/hip_runtime.h>
#include <hip/hip_bf16.h>

#define NN 1024
#define DD 256
#define LL 6

typedef __attribute__((ext_vector_type(8))) short bf16x8;
typedef __attribute__((ext_vector_type(4))) float f32x4;
typedef __attribute__((ext_vector_type(4))) unsigned short u16x4;

__device__ __forceinline__ unsigned short f2bf(float f) {
    union { float f; unsigned u; } x; x.f = f;
    return (unsigned short)((x.u + 0x7fffu + ((x.u >> 16) & 1u)) >> 16);
}

__device__ __forceinline__ unsigned short f2bf_trunc(float f) {
    union { float f; unsigned u; } x; x.f = f;
    return (unsigned short)(x.u >> 16);
}

__device__ __forceinline__ float bf2f(unsigned short u) {
    union { unsigned u; float f; } x; x.u = ((unsigned)u) << 16; return x.f;
}

__device__ __forceinline__ f32x4 mfma16(bf16x8 a, bf16x8 b, f32x4 c) {
    return __builtin_amdgcn_mfma_f32_16x16x32_bf16(a, b, c, 0, 0, 0);
}

// async global->LDS, 16B per lane; lds dest = wave-uniform base + lane*16
__device__ __forceinline__ void gll16(const unsigned short* g, unsigned short* l) {
    __builtin_amdgcn_global_load_lds(
        (const __attribute__((address_space(1))) unsigned int*)g,
        (__attribute__((address_space(3))) unsigned int*)l, 16, 0, 0);
}

// ---------------- prep: wconv(vec4) | maskconv | fold2 | init, block-partitioned ------
__global__ __launch_bounds__(256) void prep_kernel(
    const float* __restrict__ desc0, const float* __restrict__ desc1,
    const float* __restrict__ M0, const float* __restrict__ M1,
    const float* __restrict__ Wq, const float* __restrict__ Wk,
    const float* __restrict__ Wv, const float* __restrict__ Wm,
    const float* __restrict__ W1, const float* __restrict__ W2,
    const float* __restrict__ bm, const float* __restrict__ b1,
    unsigned short* __restrict__ wbf, unsigned short* __restrict__ maskbf,
    float* __restrict__ bmix, float* __restrict__ desc, unsigned short* __restrict__ xbf) {
    __shared__ float T[32][33];
    const int SQ = LL * 65536;
    const int S1 = LL * 262144;
    int blk = blockIdx.x, tid = threadIdx.x;
    if (blk < 3840) {
        int idx = blk * 256 + tid;
        size_t base = (size_t)idx * 4;
        f32x4 v;
        if (base < (size_t)4 * SQ) {
            int seg = (int)(base / SQ), off = (int)(base % SQ);
            const float* p = (seg == 0) ? Wq : (seg == 1) ? Wk : (seg == 2) ? Wv : Wm;
            if (seg < 3) {
                int l = off >> 16, rem = off & 65535;
                int op = rem >> 8, i = rem & 255;
                int src = ((op & 63) << 2) | (op >> 6);
                v = *(const f32x4*)(p + (size_t)l * 65536 + (size_t)src * 256 + i);
            } else {
                v = *(const f32x4*)(p + off);
            }
        } else if (base < (size_t)4 * SQ + S1) {
            v = *(const f32x4*)(W1 + base - 4 * SQ);
        } else {
            v = *(const f32x4*)(W2 + base - 4 * SQ - S1);
        }
        u16x4 o;
#pragma unroll
        for (int j = 0; j < 4; j++) o[j] = f2bf(v[j]);
        *(u16x4*)(wbf + base) = o;
    } else if (blk < 7936) {
        int idx = (blk - 3840) * 256 + tid;
        size_t base = (size_t)idx * 4;
        int bb = (int)(base >> 20);
        const float* src = (bb < 2) ? (M0 + base) : (M1 + base - (2ull << 20));
        f32x4 v = *(const f32x4*)src;
        u16x4 o;
#pragma unroll
        for (int j = 0; j < 4; j++) o[j] = f2bf(v[j]);
        *(u16x4*)(maskbf + base) = o;
    } else if (blk < 8704) {
        int lane = tid & 63;
        int wid = (blk - 7936) * 4 + (tid >> 6);
        int l = wid >> 9, o = wid & 511;
        const float* row = W1 + ((size_t)l * 512 + o) * 512 + 256;
        const float* bmr = bm + (size_t)l * 256;
        f32x4 r = *(const f32x4*)(row + lane * 4);
        f32x4 b4 = *(const f32x4*)(bmr + lane * 4);
        float acc = r[0] * b4[0] + r[1] * b4[1] + r[2] * b4[2] + r[3] * b4[3];
        acc += __shfl_xor(acc, 1, 64);
        acc += __shfl_xor(acc, 2, 64);
        acc += __shfl_xor(acc, 4, 64);
        acc += __shfl_xor(acc, 8, 64);
        acc += __shfl_xor(acc, 16, 64);
        acc += __shfl_xor(acc, 32, 64);
        if (lane == 0) bmix[wid] = b1[wid] + acc;
    } else {
        int task = blk - 8704;
        int bb = task >> 8, tt = task & 255;
        int n0 = (tt >> 3) * 32, c0 = (tt & 7) * 32;
        const float* src = (bb < 2) ? (desc0 + (size_t)bb * DD * NN)
                                    : (desc1 + (size_t)(bb - 2) * DD * NN);
        int i = tid >> 5, j = tid & 31;
#pragma unroll
        for (int r = 0; r < 4; r++) {
            int c = i + r * 8;
            T[c][j] = src[(size_t)(c0 + c) * NN + n0 + j];
        }
        __syncthreads();
#pragma unroll
        for (int r = 0; r < 4; r++) {
            int n = i + r * 8;
            float v = T[j][n];
            size_t di = ((size_t)bb * NN + n0 + n) * DD + c0 + j;
            desc[di] = v;
            xbf[di] = f2bf(v);
        }
    }
}

// ---------------- fold1 (MFMA, bf16 inputs): W1m_perm[l][o][h*64+d] ----------------
__global__ __launch_bounds__(256) void fold1_kernel(const unsigned short* __restrict__ W1bf,
                                                    const unsigned short* __restrict__ Wmbf,
                                                    unsigned short* __restrict__ W1m) {
    int l = blockIdx.z;
    int o0 = blockIdx.x * 64, i0 = blockIdx.y * 64;
    const unsigned short* A = W1bf + (size_t)l * 262144;
    const unsigned short* B = Wmbf + (size_t)l * 65536;
    __shared__ unsigned short Bt[64][264];
    int t = threadIdx.x;
#pragma unroll
    for (int r = 0; r < 8; r++) {
        int j = r * 32 + (t >> 3);
        int il = (t & 7) * 8;
        union { bf16x8 v; unsigned short u[8]; } ld;
        ld.v = *(const bf16x8*)(B + (size_t)j * 256 + i0 + il);
#pragma unroll
        for (int jj = 0; jj < 8; jj++) Bt[il + jj][j] = ld.u[jj];
    }
    __syncthreads();
    int w = t >> 6, lane = t & 63, quad = lane >> 4, l15 = lane & 15;
    int wr = (w & 1) * 32, wc = (w >> 1) * 32;
    const unsigned short* Ab = A + (size_t)(o0 + wr + l15) * 512 + 256 + quad * 8;
    f32x4 acc[2][2];
#pragma unroll
    for (int r = 0; r < 2; r++)
#pragma unroll
        for (int c = 0; c < 2; c++) acc[r][c] = (f32x4){0.f, 0.f, 0.f, 0.f};
#pragma unroll
    for (int s = 0; s < 8; s++) {
        int kk = s * 32;
        bf16x8 a0 = *(const bf16x8*)(Ab + kk);
        bf16x8 a1 = *(const bf16x8*)(Ab + 16 * 512 + kk);
        bf16x8 b0 = *(const bf16x8*)(&Bt[wc + l15][kk + quad * 8]);
        bf16x8 b1 = *(const bf16x8*)(&Bt[wc + 16 + l15][kk + quad * 8]);
        acc[0][0] = mfma16(a0, b0, acc[0][0]);
        acc[0][1] = mfma16(a0, b1, acc[0][1]);
        acc[1][0] = mfma16(a1, b0, acc[1][0]);
        acc[1][1] = mfma16(a1, b1, acc[1][1]);
    }
#pragma unroll
    for (int rs = 0; rs < 2; rs++)
#pragma unroll
        for (int cs = 0; cs < 2; cs++)
#pragma unroll
            for (int reg = 0; reg < 4; reg++) {
                int o = o0 + wr + rs * 16 + quad * 4 + reg;
                int i = i0 + wc + cs * 16 + l15;
                int pc = (i & 3) * 64 + (i >> 2);
                W1m[((size_t)l * 512 + o) * 256 + pc] = f2bf(acc[rs][cs][reg]);
            }
}

// ---------------- final: [4][1024][256] -> [4][256][1024] via LDS tiles ----------------
__global__ __launch_bounds__(256) void final_kernel(const float* __restrict__ desc,
                                                    float* __restrict__ out) {
    __shared__ float T[32][33];
    int bb = blockIdx.z;
    int n0 = blockIdx.x * 32, c0 = blockIdx.y * 32;
    int i = threadIdx.x >> 5, j = threadIdx.x & 31;
#pragma unroll
    for (int r = 0; r < 4; r++) {
        int n = i + r * 8;
        T[n][j] = desc[((size_t)bb * NN + n0 + n) * DD + c0 + j];
    }
    __syncthreads();
#pragma unroll
    for (int r = 0; r < 4; r++) {
        int c = i + r * 8;
        out[((size_t)bb * DD + c0 + c) * NN + n0 + j] = T[j][c];
    }
}

// ---------------- proj: M=4096, N=768 (q|k|v), K=256; 64x64 tiles, swizzled staging ---
// LDS rows are 128B (bank-aligned); stage logical chunk c of row r at physical chunk
// c^(r&7) via the gll16 *source* address, read back with the same XOR -> conflict-free.
__global__ __launch_bounds__(256) void proj_kernel(
    const unsigned short* __restrict__ xbf,
    const unsigned short* __restrict__ Wq_l, const unsigned short* __restrict__ Wk_l,
    const unsigned short* __restrict__ Wv_l,
    const float* __restrict__ bq_l, const float* __restrict__ bk_l,
    const float* __restrict__ bv_l,
    unsigned short* __restrict__ qb, unsigned short* __restrict__ kb,
    unsigned short* __restrict__ vb, int cross) {
    __shared__ __align__(16) unsigned short sm[8192];
    unsigned short* Al = sm;
    unsigned short* Bl = sm + 4096;

    int m0 = blockIdx.x * 64;
    int by = blockIdx.y;
    int mat = by >> 2;
    int o0c = (by & 3) * 64;
    int bb = m0 >> 10, nloc0 = m0 & 1023;
    int srcbb = (mat == 0) ? bb : (cross ? (bb ^ 2) : bb);
    const unsigned short* A = xbf + (size_t)srcbb * NN * DD + (size_t)nloc0 * DD;
    const unsigned short* W = ((mat == 0) ? Wq_l : (mat == 1) ? Wk_l : Wv_l) + (size_t)o0c * DD;
    const float* bias = (mat == 0) ? bq_l : (mat == 1) ? bk_l : bv_l;

    int tid = threadIdx.x, w = tid >> 6, lane = tid & 63, quad = lane >> 4, l15 = lane & 15;
    int wrow = (w & 1) * 32, wcol = (w >> 1) * 32;
    int lrow = lane >> 3, chnk = lane & 7;

    f32x4 acc[2][2];
#pragma unroll
    for (int r = 0; r < 2; r++)
#pragma unroll
        for (int c = 0; c < 2; c++) acc[r][c] = (f32x4){0.f, 0.f, 0.f, 0.f};

    for (int ks = 0; ks < 4; ks++) {
        int k0 = ks * 64;
        __syncthreads();
#pragma unroll
        for (int j = 0; j < 2; j++) {
            int r = w * 16 + j * 8 + lrow;
            gll16(A + (size_t)r * DD + k0 + ((chnk ^ (r & 7)) * 8), Al + (w * 16 + j * 8) * 64);
            gll16(W + (size_t)r * DD + k0 + ((chnk ^ (r & 7)) * 8), Bl + (w * 16 + j * 8) * 64);
        }
        __syncthreads();
#pragma unroll
        for (int kh = 0; kh < 2; kh++) {
            bf16x8 bf[2], af[2];
#pragma unroll
            for (int cs = 0; cs < 2; cs++) {
                int rb = wcol + cs * 16 + l15;
                bf[cs] = *(const bf16x8*)(Bl + rb * 64 + (((kh * 4 + quad) ^ (rb & 7)) * 8));
            }
#pragma unroll
            for (int rs = 0; rs < 2; rs++) {
                int ra = wrow + rs * 16 + l15;
                af[rs] = *(const bf16x8*)(Al + ra * 64 + (((kh * 4 + quad) ^ (ra & 7)) * 8));
            }
#pragma unroll
            for (int rs = 0; rs < 2; rs++)
#pragma unroll
                for (int cs = 0; cs < 2; cs++)
                    acc[rs][cs] = mfma16(af[rs], bf[cs], acc[rs][cs]);
        }
    }
    __syncthreads();
    float qscale = (mat == 0) ? 0.1803368801f : 1.0f;   // 0.125 * log2(e) for q
    if (mat < 2) {
#pragma unroll
        for (int rs = 0; rs < 2; rs++)
#pragma unroll
            for (int cs = 0; cs < 2; cs++) {
                int op = o0c + wcol + cs * 16 + l15;
                float bv4 = bias[((op & 63) << 2) | (op >> 6)];
#pragma unroll
                for (int reg = 0; reg < 4; reg++)
                    sm[(wrow + rs * 16 + quad * 4 + reg) * 72 + wcol + cs * 16 + l15] =
                        f2bf((acc[rs][cs][reg] + bv4) * qscale);
            }
        __syncthreads();
        int r = tid >> 2, ch = (tid & 3) * 16;
        unsigned short* dst = ((mat == 0) ? qb : kb) + ((size_t)(bb * NN) + nloc0 + r) * 256 + o0c + ch;
        *(bf16x8*)(dst) = *(const bf16x8*)(&sm[r * 72 + ch]);
        *(bf16x8*)(dst + 8) = *(const bf16x8*)(&sm[r * 72 + ch + 8]);
    } else {
#pragma unroll
        for (int rs = 0; rs < 2; rs++)
#pragma unroll
            for (int cs = 0; cs < 2; cs++) {
                int op = o0c + wcol + cs * 16 + l15;
                float bv4 = bias[((op & 63) << 2) | (op >> 6)];
#pragma unroll
                for (int reg = 0; reg < 4; reg++)
                    sm[(wcol + cs * 16 + l15) * 72 + wrow + rs * 16 + quad * 4 + reg] =
                        f2bf(acc[rs][cs][reg] + bv4);
            }
        __syncthreads();
        int o = tid >> 2, nch = (tid & 3) * 16;
        int opg = o0c + o;
        unsigned short* dst = vb + ((size_t)(bb * 4 + (opg >> 6)) * 64 + (opg & 63)) * NN + nloc0 + nch;
        *(bf16x8*)(dst) = *(const bf16x8*)(&sm[o * 72 + nch]);
        *(bf16x8*)(dst + 8) = *(const bf16x8*)(&sm[o * 72 + nch + 8]);
    }
}

// ---------------- flash: 4 waves/block, wave = m-split, 2 q-groups per wave -----------
__global__ __launch_bounds__(256, 2) void flash_kernel(
    const unsigned short* __restrict__ qb, const unsigned short* __restrict__ kb,
    const unsigned short* __restrict__ vb,
    const unsigned short* __restrict__ maskbf,
    unsigned short* __restrict__ xattn, float* __restrict__ bnsumm) {
    __shared__ __align__(16) char smem[51200];
    unsigned short* Plds = (unsigned short*)smem;
    float* OL = (float*)smem;

    int bh = blockIdx.y, nb = blockIdx.x;
    int bb = bh >> 2, h = bh & 3;
    int tid = threadIdx.x, w = tid >> 6, lane = tid & 63, quad = lane >> 4, l15 = lane & 15;

    if (nb == 0 && bh == 0) {
        bnsumm[tid] = 0.f; bnsumm[tid + 256] = 0.f;
        bnsumm[tid + 512] = 0.f; bnsumm[tid + 768] = 0.f;
    }

    const unsigned short* mask = maskbf + (size_t)bb * NN * NN;
    const unsigned short* Q = qb + (size_t)bb * NN * 256 + h * 64;
    const unsigned short* Kb = kb + (size_t)bb * NN * 256 + h * 64;
    const unsigned short* Vb = vb + (size_t)bh * 64 * NN;
    int row0 = nb * 32;

    bf16x8 qf[2][2];
#pragma unroll
    for (int s = 0; s < 2; s++)
#pragma unroll
        for (int kc = 0; kc < 2; kc++)
            qf[s][kc] = *(const bf16x8*)(Q + (size_t)(row0 + s * 16 + l15) * 256 + kc * 32 + quad * 8);

    const unsigned short* mrow[2][4];
#pragma unroll
    for (int s = 0; s < 2; s++)
#pragma unroll
        for (int reg = 0; reg < 4; reg++)
            mrow[s][reg] = mask + (size_t)(row0 + s * 16 + quad * 4 + reg) * NN + w * 256;

    f32x4 Oa[2][4];
#pragma unroll
    for (int s = 0; s < 2; s++)
#pragma unroll
        for (int dt = 0; dt < 4; dt++) Oa[s][dt] = (f32x4){0.f, 0.f, 0.f, 0.f};
    float mrun[2][4], lrun[2][4];
#pragma unroll
    for (int s = 0; s < 2; s++)
#pragma unroll
        for (int r = 0; r < 4; r++) { mrun[s][r] = -1e30f; lrun[s][r] = 0.f; }

    unsigned short* Pw = Plds + w * (16 * 72);

    for (int mt = 0; mt < 4; mt++) {
        int ml = mt * 64;
        int m0 = w * 256 + ml;
        f32x4 sA[4], sB[4];
#pragma unroll
        for (int t = 0; t < 4; t++) {
            sA[t] = (f32x4){0.f, 0.f, 0.f, 0.f};
            sB[t] = (f32x4){0.f, 0.f, 0.f, 0.f};
        }
#pragma unroll
        for (int t = 0; t < 4; t++)
#pragma unroll
            for (int kc = 0; kc < 2; kc++) {
                bf16x8 kf = *(const bf16x8*)(Kb + (size_t)(m0 + t * 16 + l15) * 256 + kc * 32 + quad * 8);
                sA[t] = mfma16(qf[0][kc], kf, sA[t]);
                sB[t] = mfma16(qf[1][kc], kf, sB[t]);
            }
        bf16x8 vf[8];
#pragma unroll
        for (int dt = 0; dt < 4; dt++)
#pragma unroll
            for (int kc = 0; kc < 2; kc++)
                vf[dt * 2 + kc] = *(const bf16x8*)(Vb + (size_t)(dt * 16 + l15) * NN + m0 + kc * 32 + quad * 8);
#pragma unroll
        for (int s = 0; s < 2; s++) {
            float sv[4][4], rmax[4];
#pragma unroll
            for (int r = 0; r < 4; r++) rmax[r] = -1e30f;
#pragma unroll
            for (int t = 0; t < 4; t++)
#pragma unroll
                for (int reg = 0; reg < 4; reg++) {
                    float sc = (s == 0) ? sA[t][reg] : sB[t][reg];
                    float v = sc * bf2f(mrow[s][reg][ml + t * 16 + l15]);
                    sv[t][reg] = v;
                    rmax[reg] = fmaxf(rmax[reg], v);
                }
#pragma unroll
            for (int reg = 0; reg < 4; reg++) {
                rmax[reg] = fmaxf(rmax[reg], __shfl_xor(rmax[reg], 1, 64));
                rmax[reg] = fmaxf(rmax[reg], __shfl_xor(rmax[reg], 2, 64));
                rmax[reg] = fmaxf(rmax[reg], __shfl_xor(rmax[reg], 4, 64));
                rmax[reg] = fmaxf(rmax[reg], __shfl_xor(rmax[reg], 8, 64));
            }
            float alpha[4], rsum[4];
#pragma unroll
            for (int reg = 0; reg < 4; reg++) {
                float mn = fmaxf(mrun[s][reg], rmax[reg]);
                alpha[reg] = exp2f(mrun[s][reg] - mn);
                mrun[s][reg] = mn;
                rsum[reg] = 0.f;
            }
#pragma unroll
            for (int t = 0; t < 4; t++)
#pragma unroll
                for (int reg = 0; reg < 4; reg++) {
                    float p = exp2f(sv[t][reg] - mrun[s][reg]);
                    sv[t][reg] = p;
                    rsum[reg] += p;
                }
#pragma unroll
            for (int reg = 0; reg < 4; reg++) {
                rsum[reg] += __shfl_xor(rsum[reg], 1, 64);
                rsum[reg] += __shfl_xor(rsum[reg], 2, 64);
                rsum[reg] += __shfl_xor(rsum[reg], 4, 64);
                rsum[reg] += __shfl_xor(rsum[reg], 8, 64);
                lrun[s][reg] = lrun[s][reg] * alpha[reg] + rsum[reg];
            }
#pragma unroll
            for (int dt = 0; dt < 4; dt++)
#pragma unroll
                for (int reg = 0; reg < 4; reg++) Oa[s][dt][reg] *= alpha[reg];
#pragma unroll
            for (int t = 0; t < 4; t++)
#pragma unroll
                for (int reg = 0; reg < 4; reg++)
                    Pw[(quad * 4 + reg) * 72 + t * 16 + l15] = f2bf_trunc(sv[t][reg]);
            bf16x8 pf[2];
#pragma unroll
            for (int kc = 0; kc < 2; kc++)
                pf[kc] = *(const bf16x8*)(Pw + l15 * 72 + kc * 32 + quad * 8);
#pragma unroll
            for (int dt = 0; dt < 4; dt++)
#pragma unroll
                for (int kc = 0; kc < 2; kc++)
                    Oa[s][dt] = mfma16(pf[kc], vf[dt * 2 + kc], Oa[s][dt]);
        }
    }
    __syncthreads();
#pragma unroll
    for (int s = 0; s < 2; s++) {
        float* mine = OL + (size_t)((s + 2 * w) * 64 + lane) * 25;
#pragma unroll
        for (int dt = 0; dt < 4; dt++)
#pragma unroll
            for (int reg = 0; reg < 4; reg++) mine[dt * 4 + reg] = Oa[s][dt][reg];
#pragma unroll
        for (int reg = 0; reg < 4; reg++) { mine[16 + reg] = mrun[s][reg]; mine[20 + reg] = lrun[s][reg]; }
    }
    __syncthreads();
    if (w < 2) {
        const float* p[4];
#pragma unroll
        for (int j = 0; j < 4; j++) p[j] = OL + (size_t)((w + 2 * j) * 64 + lane) * 25;
        float e[4][4], li[4];
#pragma unroll
        for (int reg = 0; reg < 4; reg++) {
            float M = fmaxf(fmaxf(p[0][16 + reg], p[1][16 + reg]),
                            fmaxf(p[2][16 + reg], p[3][16 + reg]));
            float L = 0.f;
#pragma unroll
            for (int j = 0; j < 4; j++) {
                e[j][reg] = exp2f(p[j][16 + reg] - M);
                L += p[j][20 + reg] * e[j][reg];
            }
            li[reg] = 1.f / L;
        }
#pragma unroll
        for (int dt = 0; dt < 4; dt++)
#pragma unroll
            for (int reg = 0; reg < 4; reg++) {
                float val = 0.f;
#pragma unroll
                for (int j = 0; j < 4; j++) val += p[j][dt * 4 + reg] * e[j][reg];
                val *= li[reg];
                int n = row0 + w * 16 + quad * 4 + reg;
                int col = h * 64 + dt * 16 + l15;
                xattn[((size_t)bb * NN + n) * DD + col] = f2bf(val);
            }
    }
}

// ---------------- conv1: M=4096, N=512, K=512 (x|attn); swizzled staging + BN stats ---
__global__ __launch_bounds__(256) void conv1_kernel(
    const unsigned short* __restrict__ xbf, const unsigned short* __restrict__ xattn,
    const unsigned short* __restrict__ W1_l, const unsigned short* __restrict__ W1m_l,
    const float* __restrict__ bmix_l,
    unsigned short* __restrict__ out1, float* __restrict__ bnsumm) {
    __shared__ __align__(16) unsigned short sm[8192];
    unsigned short* Al = sm;
    unsigned short* Bl = sm + 4096;

    int m0 = blockIdx.x * 64, o0 = blockIdx.y * 64;
    int bb = m0 >> 10, nloc0 = m0 & 1023;
    const unsigned short* A1 = xbf + (size_t)bb * NN * DD + (size_t)nloc0 * DD;
    const unsigned short* A2 = xattn + (size_t)bb * NN * DD + (size_t)nloc0 * DD;

    int tid = threadIdx.x, w = tid >> 6, lane = tid & 63, quad = lane >> 4, l15 = lane & 15;
    int wrow = (w & 1) * 32, wcol = (w >> 1) * 32;
    int lrow = lane >> 3, chnk = lane & 7;

    f32x4 acc[2][2];
#pragma unroll
    for (int r = 0; r < 2; r++)
#pragma unroll
        for (int c = 0; c < 2; c++) acc[r][c] = (f32x4){0.f, 0.f, 0.f, 0.f};

    for (int ks = 0; ks < 8; ks++) {
        const unsigned short* As = (ks < 4) ? A1 : A2;
        int kloc = (ks & 3) * 64;
        __syncthreads();
#pragma unroll
        for (int j = 0; j < 2; j++) {
            int r = w * 16 + j * 8 + lrow;
            gll16(As + (size_t)r * DD + kloc + ((chnk ^ (r & 7)) * 8), Al + (w * 16 + j * 8) * 64);
            int orow = o0 + r;
            const unsigned short* bg = (ks < 4)
                ? (W1_l + (size_t)orow * 512 + ks * 64 + ((chnk ^ (r & 7)) * 8))
                : (W1m_l + (size_t)orow * 256 + (ks - 4) * 64 + ((chnk ^ (r & 7)) * 8));
            gll16(bg, Bl + (w * 16 + j * 8) * 64);
        }
        __syncthreads();
#pragma unroll
        for (int kh = 0; kh < 2; kh++) {
            bf16x8 bf[2], af[2];
#pragma unroll
            for (int cs = 0; cs < 2; cs++) {
                int rb = wcol + cs * 16 + l15;
                bf[cs] = *(const bf16x8*)(Bl + rb * 64 + (((kh * 4 + quad) ^ (rb & 7)) * 8));
            }
#pragma unroll
            for (int rs = 0; rs < 2; rs++) {
                int ra = wrow + rs * 16 + l15;
                af[rs] = *(const bf16x8*)(Al + ra * 64 + (((kh * 4 + quad) ^ (ra & 7)) * 8));
            }
#pragma unroll
            for (int rs = 0; rs < 2; rs++)
#pragma unroll
                for (int cs = 0; cs < 2; cs++)
                    acc[rs][cs] = mfma16(af[rs], bf[cs], acc[rs][cs]);
        }
    }
    __syncthreads();
    float cs_s[2] = {0.f, 0.f}, cs_q[2] = {0.f, 0.f};
#pragma unroll
    for (int rs = 0; rs < 2; rs++)
#pragma unroll
        for (int cs = 0; cs < 2; cs++) {
            int o = o0 + wcol + cs * 16 + l15;
            float bvx = bmix_l[o];
#pragma unroll
            for (int reg = 0; reg < 4; reg++) {
                float val = acc[rs][cs][reg] + bvx;
                sm[(wrow + rs * 16 + quad * 4 + reg) * 72 + wcol + cs * 16 + l15] = f2bf(val);
                cs_s[cs] += val;
                cs_q[cs] += val * val;
            }
        }
#pragma unroll
    for (int cs = 0; cs < 2; cs++) {
        cs_s[cs] += __shfl_xor(cs_s[cs], 16, 64);
        cs_s[cs] += __shfl_xor(cs_s[cs], 32, 64);
        cs_q[cs] += __shfl_xor(cs_q[cs], 16, 64);
        cs_q[cs] += __shfl_xor(cs_q[cs], 32, 64);
    }
    if (lane < 16) {
#pragma unroll
        for (int cs = 0; cs < 2; cs++) {
            atomicAdd(&bnsumm[o0 + wcol + cs * 16 + lane], cs_s[cs]);
            atomicAdd(&bnsumm[512 + o0 + wcol + cs * 16 + lane], cs_q[cs]);
        }
    }
    __syncthreads();
    int r = tid >> 2, ch = (tid & 3) * 16;
    unsigned short* dst = out1 + ((size_t)(bb * NN) + nloc0 + r) * 512 + o0 + ch;
    *(bf16x8*)(dst) = *(const bf16x8*)(&sm[r * 72 + ch]);
    *(bf16x8*)(dst + 8) = *(const bf16x8*)(&sm[r * 72 + ch + 8]);
}

// ---------------- bnrelu: y = relu(sc*out1 + sh) -> bf16 (BN finalize inlined) --------
__global__ __launch_bounds__(256) void bnrelu_kernel(
    const unsigned short* __restrict__ out1, const float* __restrict__ bnsumm,
    const float* __restrict__ g1_l, const float* __restrict__ beta1_l,
    unsigned short* __restrict__ ybf) {
    int idx = blockIdx.x * 256 + threadIdx.x;
    int base = idx * 8;
    int o = base & 511;
    union { bf16x8 v; unsigned short u[8]; } in, op;
    in.v = *(const bf16x8*)(out1 + base);
#pragma unroll
    for (int j = 0; j < 8; j++) {
        int ch = o + j;
        float s = bnsumm[ch], s2 = bnsumm[512 + ch];
        float mean = s * (1.f / 4096.f);
        float var = s2 * (1.f / 4096.f) - mean * mean;
        float sc = g1_l[ch] * rsqrtf(var + 1e-5f);
        float sh = beta1_l[ch] - mean * sc;
        op.u[j] = f2bf(fmaxf(0.f, bf2f(in.u[j]) * sc + sh));
    }
    *(bf16x8*)(ybf + base) = op.v;
}

// ---------------- conv2: pure GEMM M=4096, N=256, K=512; swizzled staging -------------
__global__ __launch_bounds__(256) void conv2_kernel(
    const unsigned short* __restrict__ ybf, const unsigned short* __restrict__ W2_l,
    const float* __restrict__ b2_l, float* __restrict__ desc,
    unsigned short* __restrict__ xbf) {
    __shared__ __align__(16) unsigned short sm[6144];
    unsigned short* Al = sm;
    unsigned short* Bl = sm + 2048;

    int m0 = blockIdx.x * 32, o0 = blockIdx.y * 64;
    int bb = m0 >> 10, nloc0 = m0 & 1023;
    const unsigned short* A = ybf + ((size_t)(bb * NN) + nloc0) * 512;

    int tid = threadIdx.x, w = tid >> 6, lane = tid & 63, quad = lane >> 4, l15 = lane & 15;
    int wr = (w & 1) * 16, wc = (w >> 1) * 32;
    int lrow = lane >> 3, chnk = lane & 7;

    f32x4 acc[2];
    acc[0] = (f32x4){0.f, 0.f, 0.f, 0.f};
    acc[1] = (f32x4){0.f, 0.f, 0.f, 0.f};

    for (int ks = 0; ks < 8; ks++) {
        int k0 = ks * 64;
        __syncthreads();
        {
            int r = w * 8 + lrow;
            gll16(A + (size_t)r * 512 + k0 + ((chnk ^ (r & 7)) * 8), Al + (w * 8) * 64);
        }
#pragma unroll
        for (int j = 0; j < 2; j++) {
            int r = w * 16 + j * 8 + lrow;
            gll16(W2_l + (size_t)(o0 + r) * 512 + k0 + ((chnk ^ (r & 7)) * 8),
                  Bl + (w * 16 + j * 8) * 64);
        }
        __syncthreads();
#pragma unroll
        for (int kh = 0; kh < 2; kh++) {
            int ra = wr + l15;
            bf16x8 af = *(const bf16x8*)(Al + ra * 64 + (((kh * 4 + quad) ^ (ra & 7)) * 8));
#pragma unroll
            for (int cs = 0; cs < 2; cs++) {
                int rb = wc + cs * 16 + l15;
                bf16x8 bf = *(const bf16x8*)(Bl + rb * 64 + (((kh * 4 + quad) ^ (rb & 7)) * 8));
                acc[cs] = mfma16(af, bf, acc[cs]);
            }
        }
    }
#pragma unroll
    for (int cs = 0; cs < 2; cs++)
#pragma unroll
        for (int reg = 0; reg < 4; reg++) {
            int n = nloc0 + wr + quad * 4 + reg;
            int o = o0 + wc + cs * 16 + l15;
            size_t di = ((size_t)bb * NN + n) * DD + o;
            float nd = desc[di] + acc[cs][reg] + b2_l[o];
            desc[di] = nd;
            xbf[di] = f2bf(nd);
        }
}

extern "C" void kernel_launch(void* const* d_in, const int* in_sizes, int n_in,
                              void* d_out, int out_size, void* d_ws, size_t ws_size,
                              hipStream_t stream) {
    const float* desc0 = (const float*)d_in[0];
    const float* desc1 = (const float*)d_in[1];
    const float* M0p   = (const float*)d_in[2];
    const float* M1p   = (const float*)d_in[3];
    const float* Wq = (const float*)d_in[4];  const float* bq = (const float*)d_in[5];
    const float* Wk = (const float*)d_in[6];  const float* bk = (const float*)d_in[7];
    const float* Wv = (const float*)d_in[8];  const float* bv = (const float*)d_in[9];
    const float* Wm = (const float*)d_in[10]; const float* bm = (const float*)d_in[11];
    const float* W1 = (const float*)d_in[12]; const float* b1 = (const float*)d_in[13];
    const float* g1 = (const float*)d_in[14]; const float* beta1 = (const float*)d_in[15];
    const float* W2 = (const float*)d_in[16]; const float* b2 = (const float*)d_in[17];
    float* out = (float*)d_out;
    char* ws = (char*)d_ws;

    float*          desc   = (float*)(ws);
    unsigned short* xbf    = (unsigned short*)(ws + (4ull << 20));
    unsigned short* qb     = (unsigned short*)(ws + (6ull << 20));
    unsigned short* kbuf   = (unsigned short*)(ws + (8ull << 20));
    unsigned short* vbuf   = (unsigned short*)(ws + (10ull << 20));
    unsigned short* xattn  = (unsigned short*)(ws + (12ull << 20));
    unsigned short* out1   = (unsigned short*)(ws + (14ull << 20));
    float*          bnsumm = (float*)(ws + (18ull << 20));
    float*          bmix   = (float*)(ws + (18ull << 20) + 8192);
    unsigned short* maskbf = (unsigned short*)(ws + (19ull << 20));
    unsigned short* W1m    = (unsigned short*)(ws + (27ull << 20));
    unsigned short* wbf    = (unsigned short*)(ws + (29ull << 20));
    unsigned short* ybf    = (unsigned short*)(ws + (37ull << 20));

    const int SQ = LL * 65536;

    prep_kernel<<<9728, 256, 0, stream>>>(desc0, desc1, M0p, M1p, Wq, Wk, Wv, Wm,
                                          W1, W2, bm, b1, wbf, maskbf, bmix, desc, xbf);
    fold1_kernel<<<dim3(8, 4, 6), 256, 0, stream>>>(wbf + 4 * (size_t)SQ, wbf + 3 * (size_t)SQ, W1m);

    for (int l = 0; l < LL; l++) {
        int cross = l & 1;
        const unsigned short* Wq_l = wbf + (size_t)l * 65536;
        const unsigned short* Wk_l = wbf + SQ + (size_t)l * 65536;
        const unsigned short* Wv_l = wbf + 2 * (size_t)SQ + (size_t)l * 65536;
        const unsigned short* W1_l = wbf + 4 * (size_t)SQ + (size_t)l * 262144;
        const unsigned short* W2_l = wbf + 4 * (size_t)SQ + (size_t)LL * 262144 + (size_t)l * 131072;
        const unsigned short* W1m_l = W1m + (size_t)l * 131072;

        proj_kernel<<<dim3(64, 12), 256, 0, stream>>>(
            xbf, Wq_l, Wk_l, Wv_l, bq + l * 256, bk + l * 256, bv + l * 256,
            qb, kbuf, vbuf, cross);
        flash_kernel<<<dim3(32, 16), 256, 0, stream>>>(qb, kbuf, vbuf, maskbf, xattn, bnsumm);
        conv1_kernel<<<dim3(64, 8), 256, 0, stream>>>(
            xbf, xattn, W1_l, W1m_l, bmix + l * 512, out1, bnsumm);
        bnrelu_kernel<<<1024, 256, 0, stream>>>(out1, bnsumm, g1 + l * 512, beta1 + l * 512, ybf);
        conv2_kernel<<<dim3(128, 4), 256, 0, stream>>>(
            ybf, W2_l, b2 + l * 256, desc, xbf);
    }

    final_kernel<<<dim3(32, 8, 4), 256, 0, stream>>>(desc, out);
}

// Round 14
// 436.823 us; speedup vs baseline: 1.2307x; 1.0348x over previous
//
#include <hip/hip_runtime.h>
#include <hip/hip_bf16.h>

#define NN 1024
#define DD 256
#define LL 6

typedef __attribute__((ext_vector_type(8))) short bf16x8;
typedef __attribute__((ext_vector_type(4))) float f32x4;
typedef __attribute__((ext_vector_type(4))) unsigned short u16x4;

__device__ __forceinline__ unsigned short f2bf(float f) {
    union { float f; unsigned u; } x; x.f = f;
    return (unsigned short)((x.u + 0x7fffu + ((x.u >> 16) & 1u)) >> 16);
}

__device__ __forceinline__ unsigned short f2bf_trunc(float f) {
    union { float f; unsigned u; } x; x.f = f;
    return (unsigned short)(x.u >> 16);
}

__device__ __forceinline__ float bf2f(unsigned short u) {
    union { unsigned u; float f; } x; x.u = ((unsigned)u) << 16; return x.f;
}

__device__ __forceinline__ f32x4 mfma16(bf16x8 a, bf16x8 b, f32x4 c) {
    return __builtin_amdgcn_mfma_f32_16x16x32_bf16(a, b, c, 0, 0, 0);
}

// async global->LDS, 16B per lane; lds dest = wave-uniform base + lane*16
__device__ __forceinline__ void gll16(const unsigned short* g, unsigned short* l) {
    __builtin_amdgcn_global_load_lds(
        (const __attribute__((address_space(1))) unsigned int*)g,
        (__attribute__((address_space(3))) unsigned int*)l, 16, 0, 0);
}

// ---------------- prep: wconv(vec4) | maskconv | fold2 | init, block-partitioned ------
__global__ __launch_bounds__(256) void prep_kernel(
    const float* __restrict__ desc0, const float* __restrict__ desc1,
    const float* __restrict__ M0, const float* __restrict__ M1,
    const float* __restrict__ Wq, const float* __restrict__ Wk,
    const float* __restrict__ Wv, const float* __restrict__ Wm,
    const float* __restrict__ W1, const float* __restrict__ W2,
    const float* __restrict__ bm, const float* __restrict__ b1,
    unsigned short* __restrict__ wbf, unsigned short* __restrict__ maskbf,
    float* __restrict__ bmix, float* __restrict__ desc, unsigned short* __restrict__ xbf) {
    __shared__ float T[32][33];
    const int SQ = LL * 65536;
    const int S1 = LL * 262144;
    int blk = blockIdx.x, tid = threadIdx.x;
    if (blk < 3840) {
        int idx = blk * 256 + tid;
        size_t base = (size_t)idx * 4;
        f32x4 v;
        if (base < (size_t)4 * SQ) {
            int seg = (int)(base / SQ), off = (int)(base % SQ);
            const float* p = (seg == 0) ? Wq : (seg == 1) ? Wk : (seg == 2) ? Wv : Wm;
            if (seg < 3) {
                int l = off >> 16, rem = off & 65535;
                int op = rem >> 8, i = rem & 255;
                int src = ((op & 63) << 2) | (op >> 6);
                v = *(const f32x4*)(p + (size_t)l * 65536 + (size_t)src * 256 + i);
            } else {
                v = *(const f32x4*)(p + off);
            }
        } else if (base < (size_t)4 * SQ + S1) {
            v = *(const f32x4*)(W1 + base - 4 * SQ);
        } else {
            v = *(const f32x4*)(W2 + base - 4 * SQ - S1);
        }
        u16x4 o;
#pragma unroll
        for (int j = 0; j < 4; j++) o[j] = f2bf(v[j]);
        *(u16x4*)(wbf + base) = o;
    } else if (blk < 7936) {
        int idx = (blk - 3840) * 256 + tid;
        size_t base = (size_t)idx * 4;
        int bb = (int)(base >> 20);
        const float* src = (bb < 2) ? (M0 + base) : (M1 + base - (2ull << 20));
        f32x4 v = *(const f32x4*)src;
        u16x4 o;
#pragma unroll
        for (int j = 0; j < 4; j++) o[j] = f2bf(v[j]);
        *(u16x4*)(maskbf + base) = o;
    } else if (blk < 8704) {
        int lane = tid & 63;
        int wid = (blk - 7936) * 4 + (tid >> 6);
        int l = wid >> 9, o = wid & 511;
        const float* row = W1 + ((size_t)l * 512 + o) * 512 + 256;
        const float* bmr = bm + (size_t)l * 256;
        f32x4 r = *(const f32x4*)(row + lane * 4);
        f32x4 b4 = *(const f32x4*)(bmr + lane * 4);
        float acc = r[0] * b4[0] + r[1] * b4[1] + r[2] * b4[2] + r[3] * b4[3];
        acc += __shfl_xor(acc, 1, 64);
        acc += __shfl_xor(acc, 2, 64);
        acc += __shfl_xor(acc, 4, 64);
        acc += __shfl_xor(acc, 8, 64);
        acc += __shfl_xor(acc, 16, 64);
        acc += __shfl_xor(acc, 32, 64);
        if (lane == 0) bmix[wid] = b1[wid] + acc;
    } else {
        int task = blk - 8704;
        int bb = task >> 8, tt = task & 255;
        int n0 = (tt >> 3) * 32, c0 = (tt & 7) * 32;
        const float* src = (bb < 2) ? (desc0 + (size_t)bb * DD * NN)
                                    : (desc1 + (size_t)(bb - 2) * DD * NN);
        int i = tid >> 5, j = tid & 31;
#pragma unroll
        for (int r = 0; r < 4; r++) {
            int c = i + r * 8;
            T[c][j] = src[(size_t)(c0 + c) * NN + n0 + j];
        }
        __syncthreads();
#pragma unroll
        for (int r = 0; r < 4; r++) {
            int n = i + r * 8;
            float v = T[j][n];
            size_t di = ((size_t)bb * NN + n0 + n) * DD + c0 + j;
            desc[di] = v;
            xbf[di] = f2bf(v);
        }
    }
}

// ---------------- fold1 (MFMA, bf16 inputs): W1m_perm[l][o][h*64+d] ----------------
__global__ __launch_bounds__(256) void fold1_kernel(const unsigned short* __restrict__ W1bf,
                                                    const unsigned short* __restrict__ Wmbf,
                                                    unsigned short* __restrict__ W1m) {
    int l = blockIdx.z;
    int o0 = blockIdx.x * 64, i0 = blockIdx.y * 64;
    const unsigned short* A = W1bf + (size_t)l * 262144;
    const unsigned short* B = Wmbf + (size_t)l * 65536;
    __shared__ unsigned short Bt[64][264];
    int t = threadIdx.x;
#pragma unroll
    for (int r = 0; r < 8; r++) {
        int j = r * 32 + (t >> 3);
        int il = (t & 7) * 8;
        union { bf16x8 v; unsigned short u[8]; } ld;
        ld.v = *(const bf16x8*)(B + (size_t)j * 256 + i0 + il);
#pragma unroll
        for (int jj = 0; jj < 8; jj++) Bt[il + jj][j] = ld.u[jj];
    }
    __syncthreads();
    int w = t >> 6, lane = t & 63, quad = lane >> 4, l15 = lane & 15;
    int wr = (w & 1) * 32, wc = (w >> 1) * 32;
    const unsigned short* Ab = A + (size_t)(o0 + wr + l15) * 512 + 256 + quad * 8;
    f32x4 acc[2][2];
#pragma unroll
    for (int r = 0; r < 2; r++)
#pragma unroll
        for (int c = 0; c < 2; c++) acc[r][c] = (f32x4){0.f, 0.f, 0.f, 0.f};
#pragma unroll
    for (int s = 0; s < 8; s++) {
        int kk = s * 32;
        bf16x8 a0 = *(const bf16x8*)(Ab + kk);
        bf16x8 a1 = *(const bf16x8*)(Ab + 16 * 512 + kk);
        bf16x8 b0 = *(const bf16x8*)(&Bt[wc + l15][kk + quad * 8]);
        bf16x8 b1 = *(const bf16x8*)(&Bt[wc + 16 + l15][kk + quad * 8]);
        acc[0][0] = mfma16(a0, b0, acc[0][0]);
        acc[0][1] = mfma16(a0, b1, acc[0][1]);
        acc[1][0] = mfma16(a1, b0, acc[1][0]);
        acc[1][1] = mfma16(a1, b1, acc[1][1]);
    }
#pragma unroll
    for (int rs = 0; rs < 2; rs++)
#pragma unroll
        for (int cs = 0; cs < 2; cs++)
#pragma unroll
            for (int reg = 0; reg < 4; reg++) {
                int o = o0 + wr + rs * 16 + quad * 4 + reg;
                int i = i0 + wc + cs * 16 + l15;
                int pc = (i & 3) * 64 + (i >> 2);
                W1m[((size_t)l * 512 + o) * 256 + pc] = f2bf(acc[rs][cs][reg]);
            }
}

// ---------------- final: [4][1024][256] -> [4][256][1024] via LDS tiles ----------------
__global__ __launch_bounds__(256) void final_kernel(const float* __restrict__ desc,
                                                    float* __restrict__ out) {
    __shared__ float T[32][33];
    int bb = blockIdx.z;
    int n0 = blockIdx.x * 32, c0 = blockIdx.y * 32;
    int i = threadIdx.x >> 5, j = threadIdx.x & 31;
#pragma unroll
    for (int r = 0; r < 4; r++) {
        int n = i + r * 8;
        T[n][j] = desc[((size_t)bb * NN + n0 + n) * DD + c0 + j];
    }
    __syncthreads();
#pragma unroll
    for (int r = 0; r < 4; r++) {
        int c = i + r * 8;
        out[((size_t)bb * DD + c0 + c) * NN + n0 + j] = T[j][c];
    }
}

// ---------------- proj: M=4096, N=768 (q|k|v), K=256; 64x64 tiles, swizzled staging ---
__global__ __launch_bounds__(256) void proj_kernel(
    const unsigned short* __restrict__ xbf,
    const unsigned short* __restrict__ Wq_l, const unsigned short* __restrict__ Wk_l,
    const unsigned short* __restrict__ Wv_l,
    const float* __restrict__ bq_l, const float* __restrict__ bk_l,
    const float* __restrict__ bv_l,
    unsigned short* __restrict__ qb, unsigned short* __restrict__ kb,
    unsigned short* __restrict__ vb, int cross) {
    __shared__ __align__(16) unsigned short sm[8192];
    unsigned short* Al = sm;
    unsigned short* Bl = sm + 4096;

    int m0 = blockIdx.x * 64;
    int by = blockIdx.y;
    int mat = by >> 2;
    int o0c = (by & 3) * 64;
    int bb = m0 >> 10, nloc0 = m0 & 1023;
    int srcbb = (mat == 0) ? bb : (cross ? (bb ^ 2) : bb);
    const unsigned short* A = xbf + (size_t)srcbb * NN * DD + (size_t)nloc0 * DD;
    const unsigned short* W = ((mat == 0) ? Wq_l : (mat == 1) ? Wk_l : Wv_l) + (size_t)o0c * DD;
    const float* bias = (mat == 0) ? bq_l : (mat == 1) ? bk_l : bv_l;

    int tid = threadIdx.x, w = tid >> 6, lane = tid & 63, quad = lane >> 4, l15 = lane & 15;
    int wrow = (w & 1) * 32, wcol = (w >> 1) * 32;
    int lrow = lane >> 3, chnk = lane & 7;

    f32x4 acc[2][2];
#pragma unroll
    for (int r = 0; r < 2; r++)
#pragma unroll
        for (int c = 0; c < 2; c++) acc[r][c] = (f32x4){0.f, 0.f, 0.f, 0.f};

    for (int ks = 0; ks < 4; ks++) {
        int k0 = ks * 64;
        __syncthreads();
#pragma unroll
        for (int j = 0; j < 2; j++) {
            int r = w * 16 + j * 8 + lrow;
            gll16(A + (size_t)r * DD + k0 + ((chnk ^ (r & 7)) * 8), Al + (w * 16 + j * 8) * 64);
            gll16(W + (size_t)r * DD + k0 + ((chnk ^ (r & 7)) * 8), Bl + (w * 16 + j * 8) * 64);
        }
        __syncthreads();
#pragma unroll
        for (int kh = 0; kh < 2; kh++) {
            bf16x8 bf[2], af[2];
#pragma unroll
            for (int cs = 0; cs < 2; cs++) {
                int rb = wcol + cs * 16 + l15;
                bf[cs] = *(const bf16x8*)(Bl + rb * 64 + (((kh * 4 + quad) ^ (rb & 7)) * 8));
            }
#pragma unroll
            for (int rs = 0; rs < 2; rs++) {
                int ra = wrow + rs * 16 + l15;
                af[rs] = *(const bf16x8*)(Al + ra * 64 + (((kh * 4 + quad) ^ (ra & 7)) * 8));
            }
#pragma unroll
            for (int rs = 0; rs < 2; rs++)
#pragma unroll
                for (int cs = 0; cs < 2; cs++)
                    acc[rs][cs] = mfma16(af[rs], bf[cs], acc[rs][cs]);
        }
    }
    __syncthreads();
    float qscale = (mat == 0) ? 0.1803368801f : 1.0f;   // 0.125 * log2(e) for q
    if (mat < 2) {
#pragma unroll
        for (int rs = 0; rs < 2; rs++)
#pragma unroll
            for (int cs = 0; cs < 2; cs++) {
                int op = o0c + wcol + cs * 16 + l15;
                float bv4 = bias[((op & 63) << 2) | (op >> 6)];
#pragma unroll
                for (int reg = 0; reg < 4; reg++)
                    sm[(wrow + rs * 16 + quad * 4 + reg) * 72 + wcol + cs * 16 + l15] =
                        f2bf((acc[rs][cs][reg] + bv4) * qscale);
            }
        __syncthreads();
        int r = tid >> 2, ch = (tid & 3) * 16;
        unsigned short* dst = ((mat == 0) ? qb : kb) + ((size_t)(bb * NN) + nloc0 + r) * 256 + o0c + ch;
        *(bf16x8*)(dst) = *(const bf16x8*)(&sm[r * 72 + ch]);
        *(bf16x8*)(dst + 8) = *(const bf16x8*)(&sm[r * 72 + ch + 8]);
    } else {
#pragma unroll
        for (int rs = 0; rs < 2; rs++)
#pragma unroll
            for (int cs = 0; cs < 2; cs++) {
                int op = o0c + wcol + cs * 16 + l15;
                float bv4 = bias[((op & 63) << 2) | (op >> 6)];
#pragma unroll
                for (int reg = 0; reg < 4; reg++)
                    sm[(wcol + cs * 16 + l15) * 72 + wrow + rs * 16 + quad * 4 + reg] =
                        f2bf(acc[rs][cs][reg] + bv4);
            }
        __syncthreads();
        int o = tid >> 2, nch = (tid & 3) * 16;
        int opg = o0c + o;
        unsigned short* dst = vb + ((size_t)(bb * 4 + (opg >> 6)) * 64 + (opg & 63)) * NN + nloc0 + nch;
        *(bf16x8*)(dst) = *(const bf16x8*)(&sm[o * 72 + nch]);
        *(bf16x8*)(dst + 8) = *(const bf16x8*)(&sm[o * 72 + nch + 8]);
    }
}

// ---------------- flash: 4 waves/block, wave = m-split, 2 q-groups per wave -----------
__global__ __launch_bounds__(256, 2) void flash_kernel(
    const unsigned short* __restrict__ qb, const unsigned short* __restrict__ kb,
    const unsigned short* __restrict__ vb,
    const unsigned short* __restrict__ maskbf,
    unsigned short* __restrict__ xattn, float* __restrict__ bnsumm) {
    __shared__ __align__(16) char smem[51200];
    unsigned short* Plds = (unsigned short*)smem;
    float* OL = (float*)smem;

    int bh = blockIdx.y, nb = blockIdx.x;
    int bb = bh >> 2, h = bh & 3;
    int tid = threadIdx.x, w = tid >> 6, lane = tid & 63, quad = lane >> 4, l15 = lane & 15;

    if (nb == 0 && bh == 0) {
        bnsumm[tid] = 0.f; bnsumm[tid + 256] = 0.f;
        bnsumm[tid + 512] = 0.f; bnsumm[tid + 768] = 0.f;
    }

    const unsigned short* mask = maskbf + (size_t)bb * NN * NN;
    const unsigned short* Q = qb + (size_t)bb * NN * 256 + h * 64;
    const unsigned short* Kb = kb + (size_t)bb * NN * 256 + h * 64;
    const unsigned short* Vb = vb + (size_t)bh * 64 * NN;
    int row0 = nb * 32;

    bf16x8 qf[2][2];
#pragma unroll
    for (int s = 0; s < 2; s++)
#pragma unroll
        for (int kc = 0; kc < 2; kc++)
            qf[s][kc] = *(const bf16x8*)(Q + (size_t)(row0 + s * 16 + l15) * 256 + kc * 32 + quad * 8);

    const unsigned short* mrow[2][4];
#pragma unroll
    for (int s = 0; s < 2; s++)
#pragma unroll
        for (int reg = 0; reg < 4; reg++)
            mrow[s][reg] = mask + (size_t)(row0 + s * 16 + quad * 4 + reg) * NN + w * 256;

    f32x4 Oa[2][4];
#pragma unroll
    for (int s = 0; s < 2; s++)
#pragma unroll
        for (int dt = 0; dt < 4; dt++) Oa[s][dt] = (f32x4){0.f, 0.f, 0.f, 0.f};
    float mrun[2][4], lrun[2][4];
#pragma unroll
    for (int s = 0; s < 2; s++)
#pragma unroll
        for (int r = 0; r < 4; r++) { mrun[s][r] = -1e30f; lrun[s][r] = 0.f; }

    unsigned short* Pw = Plds + w * (16 * 72);

    for (int mt = 0; mt < 4; mt++) {
        int ml = mt * 64;
        int m0 = w * 256 + ml;
        f32x4 sA[4], sB[4];
#pragma unroll
        for (int t = 0; t < 4; t++) {
            sA[t] = (f32x4){0.f, 0.f, 0.f, 0.f};
            sB[t] = (f32x4){0.f, 0.f, 0.f, 0.f};
        }
#pragma unroll
        for (int t = 0; t < 4; t++)
#pragma unroll
            for (int kc = 0; kc < 2; kc++) {
                bf16x8 kf = *(const bf16x8*)(Kb + (size_t)(m0 + t * 16 + l15) * 256 + kc * 32 + quad * 8);
                sA[t] = mfma16(qf[0][kc], kf, sA[t]);
                sB[t] = mfma16(qf[1][kc], kf, sB[t]);
            }
        bf16x8 vf[8];
#pragma unroll
        for (int dt = 0; dt < 4; dt++)
#pragma unroll
            for (int kc = 0; kc < 2; kc++)
                vf[dt * 2 + kc] = *(const bf16x8*)(Vb + (size_t)(dt * 16 + l15) * NN + m0 + kc * 32 + quad * 8);
#pragma unroll
        for (int s = 0; s < 2; s++) {
            float sv[4][4], rmax[4];
#pragma unroll
            for (int r = 0; r < 4; r++) rmax[r] = -1e30f;
#pragma unroll
            for (int t = 0; t < 4; t++)
#pragma unroll
                for (int reg = 0; reg < 4; reg++) {
                    float sc = (s == 0) ? sA[t][reg] : sB[t][reg];
                    float v = sc * bf2f(mrow[s][reg][ml + t * 16 + l15]);
                    sv[t][reg] = v;
                    rmax[reg] = fmaxf(rmax[reg], v);
                }
#pragma unroll
            for (int reg = 0; reg < 4; reg++) {
                rmax[reg] = fmaxf(rmax[reg], __shfl_xor(rmax[reg], 1, 64));
                rmax[reg] = fmaxf(rmax[reg], __shfl_xor(rmax[reg], 2, 64));
                rmax[reg] = fmaxf(rmax[reg], __shfl_xor(rmax[reg], 4, 64));
                rmax[reg] = fmaxf(rmax[reg], __shfl_xor(rmax[reg], 8, 64));
            }
            float alpha[4], rsum[4];
#pragma unroll
            for (int reg = 0; reg < 4; reg++) {
                float mn = fmaxf(mrun[s][reg], rmax[reg]);
                alpha[reg] = exp2f(mrun[s][reg] - mn);
                mrun[s][reg] = mn;
                rsum[reg] = 0.f;
            }
#pragma unroll
            for (int t = 0; t < 4; t++)
#pragma unroll
                for (int reg = 0; reg < 4; reg++) {
                    float p = exp2f(sv[t][reg] - mrun[s][reg]);
                    sv[t][reg] = p;
                    rsum[reg] += p;
                }
#pragma unroll
            for (int reg = 0; reg < 4; reg++) {
                rsum[reg] += __shfl_xor(rsum[reg], 1, 64);
                rsum[reg] += __shfl_xor(rsum[reg], 2, 64);
                rsum[reg] += __shfl_xor(rsum[reg], 4, 64);
                rsum[reg] += __shfl_xor(rsum[reg], 8, 64);
                lrun[s][reg] = lrun[s][reg] * alpha[reg] + rsum[reg];
            }
#pragma unroll
            for (int dt = 0; dt < 4; dt++)
#pragma unroll
                for (int reg = 0; reg < 4; reg++) Oa[s][dt][reg] *= alpha[reg];
#pragma unroll
            for (int t = 0; t < 4; t++)
#pragma unroll
                for (int reg = 0; reg < 4; reg++)
                    Pw[(quad * 4 + reg) * 72 + t * 16 + l15] = f2bf_trunc(sv[t][reg]);
            bf16x8 pf[2];
#pragma unroll
            for (int kc = 0; kc < 2; kc++)
                pf[kc] = *(const bf16x8*)(Pw + l15 * 72 + kc * 32 + quad * 8);
#pragma unroll
            for (int dt = 0; dt < 4; dt++)
#pragma unroll
                for (int kc = 0; kc < 2; kc++)
                    Oa[s][dt] = mfma16(pf[kc], vf[dt * 2 + kc], Oa[s][dt]);
        }
    }
    __syncthreads();
#pragma unroll
    for (int s = 0; s < 2; s++) {
        float* mine = OL + (size_t)((s + 2 * w) * 64 + lane) * 25;
#pragma unroll
        for (int dt = 0; dt < 4; dt++)
#pragma unroll
            for (int reg = 0; reg < 4; reg++) mine[dt * 4 + reg] = Oa[s][dt][reg];
#pragma unroll
        for (int reg = 0; reg < 4; reg++) { mine[16 + reg] = mrun[s][reg]; mine[20 + reg] = lrun[s][reg]; }
    }
    __syncthreads();
    if (w < 2) {
        const float* p[4];
#pragma unroll
        for (int j = 0; j < 4; j++) p[j] = OL + (size_t)((w + 2 * j) * 64 + lane) * 25;
        float e[4][4], li[4];
#pragma unroll
        for (int reg = 0; reg < 4; reg++) {
            float M = fmaxf(fmaxf(p[0][16 + reg], p[1][16 + reg]),
                            fmaxf(p[2][16 + reg], p[3][16 + reg]));
            float L = 0.f;
#pragma unroll
            for (int j = 0; j < 4; j++) {
                e[j][reg] = exp2f(p[j][16 + reg] - M);
                L += p[j][20 + reg] * e[j][reg];
            }
            li[reg] = 1.f / L;
        }
#pragma unroll
        for (int dt = 0; dt < 4; dt++)
#pragma unroll
            for (int reg = 0; reg < 4; reg++) {
                float val = 0.f;
#pragma unroll
                for (int j = 0; j < 4; j++) val += p[j][dt * 4 + reg] * e[j][reg];
                val *= li[reg];
                int n = row0 + w * 16 + quad * 4 + reg;
                int col = h * 64 + dt * 16 + l15;
                xattn[((size_t)bb * NN + n) * DD + col] = f2bf(val);
            }
    }
}

// ---------------- conv1: M=4096, N=512, K=512 (x|attn); swizzled staging + BN stats ---
__global__ __launch_bounds__(256) void conv1_kernel(
    const unsigned short* __restrict__ xbf, const unsigned short* __restrict__ xattn,
    const unsigned short* __restrict__ W1_l, const unsigned short* __restrict__ W1m_l,
    const float* __restrict__ bmix_l,
    unsigned short* __restrict__ out1, float* __restrict__ bnsumm) {
    __shared__ __align__(16) unsigned short sm[8192];
    unsigned short* Al = sm;
    unsigned short* Bl = sm + 4096;

    int m0 = blockIdx.x * 64, o0 = blockIdx.y * 64;
    int bb = m0 >> 10, nloc0 = m0 & 1023;
    const unsigned short* A1 = xbf + (size_t)bb * NN * DD + (size_t)nloc0 * DD;
    const unsigned short* A2 = xattn + (size_t)bb * NN * DD + (size_t)nloc0 * DD;

    int tid = threadIdx.x, w = tid >> 6, lane = tid & 63, quad = lane >> 4, l15 = lane & 15;
    int wrow = (w & 1) * 32, wcol = (w >> 1) * 32;
    int lrow = lane >> 3, chnk = lane & 7;

    f32x4 acc[2][2];
#pragma unroll
    for (int r = 0; r < 2; r++)
#pragma unroll
        for (int c = 0; c < 2; c++) acc[r][c] = (f32x4){0.f, 0.f, 0.f, 0.f};

    for (int ks = 0; ks < 8; ks++) {
        const unsigned short* As = (ks < 4) ? A1 : A2;
        int kloc = (ks & 3) * 64;
        __syncthreads();
#pragma unroll
        for (int j = 0; j < 2; j++) {
            int r = w * 16 + j * 8 + lrow;
            gll16(As + (size_t)r * DD + kloc + ((chnk ^ (r & 7)) * 8), Al + (w * 16 + j * 8) * 64);
            int orow = o0 + r;
            const unsigned short* bg = (ks < 4)
                ? (W1_l + (size_t)orow * 512 + ks * 64 + ((chnk ^ (r & 7)) * 8))
                : (W1m_l + (size_t)orow * 256 + (ks - 4) * 64 + ((chnk ^ (r & 7)) * 8));
            gll16(bg, Bl + (w * 16 + j * 8) * 64);
        }
        __syncthreads();
#pragma unroll
        for (int kh = 0; kh < 2; kh++) {
            bf16x8 bf[2], af[2];
#pragma unroll
            for (int cs = 0; cs < 2; cs++) {
                int rb = wcol + cs * 16 + l15;
                bf[cs] = *(const bf16x8*)(Bl + rb * 64 + (((kh * 4 + quad) ^ (rb & 7)) * 8));
            }
#pragma unroll
            for (int rs = 0; rs < 2; rs++) {
                int ra = wrow + rs * 16 + l15;
                af[rs] = *(const bf16x8*)(Al + ra * 64 + (((kh * 4 + quad) ^ (ra & 7)) * 8));
            }
#pragma unroll
            for (int rs = 0; rs < 2; rs++)
#pragma unroll
                for (int cs = 0; cs < 2; cs++)
                    acc[rs][cs] = mfma16(af[rs], bf[cs], acc[rs][cs]);
        }
    }
    __syncthreads();
    float cs_s[2] = {0.f, 0.f}, cs_q[2] = {0.f, 0.f};
#pragma unroll
    for (int rs = 0; rs < 2; rs++)
#pragma unroll
        for (int cs = 0; cs < 2; cs++) {
            int o = o0 + wcol + cs * 16 + l15;
            float bvx = bmix_l[o];
#pragma unroll
            for (int reg = 0; reg < 4; reg++) {
                float val = acc[rs][cs][reg] + bvx;
                sm[(wrow + rs * 16 + quad * 4 + reg) * 72 + wcol + cs * 16 + l15] = f2bf(val);
                cs_s[cs] += val;
                cs_q[cs] += val * val;
            }
        }
#pragma unroll
    for (int cs = 0; cs < 2; cs++) {
        cs_s[cs] += __shfl_xor(cs_s[cs], 16, 64);
        cs_s[cs] += __shfl_xor(cs_s[cs], 32, 64);
        cs_q[cs] += __shfl_xor(cs_q[cs], 16, 64);
        cs_q[cs] += __shfl_xor(cs_q[cs], 32, 64);
    }
    if (lane < 16) {
#pragma unroll
        for (int cs = 0; cs < 2; cs++) {
            atomicAdd(&bnsumm[o0 + wcol + cs * 16 + lane], cs_s[cs]);
            atomicAdd(&bnsumm[512 + o0 + wcol + cs * 16 + lane], cs_q[cs]);
        }
    }
    __syncthreads();
    int r = tid >> 2, ch = (tid & 3) * 16;
    unsigned short* dst = out1 + ((size_t)(bb * NN) + nloc0 + r) * 512 + o0 + ch;
    *(bf16x8*)(dst) = *(const bf16x8*)(&sm[r * 72 + ch]);
    *(bf16x8*)(dst + 8) = *(const bf16x8*)(&sm[r * 72 + ch + 8]);
}

// ---------------- conv2: GEMM M=4096, N=256, K=512 with fused BN+ReLU A-staging -------
// BN finalize per block (LDS); A staged via register loads + transform + swizzled
// ds_write (once per element); B via gll16. Residual epilogue.
__global__ __launch_bounds__(256) void conv2_kernel(
    const unsigned short* __restrict__ out1, const unsigned short* __restrict__ W2_l,
    const float* __restrict__ b2_l, const float* __restrict__ bnsumm,
    const float* __restrict__ g1_l, const float* __restrict__ beta1_l,
    float* __restrict__ desc, unsigned short* __restrict__ xbf) {
    __shared__ __align__(16) unsigned short Al[2048];
    __shared__ __align__(16) unsigned short Bl[4096];
    __shared__ float ssc[512], ssh[512];

    int tid = threadIdx.x;
    for (int i = tid; i < 512; i += 256) {
        float s = bnsumm[i], s2 = bnsumm[512 + i];
        float mean = s * (1.f / 4096.f);
        float var = s2 * (1.f / 4096.f) - mean * mean;
        float sc = g1_l[i] * rsqrtf(var + 1e-5f);
        ssc[i] = sc;
        ssh[i] = beta1_l[i] - mean * sc;
    }

    int m0 = blockIdx.x * 32, o0 = blockIdx.y * 64;
    int bb = m0 >> 10, nloc0 = m0 & 1023;
    const unsigned short* A = out1 + ((size_t)(bb * NN) + nloc0) * 512;

    int w = tid >> 6, lane = tid & 63, quad = lane >> 4, l15 = lane & 15;
    int wr = (w & 1) * 16, wc = (w >> 1) * 32;
    int lrow = lane >> 3, chnk = lane & 7;
    int ar = tid >> 3, ap = tid & 7;   // A staging: row 0..31, physical chunk 0..7

    f32x4 acc[2];
    acc[0] = (f32x4){0.f, 0.f, 0.f, 0.f};
    acc[1] = (f32x4){0.f, 0.f, 0.f, 0.f};

    for (int ks = 0; ks < 8; ks++) {
        int k0 = ks * 64;
        __syncthreads();   // also covers ssc/ssh readiness at ks=0
        // B staging via gll16 (swizzled)
#pragma unroll
        for (int j = 0; j < 2; j++) {
            int r = w * 16 + j * 8 + lrow;
            gll16(W2_l + (size_t)(o0 + r) * 512 + k0 + ((chnk ^ (r & 7)) * 8),
                  Bl + (w * 16 + j * 8) * 64);
        }
        // A staging: load, BN+ReLU, swizzled ds_write (1 elem-group per thread)
        {
            int lc = (ap ^ (ar & 7)) * 8;   // logical chunk for this physical slot
            union { bf16x8 v; unsigned short u[8]; } in, tr;
            in.v = *(const bf16x8*)(A + (size_t)ar * 512 + k0 + lc);
#pragma unroll
            for (int j = 0; j < 8; j++) {
                int ch = k0 + lc + j;
                tr.u[j] = f2bf(fmaxf(0.f, bf2f(in.u[j]) * ssc[ch] + ssh[ch]));
            }
            *(bf16x8*)(Al + ar * 64 + ap * 8) = tr.v;
        }
        __syncthreads();
#pragma unroll
        for (int kh = 0; kh < 2; kh++) {
            int ra = wr + l15;
            bf16x8 af = *(const bf16x8*)(Al + ra * 64 + (((kh * 4 + quad) ^ (ra & 7)) * 8));
#pragma unroll
            for (int cs = 0; cs < 2; cs++) {
                int rb = wc + cs * 16 + l15;
                bf16x8 bf = *(const bf16x8*)(Bl + rb * 64 + (((kh * 4 + quad) ^ (rb & 7)) * 8));
                acc[cs] = mfma16(af, bf, acc[cs]);
            }
        }
    }
#pragma unroll
    for (int cs = 0; cs < 2; cs++)
#pragma unroll
        for (int reg = 0; reg < 4; reg++) {
            int n = nloc0 + wr + quad * 4 + reg;
            int o = o0 + wc + cs * 16 + l15;
            size_t di = ((size_t)bb * NN + n) * DD + o;
            float nd = desc[di] + acc[cs][reg] + b2_l[o];
            desc[di] = nd;
            xbf[di] = f2bf(nd);
        }
}

extern "C" void kernel_launch(void* const* d_in, const int* in_sizes, int n_in,
                              void* d_out, int out_size, void* d_ws, size_t ws_size,
                              hipStream_t stream) {
    const float* desc0 = (const float*)d_in[0];
    const float* desc1 = (const float*)d_in[1];
    const float* M0p   = (const float*)d_in[2];
    const float* M1p   = (const float*)d_in[3];
    const float* Wq = (const float*)d_in[4];  const float* bq = (const float*)d_in[5];
    const float* Wk = (const float*)d_in[6];  const float* bk = (const float*)d_in[7];
    const float* Wv = (const float*)d_in[8];  const float* bv = (const float*)d_in[9];
    const float* Wm = (const float*)d_in[10]; const float* bm = (const float*)d_in[11];
    const float* W1 = (const float*)d_in[12]; const float* b1 = (const float*)d_in[13];
    const float* g1 = (const float*)d_in[14]; const float* beta1 = (const float*)d_in[15];
    const float* W2 = (const float*)d_in[16]; const float* b2 = (const float*)d_in[17];
    float* out = (float*)d_out;
    char* ws = (char*)d_ws;

    float*          desc   = (float*)(ws);
    unsigned short* xbf    = (unsigned short*)(ws + (4ull << 20));
    unsigned short* qb     = (unsigned short*)(ws + (6ull << 20));
    unsigned short* kbuf   = (unsigned short*)(ws + (8ull << 20));
    unsigned short* vbuf   = (unsigned short*)(ws + (10ull << 20));
    unsigned short* xattn  = (unsigned short*)(ws + (12ull << 20));
    unsigned short* out1   = (unsigned short*)(ws + (14ull << 20));
    float*          bnsumm = (float*)(ws + (18ull << 20));
    float*          bmix   = (float*)(ws + (18ull << 20) + 8192);
    unsigned short* maskbf = (unsigned short*)(ws + (19ull << 20));
    unsigned short* W1m    = (unsigned short*)(ws + (27ull << 20));
    unsigned short* wbf    = (unsigned short*)(ws + (29ull << 20));

    const int SQ = LL * 65536;

    prep_kernel<<<9728, 256, 0, stream>>>(desc0, desc1, M0p, M1p, Wq, Wk, Wv, Wm,
                                          W1, W2, bm, b1, wbf, maskbf, bmix, desc, xbf);
    fold1_kernel<<<dim3(8, 4, 6), 256, 0, stream>>>(wbf + 4 * (size_t)SQ, wbf + 3 * (size_t)SQ, W1m);

    for (int l = 0; l < LL; l++) {
        int cross = l & 1;
        const unsigned short* Wq_l = wbf + (size_t)l * 65536;
        const unsigned short* Wk_l = wbf + SQ + (size_t)l * 65536;
        const unsigned short* Wv_l = wbf + 2 * (size_t)SQ + (size_t)l * 65536;
        const unsigned short* W1_l = wbf + 4 * (size_t)SQ + (size_t)l * 262144;
        const unsigned short* W2_l = wbf + 4 * (size_t)SQ + (size_t)LL * 262144 + (size_t)l * 131072;
        const unsigned short* W1m_l = W1m + (size_t)l * 131072;

        proj_kernel<<<dim3(64, 12), 256, 0, stream>>>(
            xbf, Wq_l, Wk_l, Wv_l, bq + l * 256, bk + l * 256, bv + l * 256,
            qb, kbuf, vbuf, cross);
        flash_kernel<<<dim3(32, 16), 256, 0, stream>>>(qb, kbuf, vbuf, maskbf, xattn, bnsumm);
        conv1_kernel<<<dim3(64, 8), 256, 0, stream>>>(
            xbf, xattn, W1_l, W1m_l, bmix + l * 512, out1, bnsumm);
        conv2_kernel<<<dim3(128, 4), 256, 0, stream>>>(
            out1, W2_l, b2 + l * 256, bnsumm, g1 + l * 512, beta1 + l * 512, desc, xbf);
    }

    final_kernel<<<dim3(32, 8, 4), 256, 0, stream>>>(desc, out);
}

// Round 15
// 432.247 us; speedup vs baseline: 1.2437x; 1.0106x over previous
//
#include <hip/hip_runtime.h>
#include <hip/hip_bf16.h>

#define NN 1024
#define DD 256
#define LL 6

typedef __attribute__((ext_vector_type(8))) short bf16x8;
typedef __attribute__((ext_vector_type(4))) float f32x4;
typedef __attribute__((ext_vector_type(4))) unsigned short u16x4;

__device__ __forceinline__ unsigned short f2bf(float f) {
    union { float f; unsigned u; } x; x.f = f;
    return (unsigned short)((x.u + 0x7fffu + ((x.u >> 16) & 1u)) >> 16);
}

__device__ __forceinline__ unsigned short f2bf_trunc(float f) {
    union { float f; unsigned u; } x; x.f = f;
    return (unsigned short)(x.u >> 16);
}

__device__ __forceinline__ float bf2f(unsigned short u) {
    union { unsigned u; float f; } x; x.u = ((unsigned)u) << 16; return x.f;
}

__device__ __forceinline__ f32x4 mfma16(bf16x8 a, bf16x8 b, f32x4 c) {
    return __builtin_amdgcn_mfma_f32_16x16x32_bf16(a, b, c, 0, 0, 0);
}

// async global->LDS, 16B per lane; lds dest = wave-uniform base + lane*16
__device__ __forceinline__ void gll16(const unsigned short* g, unsigned short* l) {
    __builtin_amdgcn_global_load_lds(
        (const __attribute__((address_space(1))) unsigned int*)g,
        (__attribute__((address_space(3))) unsigned int*)l, 16, 0, 0);
}

// ---------------- prep: wconv(vec4) | maskconv | fold2 | init, block-partitioned ------
__global__ __launch_bounds__(256) void prep_kernel(
    const float* __restrict__ desc0, const float* __restrict__ desc1,
    const float* __restrict__ M0, const float* __restrict__ M1,
    const float* __restrict__ Wq, const float* __restrict__ Wk,
    const float* __restrict__ Wv, const float* __restrict__ Wm,
    const float* __restrict__ W1, const float* __restrict__ W2,
    const float* __restrict__ bm, const float* __restrict__ b1,
    unsigned short* __restrict__ wbf, unsigned short* __restrict__ maskbf,
    float* __restrict__ bmix, float* __restrict__ desc, unsigned short* __restrict__ xbf) {
    __shared__ float T[32][33];
    const int SQ = LL * 65536;
    const int S1 = LL * 262144;
    int blk = blockIdx.x, tid = threadIdx.x;
    if (blk < 3840) {
        int idx = blk * 256 + tid;
        size_t base = (size_t)idx * 4;
        f32x4 v;
        if (base < (size_t)4 * SQ) {
            int seg = (int)(base / SQ), off = (int)(base % SQ);
            const float* p = (seg == 0) ? Wq : (seg == 1) ? Wk : (seg == 2) ? Wv : Wm;
            if (seg < 3) {
                int l = off >> 16, rem = off & 65535;
                int op = rem >> 8, i = rem & 255;
                int src = ((op & 63) << 2) | (op >> 6);
                v = *(const f32x4*)(p + (size_t)l * 65536 + (size_t)src * 256 + i);
            } else {
                v = *(const f32x4*)(p + off);
            }
        } else if (base < (size_t)4 * SQ + S1) {
            v = *(const f32x4*)(W1 + base - 4 * SQ);
        } else {
            v = *(const f32x4*)(W2 + base - 4 * SQ - S1);
        }
        u16x4 o;
#pragma unroll
        for (int j = 0; j < 4; j++) o[j] = f2bf(v[j]);
        *(u16x4*)(wbf + base) = o;
    } else if (blk < 7936) {
        int idx = (blk - 3840) * 256 + tid;
        size_t base = (size_t)idx * 4;
        int bb = (int)(base >> 20);
        const float* src = (bb < 2) ? (M0 + base) : (M1 + base - (2ull << 20));
        f32x4 v = *(const f32x4*)src;
        u16x4 o;
#pragma unroll
        for (int j = 0; j < 4; j++) o[j] = f2bf(v[j]);
        *(u16x4*)(maskbf + base) = o;
    } else if (blk < 8704) {
        int lane = tid & 63;
        int wid = (blk - 7936) * 4 + (tid >> 6);
        int l = wid >> 9, o = wid & 511;
        const float* row = W1 + ((size_t)l * 512 + o) * 512 + 256;
        const float* bmr = bm + (size_t)l * 256;
        f32x4 r = *(const f32x4*)(row + lane * 4);
        f32x4 b4 = *(const f32x4*)(bmr + lane * 4);
        float acc = r[0] * b4[0] + r[1] * b4[1] + r[2] * b4[2] + r[3] * b4[3];
        acc += __shfl_xor(acc, 1, 64);
        acc += __shfl_xor(acc, 2, 64);
        acc += __shfl_xor(acc, 4, 64);
        acc += __shfl_xor(acc, 8, 64);
        acc += __shfl_xor(acc, 16, 64);
        acc += __shfl_xor(acc, 32, 64);
        if (lane == 0) bmix[wid] = b1[wid] + acc;
    } else {
        int task = blk - 8704;
        int bb = task >> 8, tt = task & 255;
        int n0 = (tt >> 3) * 32, c0 = (tt & 7) * 32;
        const float* src = (bb < 2) ? (desc0 + (size_t)bb * DD * NN)
                                    : (desc1 + (size_t)(bb - 2) * DD * NN);
        int i = tid >> 5, j = tid & 31;
#pragma unroll
        for (int r = 0; r < 4; r++) {
            int c = i + r * 8;
            T[c][j] = src[(size_t)(c0 + c) * NN + n0 + j];
        }
        __syncthreads();
#pragma unroll
        for (int r = 0; r < 4; r++) {
            int n = i + r * 8;
            float v = T[j][n];
            size_t di = ((size_t)bb * NN + n0 + n) * DD + c0 + j;
            desc[di] = v;
            xbf[di] = f2bf(v);
        }
    }
}

// ---------------- fold1 (MFMA, bf16 inputs): W1m_perm[l][o][h*64+d] ----------------
__global__ __launch_bounds__(256) void fold1_kernel(const unsigned short* __restrict__ W1bf,
                                                    const unsigned short* __restrict__ Wmbf,
                                                    unsigned short* __restrict__ W1m) {
    int l = blockIdx.z;
    int o0 = blockIdx.x * 64, i0 = blockIdx.y * 64;
    const unsigned short* A = W1bf + (size_t)l * 262144;
    const unsigned short* B = Wmbf + (size_t)l * 65536;
    __shared__ unsigned short Bt[64][264];
    int t = threadIdx.x;
#pragma unroll
    for (int r = 0; r < 8; r++) {
        int j = r * 32 + (t >> 3);
        int il = (t & 7) * 8;
        union { bf16x8 v; unsigned short u[8]; } ld;
        ld.v = *(const bf16x8*)(B + (size_t)j * 256 + i0 + il);
#pragma unroll
        for (int jj = 0; jj < 8; jj++) Bt[il + jj][j] = ld.u[jj];
    }
    __syncthreads();
    int w = t >> 6, lane = t & 63, quad = lane >> 4, l15 = lane & 15;
    int wr = (w & 1) * 32, wc = (w >> 1) * 32;
    const unsigned short* Ab = A + (size_t)(o0 + wr + l15) * 512 + 256 + quad * 8;
    f32x4 acc[2][2];
#pragma unroll
    for (int r = 0; r < 2; r++)
#pragma unroll
        for (int c = 0; c < 2; c++) acc[r][c] = (f32x4){0.f, 0.f, 0.f, 0.f};
#pragma unroll
    for (int s = 0; s < 8; s++) {
        int kk = s * 32;
        bf16x8 a0 = *(const bf16x8*)(Ab + kk);
        bf16x8 a1 = *(const bf16x8*)(Ab + 16 * 512 + kk);
        bf16x8 b0 = *(const bf16x8*)(&Bt[wc + l15][kk + quad * 8]);
        bf16x8 b1 = *(const bf16x8*)(&Bt[wc + 16 + l15][kk + quad * 8]);
        acc[0][0] = mfma16(a0, b0, acc[0][0]);
        acc[0][1] = mfma16(a0, b1, acc[0][1]);
        acc[1][0] = mfma16(a1, b0, acc[1][0]);
        acc[1][1] = mfma16(a1, b1, acc[1][1]);
    }
#pragma unroll
    for (int rs = 0; rs < 2; rs++)
#pragma unroll
        for (int cs = 0; cs < 2; cs++)
#pragma unroll
            for (int reg = 0; reg < 4; reg++) {
                int o = o0 + wr + rs * 16 + quad * 4 + reg;
                int i = i0 + wc + cs * 16 + l15;
                int pc = (i & 3) * 64 + (i >> 2);
                W1m[((size_t)l * 512 + o) * 256 + pc] = f2bf(acc[rs][cs][reg]);
            }
}

// ---------------- final: [4][1024][256] -> [4][256][1024] via LDS tiles ----------------
__global__ __launch_bounds__(256) void final_kernel(const float* __restrict__ desc,
                                                    float* __restrict__ out) {
    __shared__ float T[32][33];
    int bb = blockIdx.z;
    int n0 = blockIdx.x * 32, c0 = blockIdx.y * 32;
    int i = threadIdx.x >> 5, j = threadIdx.x & 31;
#pragma unroll
    for (int r = 0; r < 4; r++) {
        int n = i + r * 8;
        T[n][j] = desc[((size_t)bb * NN + n0 + n) * DD + c0 + j];
    }
    __syncthreads();
#pragma unroll
    for (int r = 0; r < 4; r++) {
        int c = i + r * 8;
        out[((size_t)bb * DD + c0 + c) * NN + n0 + j] = T[j][c];
    }
}

// ---------------- proj: M=4096, N=768 (q|k|v), K=256; 64x64 tiles, BK=128 staging -----
// LDS rows 256B (2 bank wraps); swizzle over 16 chunks: phys = log ^ (row & 15).
__global__ __launch_bounds__(256) void proj_kernel(
    const unsigned short* __restrict__ xbf,
    const unsigned short* __restrict__ Wq_l, const unsigned short* __restrict__ Wk_l,
    const unsigned short* __restrict__ Wv_l,
    const float* __restrict__ bq_l, const float* __restrict__ bk_l,
    const float* __restrict__ bv_l,
    unsigned short* __restrict__ qb, unsigned short* __restrict__ kb,
    unsigned short* __restrict__ vb, int cross) {
    __shared__ __align__(16) unsigned short sm[16384];   // Al 8192 | Bl 8192 ; St reuses
    unsigned short* Al = sm;
    unsigned short* Bl = sm + 8192;

    int m0 = blockIdx.x * 64;
    int by = blockIdx.y;
    int mat = by >> 2;
    int o0c = (by & 3) * 64;
    int bb = m0 >> 10, nloc0 = m0 & 1023;
    int srcbb = (mat == 0) ? bb : (cross ? (bb ^ 2) : bb);
    const unsigned short* A = xbf + (size_t)srcbb * NN * DD + (size_t)nloc0 * DD;
    const unsigned short* W = ((mat == 0) ? Wq_l : (mat == 1) ? Wk_l : Wv_l) + (size_t)o0c * DD;
    const float* bias = (mat == 0) ? bq_l : (mat == 1) ? bk_l : bv_l;

    int tid = threadIdx.x, w = tid >> 6, lane = tid & 63, quad = lane >> 4, l15 = lane & 15;
    int wrow = (w & 1) * 32, wcol = (w >> 1) * 32;
    int lrow4 = lane >> 4, lchnk = lane & 15;   // 4 rows / gll16, 16 chunks per 128-row

    f32x4 acc[2][2];
#pragma unroll
    for (int r = 0; r < 2; r++)
#pragma unroll
        for (int c = 0; c < 2; c++) acc[r][c] = (f32x4){0.f, 0.f, 0.f, 0.f};

    for (int ks = 0; ks < 2; ks++) {
        int k0 = ks * 128;
        __syncthreads();
#pragma unroll
        for (int j = 0; j < 4; j++) {
            int r = w * 16 + j * 4 + lrow4;
            int lc = (lchnk ^ (r & 15)) * 8;
            gll16(A + (size_t)r * DD + k0 + lc, Al + (w * 16 + j * 4) * 128);
            gll16(W + (size_t)r * DD + k0 + lc, Bl + (w * 16 + j * 4) * 128);
        }
        __syncthreads();
#pragma unroll
        for (int kh = 0; kh < 4; kh++) {
            bf16x8 bf[2], af[2];
#pragma unroll
            for (int cs = 0; cs < 2; cs++) {
                int rb = wcol + cs * 16 + l15;
                bf[cs] = *(const bf16x8*)(Bl + rb * 128 + (((kh * 4 + quad) ^ (rb & 15)) * 8));
            }
#pragma unroll
            for (int rs = 0; rs < 2; rs++) {
                int ra = wrow + rs * 16 + l15;
                af[rs] = *(const bf16x8*)(Al + ra * 128 + (((kh * 4 + quad) ^ (ra & 15)) * 8));
            }
#pragma unroll
            for (int rs = 0; rs < 2; rs++)
#pragma unroll
                for (int cs = 0; cs < 2; cs++)
                    acc[rs][cs] = mfma16(af[rs], bf[cs], acc[rs][cs]);
        }
    }
    __syncthreads();
    float qscale = (mat == 0) ? 0.1803368801f : 1.0f;   // 0.125 * log2(e) for q
    if (mat < 2) {
#pragma unroll
        for (int rs = 0; rs < 2; rs++)
#pragma unroll
            for (int cs = 0; cs < 2; cs++) {
                int op = o0c + wcol + cs * 16 + l15;
                float bv4 = bias[((op & 63) << 2) | (op >> 6)];
#pragma unroll
                for (int reg = 0; reg < 4; reg++)
                    sm[(wrow + rs * 16 + quad * 4 + reg) * 72 + wcol + cs * 16 + l15] =
                        f2bf((acc[rs][cs][reg] + bv4) * qscale);
            }
        __syncthreads();
        int r = tid >> 2, ch = (tid & 3) * 16;
        unsigned short* dst = ((mat == 0) ? qb : kb) + ((size_t)(bb * NN) + nloc0 + r) * 256 + o0c + ch;
        *(bf16x8*)(dst) = *(const bf16x8*)(&sm[r * 72 + ch]);
        *(bf16x8*)(dst + 8) = *(const bf16x8*)(&sm[r * 72 + ch + 8]);
    } else {
#pragma unroll
        for (int rs = 0; rs < 2; rs++)
#pragma unroll
            for (int cs = 0; cs < 2; cs++) {
                int op = o0c + wcol + cs * 16 + l15;
                float bv4 = bias[((op & 63) << 2) | (op >> 6)];
#pragma unroll
                for (int reg = 0; reg < 4; reg++)
                    sm[(wcol + cs * 16 + l15) * 72 + wrow + rs * 16 + quad * 4 + reg] =
                        f2bf(acc[rs][cs][reg] + bv4);
            }
        __syncthreads();
        int o = tid >> 2, nch = (tid & 3) * 16;
        int opg = o0c + o;
        unsigned short* dst = vb + ((size_t)(bb * 4 + (opg >> 6)) * 64 + (opg & 63)) * NN + nloc0 + nch;
        *(bf16x8*)(dst) = *(const bf16x8*)(&sm[o * 72 + nch]);
        *(bf16x8*)(dst + 8) = *(const bf16x8*)(&sm[o * 72 + nch + 8]);
    }
}

// ---------------- flash: 4 waves/block, wave = m-split, 2 q-groups per wave -----------
__global__ __launch_bounds__(256, 2) void flash_kernel(
    const unsigned short* __restrict__ qb, const unsigned short* __restrict__ kb,
    const unsigned short* __restrict__ vb,
    const unsigned short* __restrict__ maskbf,
    unsigned short* __restrict__ xattn, float* __restrict__ bnsumm) {
    __shared__ __align__(16) char smem[51200];
    unsigned short* Plds = (unsigned short*)smem;
    float* OL = (float*)smem;

    int bh = blockIdx.y, nb = blockIdx.x;
    int bb = bh >> 2, h = bh & 3;
    int tid = threadIdx.x, w = tid >> 6, lane = tid & 63, quad = lane >> 4, l15 = lane & 15;

    if (nb == 0 && bh == 0) {
        bnsumm[tid] = 0.f; bnsumm[tid + 256] = 0.f;
        bnsumm[tid + 512] = 0.f; bnsumm[tid + 768] = 0.f;
    }

    const unsigned short* mask = maskbf + (size_t)bb * NN * NN;
    const unsigned short* Q = qb + (size_t)bb * NN * 256 + h * 64;
    const unsigned short* Kb = kb + (size_t)bb * NN * 256 + h * 64;
    const unsigned short* Vb = vb + (size_t)bh * 64 * NN;
    int row0 = nb * 32;

    bf16x8 qf[2][2];
#pragma unroll
    for (int s = 0; s < 2; s++)
#pragma unroll
        for (int kc = 0; kc < 2; kc++)
            qf[s][kc] = *(const bf16x8*)(Q + (size_t)(row0 + s * 16 + l15) * 256 + kc * 32 + quad * 8);

    const unsigned short* mrow[2][4];
#pragma unroll
    for (int s = 0; s < 2; s++)
#pragma unroll
        for (int reg = 0; reg < 4; reg++)
            mrow[s][reg] = mask + (size_t)(row0 + s * 16 + quad * 4 + reg) * NN + w * 256;

    f32x4 Oa[2][4];
#pragma unroll
    for (int s = 0; s < 2; s++)
#pragma unroll
        for (int dt = 0; dt < 4; dt++) Oa[s][dt] = (f32x4){0.f, 0.f, 0.f, 0.f};
    float mrun[2][4], lrun[2][4];
#pragma unroll
    for (int s = 0; s < 2; s++)
#pragma unroll
        for (int r = 0; r < 4; r++) { mrun[s][r] = -1e30f; lrun[s][r] = 0.f; }

    unsigned short* Pw = Plds + w * (16 * 72);

    for (int mt = 0; mt < 4; mt++) {
        int ml = mt * 64;
        int m0 = w * 256 + ml;
        f32x4 sA[4], sB[4];
#pragma unroll
        for (int t = 0; t < 4; t++) {
            sA[t] = (f32x4){0.f, 0.f, 0.f, 0.f};
            sB[t] = (f32x4){0.f, 0.f, 0.f, 0.f};
        }
#pragma unroll
        for (int t = 0; t < 4; t++)
#pragma unroll
            for (int kc = 0; kc < 2; kc++) {
                bf16x8 kf = *(const bf16x8*)(Kb + (size_t)(m0 + t * 16 + l15) * 256 + kc * 32 + quad * 8);
                sA[t] = mfma16(qf[0][kc], kf, sA[t]);
                sB[t] = mfma16(qf[1][kc], kf, sB[t]);
            }
        bf16x8 vf[8];
#pragma unroll
        for (int dt = 0; dt < 4; dt++)
#pragma unroll
            for (int kc = 0; kc < 2; kc++)
                vf[dt * 2 + kc] = *(const bf16x8*)(Vb + (size_t)(dt * 16 + l15) * NN + m0 + kc * 32 + quad * 8);
#pragma unroll
        for (int s = 0; s < 2; s++) {
            float sv[4][4], rmax[4];
#pragma unroll
            for (int r = 0; r < 4; r++) rmax[r] = -1e30f;
#pragma unroll
            for (int t = 0; t < 4; t++)
#pragma unroll
                for (int reg = 0; reg < 4; reg++) {
                    float sc = (s == 0) ? sA[t][reg] : sB[t][reg];
                    float v = sc * bf2f(mrow[s][reg][ml + t * 16 + l15]);
                    sv[t][reg] = v;
                    rmax[reg] = fmaxf(rmax[reg], v);
                }
#pragma unroll
            for (int reg = 0; reg < 4; reg++) {
                rmax[reg] = fmaxf(rmax[reg], __shfl_xor(rmax[reg], 1, 64));
                rmax[reg] = fmaxf(rmax[reg], __shfl_xor(rmax[reg], 2, 64));
                rmax[reg] = fmaxf(rmax[reg], __shfl_xor(rmax[reg], 4, 64));
                rmax[reg] = fmaxf(rmax[reg], __shfl_xor(rmax[reg], 8, 64));
            }
            float alpha[4], rsum[4];
#pragma unroll
            for (int reg = 0; reg < 4; reg++) {
                float mn = fmaxf(mrun[s][reg], rmax[reg]);
                alpha[reg] = exp2f(mrun[s][reg] - mn);
                mrun[s][reg] = mn;
                rsum[reg] = 0.f;
            }
#pragma unroll
            for (int t = 0; t < 4; t++)
#pragma unroll
                for (int reg = 0; reg < 4; reg++) {
                    float p = exp2f(sv[t][reg] - mrun[s][reg]);
                    sv[t][reg] = p;
                    rsum[reg] += p;
                }
#pragma unroll
            for (int reg = 0; reg < 4; reg++) {
                rsum[reg] += __shfl_xor(rsum[reg], 1, 64);
                rsum[reg] += __shfl_xor(rsum[reg], 2, 64);
                rsum[reg] += __shfl_xor(rsum[reg], 4, 64);
                rsum[reg] += __shfl_xor(rsum[reg], 8, 64);
                lrun[s][reg] = lrun[s][reg] * alpha[reg] + rsum[reg];
            }
#pragma unroll
            for (int dt = 0; dt < 4; dt++)
#pragma unroll
                for (int reg = 0; reg < 4; reg++) Oa[s][dt][reg] *= alpha[reg];
#pragma unroll
            for (int t = 0; t < 4; t++)
#pragma unroll
                for (int reg = 0; reg < 4; reg++)
                    Pw[(quad * 4 + reg) * 72 + t * 16 + l15] = f2bf_trunc(sv[t][reg]);
            bf16x8 pf[2];
#pragma unroll
            for (int kc = 0; kc < 2; kc++)
                pf[kc] = *(const bf16x8*)(Pw + l15 * 72 + kc * 32 + quad * 8);
#pragma unroll
            for (int dt = 0; dt < 4; dt++)
#pragma unroll
                for (int kc = 0; kc < 2; kc++)
                    Oa[s][dt] = mfma16(pf[kc], vf[dt * 2 + kc], Oa[s][dt]);
        }
    }
    __syncthreads();
#pragma unroll
    for (int s = 0; s < 2; s++) {
        float* mine = OL + (size_t)((s + 2 * w) * 64 + lane) * 25;
#pragma unroll
        for (int dt = 0; dt < 4; dt++)
#pragma unroll
            for (int reg = 0; reg < 4; reg++) mine[dt * 4 + reg] = Oa[s][dt][reg];
#pragma unroll
        for (int reg = 0; reg < 4; reg++) { mine[16 + reg] = mrun[s][reg]; mine[20 + reg] = lrun[s][reg]; }
    }
    __syncthreads();
    if (w < 2) {
        const float* p[4];
#pragma unroll
        for (int j = 0; j < 4; j++) p[j] = OL + (size_t)((w + 2 * j) * 64 + lane) * 25;
        float e[4][4], li[4];
#pragma unroll
        for (int reg = 0; reg < 4; reg++) {
            float M = fmaxf(fmaxf(p[0][16 + reg], p[1][16 + reg]),
                            fmaxf(p[2][16 + reg], p[3][16 + reg]));
            float L = 0.f;
#pragma unroll
            for (int j = 0; j < 4; j++) {
                e[j][reg] = exp2f(p[j][16 + reg] - M);
                L += p[j][20 + reg] * e[j][reg];
            }
            li[reg] = 1.f / L;
        }
#pragma unroll
        for (int dt = 0; dt < 4; dt++)
#pragma unroll
            for (int reg = 0; reg < 4; reg++) {
                float val = 0.f;
#pragma unroll
                for (int j = 0; j < 4; j++) val += p[j][dt * 4 + reg] * e[j][reg];
                val *= li[reg];
                int n = row0 + w * 16 + quad * 4 + reg;
                int col = h * 64 + dt * 16 + l15;
                xattn[((size_t)bb * NN + n) * DD + col] = f2bf(val);
            }
    }
}

// ---------------- conv1: M=4096, N=512, K=512 (x|attn); BK=128 staging + BN stats -----
__global__ __launch_bounds__(256) void conv1_kernel(
    const unsigned short* __restrict__ xbf, const unsigned short* __restrict__ xattn,
    const unsigned short* __restrict__ W1_l, const unsigned short* __restrict__ W1m_l,
    const float* __restrict__ bmix_l,
    unsigned short* __restrict__ out1, float* __restrict__ bnsumm) {
    __shared__ __align__(16) unsigned short sm[16384];
    unsigned short* Al = sm;
    unsigned short* Bl = sm + 8192;

    int m0 = blockIdx.x * 64, o0 = blockIdx.y * 64;
    int bb = m0 >> 10, nloc0 = m0 & 1023;
    const unsigned short* A1 = xbf + (size_t)bb * NN * DD + (size_t)nloc0 * DD;
    const unsigned short* A2 = xattn + (size_t)bb * NN * DD + (size_t)nloc0 * DD;

    int tid = threadIdx.x, w = tid >> 6, lane = tid & 63, quad = lane >> 4, l15 = lane & 15;
    int wrow = (w & 1) * 32, wcol = (w >> 1) * 32;
    int lrow4 = lane >> 4, lchnk = lane & 15;

    f32x4 acc[2][2];
#pragma unroll
    for (int r = 0; r < 2; r++)
#pragma unroll
        for (int c = 0; c < 2; c++) acc[r][c] = (f32x4){0.f, 0.f, 0.f, 0.f};

    for (int ks = 0; ks < 4; ks++) {
        const unsigned short* As = (ks < 2) ? A1 : A2;
        int kloc = (ks & 1) * 128;
        __syncthreads();
#pragma unroll
        for (int j = 0; j < 4; j++) {
            int r = w * 16 + j * 4 + lrow4;
            int lc = (lchnk ^ (r & 15)) * 8;
            gll16(As + (size_t)r * DD + kloc + lc, Al + (w * 16 + j * 4) * 128);
            int orow = o0 + r;
            const unsigned short* bg = (ks < 2)
                ? (W1_l + (size_t)orow * 512 + ks * 128 + lc)
                : (W1m_l + (size_t)orow * 256 + (ks - 2) * 128 + lc);
            gll16(bg, Bl + (w * 16 + j * 4) * 128);
        }
        __syncthreads();
#pragma unroll
        for (int kh = 0; kh < 4; kh++) {
            bf16x8 bf[2], af[2];
#pragma unroll
            for (int cs = 0; cs < 2; cs++) {
                int rb = wcol + cs * 16 + l15;
                bf[cs] = *(const bf16x8*)(Bl + rb * 128 + (((kh * 4 + quad) ^ (rb & 15)) * 8));
            }
#pragma unroll
            for (int rs = 0; rs < 2; rs++) {
                int ra = wrow + rs * 16 + l15;
                af[rs] = *(const bf16x8*)(Al + ra * 128 + (((kh * 4 + quad) ^ (ra & 15)) * 8));
            }
#pragma unroll
            for (int rs = 0; rs < 2; rs++)
#pragma unroll
                for (int cs = 0; cs < 2; cs++)
                    acc[rs][cs] = mfma16(af[rs], bf[cs], acc[rs][cs]);
        }
    }
    __syncthreads();
    float cs_s[2] = {0.f, 0.f}, cs_q[2] = {0.f, 0.f};
#pragma unroll
    for (int rs = 0; rs < 2; rs++)
#pragma unroll
        for (int cs = 0; cs < 2; cs++) {
            int o = o0 + wcol + cs * 16 + l15;
            float bvx = bmix_l[o];
#pragma unroll
            for (int reg = 0; reg < 4; reg++) {
                float val = acc[rs][cs][reg] + bvx;
                sm[(wrow + rs * 16 + quad * 4 + reg) * 72 + wcol + cs * 16 + l15] = f2bf(val);
                cs_s[cs] += val;
                cs_q[cs] += val * val;
            }
        }
#pragma unroll
    for (int cs = 0; cs < 2; cs++) {
        cs_s[cs] += __shfl_xor(cs_s[cs], 16, 64);
        cs_s[cs] += __shfl_xor(cs_s[cs], 32, 64);
        cs_q[cs] += __shfl_xor(cs_q[cs], 16, 64);
        cs_q[cs] += __shfl_xor(cs_q[cs], 32, 64);
    }
    if (lane < 16) {
#pragma unroll
        for (int cs = 0; cs < 2; cs++) {
            atomicAdd(&bnsumm[o0 + wcol + cs * 16 + lane], cs_s[cs]);
            atomicAdd(&bnsumm[512 + o0 + wcol + cs * 16 + lane], cs_q[cs]);
        }
    }
    __syncthreads();
    int r = tid >> 2, ch = (tid & 3) * 16;
    unsigned short* dst = out1 + ((size_t)(bb * NN) + nloc0 + r) * 512 + o0 + ch;
    *(bf16x8*)(dst) = *(const bf16x8*)(&sm[r * 72 + ch]);
    *(bf16x8*)(dst + 8) = *(const bf16x8*)(&sm[r * 72 + ch + 8]);
}

// ---------------- conv2: GEMM M=4096, N=256, K=512 with fused BN+ReLU A-staging -------
__global__ __launch_bounds__(256) void conv2_kernel(
    const unsigned short* __restrict__ out1, const unsigned short* __restrict__ W2_l,
    const float* __restrict__ b2_l, const float* __restrict__ bnsumm,
    const float* __restrict__ g1_l, const float* __restrict__ beta1_l,
    float* __restrict__ desc, unsigned short* __restrict__ xbf) {
    __shared__ __align__(16) unsigned short Al[2048];
    __shared__ __align__(16) unsigned short Bl[4096];
    __shared__ float ssc[512], ssh[512];

    int tid = threadIdx.x;
    for (int i = tid; i < 512; i += 256) {
        float s = bnsumm[i], s2 = bnsumm[512 + i];
        float mean = s * (1.f / 4096.f);
        float var = s2 * (1.f / 4096.f) - mean * mean;
        float sc = g1_l[i] * rsqrtf(var + 1e-5f);
        ssc[i] = sc;
        ssh[i] = beta1_l[i] - mean * sc;
    }

    int m0 = blockIdx.x * 32, o0 = blockIdx.y * 64;
    int bb = m0 >> 10, nloc0 = m0 & 1023;
    const unsigned short* A = out1 + ((size_t)(bb * NN) + nloc0) * 512;

    int w = tid >> 6, lane = tid & 63, quad = lane >> 4, l15 = lane & 15;
    int wr = (w & 1) * 16, wc = (w >> 1) * 32;
    int lrow = lane >> 3, chnk = lane & 7;
    int ar = tid >> 3, ap = tid & 7;

    f32x4 acc[2];
    acc[0] = (f32x4){0.f, 0.f, 0.f, 0.f};
    acc[1] = (f32x4){0.f, 0.f, 0.f, 0.f};

    for (int ks = 0; ks < 8; ks++) {
        int k0 = ks * 64;
        __syncthreads();
#pragma unroll
        for (int j = 0; j < 2; j++) {
            int r = w * 16 + j * 8 + lrow;
            gll16(W2_l + (size_t)(o0 + r) * 512 + k0 + ((chnk ^ (r & 7)) * 8),
                  Bl + (w * 16 + j * 8) * 64);
        }
        {
            int lc = (ap ^ (ar & 7)) * 8;
            union { bf16x8 v; unsigned short u[8]; } in, tr;
            in.v = *(const bf16x8*)(A + (size_t)ar * 512 + k0 + lc);
#pragma unroll
            for (int j = 0; j < 8; j++) {
                int ch = k0 + lc + j;
                tr.u[j] = f2bf(fmaxf(0.f, bf2f(in.u[j]) * ssc[ch] + ssh[ch]));
            }
            *(bf16x8*)(Al + ar * 64 + ap * 8) = tr.v;
        }
        __syncthreads();
#pragma unroll
        for (int kh = 0; kh < 2; kh++) {
            int ra = wr + l15;
            bf16x8 af = *(const bf16x8*)(Al + ra * 64 + (((kh * 4 + quad) ^ (ra & 7)) * 8));
#pragma unroll
            for (int cs = 0; cs < 2; cs++) {
                int rb = wc + cs * 16 + l15;
                bf16x8 bf = *(const bf16x8*)(Bl + rb * 64 + (((kh * 4 + quad) ^ (rb & 7)) * 8));
                acc[cs] = mfma16(af, bf, acc[cs]);
            }
        }
    }
#pragma unroll
    for (int cs = 0; cs < 2; cs++)
#pragma unroll
        for (int reg = 0; reg < 4; reg++) {
            int n = nloc0 + wr + quad * 4 + reg;
            int o = o0 + wc + cs * 16 + l15;
            size_t di = ((size_t)bb * NN + n) * DD + o;
            float nd = desc[di] + acc[cs][reg] + b2_l[o];
            desc[di] = nd;
            xbf[di] = f2bf(nd);
        }
}

extern "C" void kernel_launch(void* const* d_in, const int* in_sizes, int n_in,
                              void* d_out, int out_size, void* d_ws, size_t ws_size,
                              hipStream_t stream) {
    const float* desc0 = (const float*)d_in[0];
    const float* desc1 = (const float*)d_in[1];
    const float* M0p   = (const float*)d_in[2];
    const float* M1p   = (const float*)d_in[3];
    const float* Wq = (const float*)d_in[4];  const float* bq = (const float*)d_in[5];
    const float* Wk = (const float*)d_in[6];  const float* bk = (const float*)d_in[7];
    const float* Wv = (const float*)d_in[8];  const float* bv = (const float*)d_in[9];
    const float* Wm = (const float*)d_in[10]; const float* bm = (const float*)d_in[11];
    const float* W1 = (const float*)d_in[12]; const float* b1 = (const float*)d_in[13];
    const float* g1 = (const float*)d_in[14]; const float* beta1 = (const float*)d_in[15];
    const float* W2 = (const float*)d_in[16]; const float* b2 = (const float*)d_in[17];
    float* out = (float*)d_out;
    char* ws = (char*)d_ws;

    float*          desc   = (float*)(ws);
    unsigned short* xbf    = (unsigned short*)(ws + (4ull << 20));
    unsigned short* qb     = (unsigned short*)(ws + (6ull << 20));
    unsigned short* kbuf   = (unsigned short*)(ws + (8ull << 20));
    unsigned short* vbuf   = (unsigned short*)(ws + (10ull << 20));
    unsigned short* xattn  = (unsigned short*)(ws + (12ull << 20));
    unsigned short* out1   = (unsigned short*)(ws + (14ull << 20));
    float*          bnsumm = (float*)(ws + (18ull << 20));
    float*          bmix   = (float*)(ws + (18ull << 20) + 8192);
    unsigned short* maskbf = (unsigned short*)(ws + (19ull << 20));
    unsigned short* W1m    = (unsigned short*)(ws + (27ull << 20));
    unsigned short* wbf    = (unsigned short*)(ws + (29ull << 20));

    const int SQ = LL * 65536;

    prep_kernel<<<9728, 256, 0, stream>>>(desc0, desc1, M0p, M1p, Wq, Wk, Wv, Wm,
                                          W1, W2, bm, b1, wbf, maskbf, bmix, desc, xbf);
    fold1_kernel<<<dim3(8, 4, 6), 256, 0, stream>>>(wbf + 4 * (size_t)SQ, wbf + 3 * (size_t)SQ, W1m);

    for (int l = 0; l < LL; l++) {
        int cross = l & 1;
        const unsigned short* Wq_l = wbf + (size_t)l * 65536;
        const unsigned short* Wk_l = wbf + SQ + (size_t)l * 65536;
        const unsigned short* Wv_l = wbf + 2 * (size_t)SQ + (size_t)l * 65536;
        const unsigned short* W1_l = wbf + 4 * (size_t)SQ + (size_t)l * 262144;
        const unsigned short* W2_l = wbf + 4 * (size_t)SQ + (size_t)LL * 262144 + (size_t)l * 131072;
        const unsigned short* W1m_l = W1m + (size_t)l * 131072;

        proj_kernel<<<dim3(64, 12), 256, 0, stream>>>(
            xbf, Wq_l, Wk_l, Wv_l, bq + l * 256, bk + l * 256, bv + l * 256,
            qb, kbuf, vbuf, cross);
        flash_kernel<<<dim3(32, 16), 256, 0, stream>>>(qb, kbuf, vbuf, maskbf, xattn, bnsumm);
        conv1_kernel<<<dim3(64, 8), 256, 0, stream>>>(
            xbf, xattn, W1_l, W1m_l, bmix + l * 512, out1, bnsumm);
        conv2_kernel<<<dim3(128, 4), 256, 0, stream>>>(
            out1, W2_l, b2 + l * 256, bnsumm, g1 + l * 512, beta1 + l * 512, desc, xbf);
    }

    final_kernel<<<dim3(32, 8, 4), 256, 0, stream>>>(desc, out);
}